// Round 5
// baseline (4296.108 us; speedup 1.0000x reference)
//
#include <hip/hip_runtime.h>
#include <math.h>

constexpr int Bn = 8;
constexpr int Np = 2048;
constexpr int Kn = 32;
constexpr float NEGS = 0.2f;

typedef __attribute__((ext_vector_type(8))) short short8;
typedef __attribute__((ext_vector_type(4))) float f32x4;
typedef unsigned short ushortT;

__device__ __forceinline__ float lrelu(float v) { return v > 0.f ? v : NEGS * v; }

// split fp32 -> bf16 hi (truncate) + bf16 lo (residual, truncate); packed 2-at-a-time
__device__ __forceinline__ void cvt2u(float a, float b, unsigned& h, unsigned& l) {
    unsigned ua = __float_as_uint(a), ub = __float_as_uint(b);
    h = (ua >> 16) | (ub & 0xffff0000u);
    float ra = a - __uint_as_float(ua & 0xffff0000u);
    float rb = b - __uint_as_float(ub & 0xffff0000u);
    l = (__float_as_uint(ra) >> 16) | (__float_as_uint(rb) & 0xffff0000u);
}

// x [B,3,N] -> pts point-major [B*N, 4] (pad lane = 0)
__global__ __launch_bounds__(256) void k_transpose(const float* __restrict__ x, float* __restrict__ pts) {
    int i = blockIdx.x * 256 + threadIdx.x;
    int b = i / Np, n = i % Np;
    float p0 = x[((size_t)b * 3 + 0) * Np + n];
    float p1 = x[((size_t)b * 3 + 1) * Np + n];
    float p2 = x[((size_t)b * 3 + 2) * Np + n];
    float4 v = make_float4(p0, p1, p2, 0.f);
    *(float4*)&pts[(size_t)i * 4] = v;
}

// xx[i] = sum_c pm[i*ld+c]^2 ; one wave per point, 4 points per block
__global__ __launch_bounds__(256) void k_xx(const float* __restrict__ pm, float* __restrict__ xxg, int C, int ld) {
    int wid = threadIdx.x >> 6, lane = threadIdx.x & 63;
    int pt = blockIdx.x * 4 + wid;
    const float* row = pm + (size_t)pt * ld;
    float acc = 0.f;
    for (int c = lane; c < C; c += 64) { float v = row[c]; acc = fmaf(v, v, acc); }
    #pragma unroll
    for (int off = 32; off; off >>= 1) acc += __shfl_down(acc, off, 64);
    if (lane == 0) xxg[pt] = acc;
}

// Pack points into mfma_16x16x32 B-fragment order (bf16 hi/lo), per batch.
// idx = (((b*KS+ks)*128 + nt)*64 + lane)*8 + j ; k = ks*32 + (lane>>4)*8 + j ; n = nt*16 + (lane&15)
template<int C, int CK, int LD>
__global__ __launch_bounds__(256) void k_bpack(const float* __restrict__ Xpm,
                                               ushortT* __restrict__ Bh, ushortT* __restrict__ Bl) {
    constexpr int KS = CK / 32;
    int i = blockIdx.x * 256 + threadIdx.x;
    int j = i & 7;
    int lane = (i >> 3) & 63;
    int nt = (i >> 9) & 127;
    int rest = i >> 16;
    int ks = rest % KS;
    int b = rest / KS;
    int k = ks * 32 + (lane >> 4) * 8 + j;
    int n = nt * 16 + (lane & 15);
    float v = (k < C) ? Xpm[((size_t)b * Np + n) * LD + k] : 0.f;
    unsigned u = __float_as_uint(v);
    Bh[i] = (ushortT)(u >> 16);
    float r = v - __uint_as_float(u & 0xffff0000u);
    Bl[i] = (ushortT)(__float_as_uint(r) >> 16);
}

// MFMA kNN: 16 query rows/block, 512 threads (8 waves x 256-col strips).
// d = 2*(split-bf16 MFMA dot) - xx_m - xx_n -> dynamic-LDS dl[16][2050], then
// per-wave hierarchical top-32 (lowest-index tie-break, matches lax.top_k).
template<int C, int CK, int LD>
__global__ __launch_bounds__(512) void k_knn2(const float* __restrict__ Xpm,
                                              const ushortT* __restrict__ Bh, const ushortT* __restrict__ Bl,
                                              const float* __restrict__ xxg, int* __restrict__ idxo) {
    constexpr int KS = CK / 32, CP = CK + 8, CK4 = CK / 4, C4src = LD / 4;
    constexpr int SD = 2050;
    extern __shared__ char smem[];
    ushortT* Ah = (ushortT*)smem;              // [16][CP]
    ushortT* Al = Ah + 16 * CP;                // [16][CP]
    float* xxm = (float*)(Al + 16 * CP);       // [16]
    float* dl = xxm + 16;                      // [16][SD]
    int b = blockIdx.x / (Np / 16);
    int n0 = (blockIdx.x % (Np / 16)) * 16;
    int t = threadIdx.x;
    const float4* Xp4 = (const float4*)Xpm;
    for (int e = t; e < 16 * CK4; e += 512) {
        int r = e / CK4, c4 = e % CK4;
        float4 v = (c4 < C4src) ? Xp4[((size_t)b * Np + n0 + r) * C4src + c4] : make_float4(0.f, 0.f, 0.f, 0.f);
        unsigned h0, l0, h1, l1;
        cvt2u(v.x, v.y, h0, l0);
        cvt2u(v.z, v.w, h1, l1);
        *(uint2*)&Ah[r * CP + 4 * c4] = make_uint2(h0, h1);
        *(uint2*)&Al[r * CP + 4 * c4] = make_uint2(l0, l1);
    }
    if (t < 16) xxm[t] = xxg[b * Np + n0 + t];
    __syncthreads();

    int w = t >> 6, lane = t & 63;
    int quad = lane >> 4, col = lane & 15;
    // preload A fragments (shared across all n-tiles)
    short8 ah[KS], al[KS];
    #pragma unroll
    for (int ks = 0; ks < KS; ++ks) {
        ah[ks] = *(const short8*)&Ah[col * CP + ks * 32 + quad * 8];
        al[ks] = *(const short8*)&Al[col * CP + ks * 32 + quad * 8];
    }
    float xmr[4];
    #pragma unroll
    for (int r = 0; r < 4; ++r) xmr[r] = xxm[quad * 4 + r];

    for (int i = 0; i < 8; ++i) {
        int nt0 = w * 16 + 2 * i, nt1 = nt0 + 1;
        f32x4 a0 = (f32x4){0.f, 0.f, 0.f, 0.f};
        f32x4 a1 = (f32x4){0.f, 0.f, 0.f, 0.f};
        #pragma unroll
        for (int ks = 0; ks < KS; ++ks) {
            size_t bi0 = (((size_t)(b * KS + ks) * 128 + nt0) * 64 + lane) * 8;
            size_t bi1 = (((size_t)(b * KS + ks) * 128 + nt1) * 64 + lane) * 8;
            short8 bh0 = *(const short8*)(Bh + bi0);
            short8 bl0 = *(const short8*)(Bl + bi0);
            short8 bh1 = *(const short8*)(Bh + bi1);
            short8 bl1 = *(const short8*)(Bl + bi1);
            a0 = __builtin_amdgcn_mfma_f32_16x16x32_bf16(ah[ks], bh0, a0, 0, 0, 0);
            a1 = __builtin_amdgcn_mfma_f32_16x16x32_bf16(ah[ks], bh1, a1, 0, 0, 0);
            a0 = __builtin_amdgcn_mfma_f32_16x16x32_bf16(ah[ks], bl0, a0, 0, 0, 0);
            a1 = __builtin_amdgcn_mfma_f32_16x16x32_bf16(ah[ks], bl1, a1, 0, 0, 0);
            a0 = __builtin_amdgcn_mfma_f32_16x16x32_bf16(al[ks], bh0, a0, 0, 0, 0);
            a1 = __builtin_amdgcn_mfma_f32_16x16x32_bf16(al[ks], bh1, a1, 0, 0, 0);
        }
        float xn0 = xxg[b * Np + nt0 * 16 + col];
        float xn1 = xxg[b * Np + nt1 * 16 + col];
        #pragma unroll
        for (int r = 0; r < 4; ++r) {
            int m = quad * 4 + r;
            dl[m * SD + nt0 * 16 + col] = 2.f * a0[r] - xmr[r] - xn0;
            dl[m * SD + nt1 * 16 + col] = 2.f * a1[r] - xmr[r] - xn1;
        }
    }
    __syncthreads();

    // selection: 2 rows per wave, hierarchical (4 groups of 8) lazy-repair extractor
    for (int rr = 0; rr < 2; ++rr) {
        int row = w * 2 + rr;
        const float* drow = dl + row * SD;
        float v[32];
        #pragma unroll
        for (int j = 0; j < 32; ++j) v[j] = drow[lane + 64 * j];
        float gv[4]; int gj[4];
        #pragma unroll
        for (int g = 0; g < 4; ++g) {
            gv[g] = v[8 * g]; gj[g] = 8 * g;
            #pragma unroll
            for (int e = 1; e < 8; ++e) {
                float u = v[8 * g + e];
                if (u > gv[g]) { gv[g] = u; gj[g] = 8 * g + e; }
            }
        }
        float lv = gv[0]; int lg = 0;
        #pragma unroll
        for (int g = 1; g < 4; ++g) if (gv[g] > lv) { lv = gv[g]; lg = g; }
        size_t ob = ((size_t)b * Np + n0 + row) * Kn;
        for (int it = 0; it < Kn; ++it) {
            float bv = lv; int bn = lane + 64 * gj[lg];
            #pragma unroll
            for (int off2 = 32; off2; off2 >>= 1) {
                float ov = __shfl_down(bv, off2, 64);
                int on = __shfl_down(bn, off2, 64);
                if (ov > bv || (ov == bv && on < bn)) { bv = ov; bn = on; }
            }
            bn = __shfl(bn, 0, 64);
            if ((bn & 63) == lane) {
                int j = bn >> 6, g = j >> 3;
                v[j] = -INFINITY;
                gv[g] = v[8 * g]; gj[g] = 8 * g;
                #pragma unroll
                for (int e = 1; e < 8; ++e) {
                    float u = v[8 * g + e];
                    if (u > gv[g]) { gv[g] = u; gj[g] = 8 * g + e; }
                }
                lv = gv[0]; lg = 0;
                #pragma unroll
                for (int g2 = 1; g2 < 4; ++g2) if (gv[g2] > lv) { lv = gv[g2]; lg = g2; }
            }
            if (lane == 0) idxo[ob + it] = bn;
        }
    }
}

// W split+scale+transpose (fp32, for k_ctr): WdsT[c][o] = (W[o][C+c]-W[o][c])*s[o]
__global__ __launch_bounds__(256) void k_wsplit(const float* __restrict__ W, const float* __restrict__ s,
                                                int C, int O, float* __restrict__ WnsT, float* __restrict__ WdsT) {
    int i = blockIdx.x * 256 + threadIdx.x;
    if (i >= C * O) return;
    int c = i / O, o = i % O;
    float a = W[(size_t)o * 2 * C + c];
    float q = W[(size_t)o * 2 * C + C + c];
    float sv = s[o];
    WnsT[i] = a * sv;
    WdsT[i] = (q - a) * sv;
}

// Pack neighbor-half of W (scaled) into mfma_16x16x32 B-fragment order, split bf16 hi/lo.
__global__ __launch_bounds__(256) void k_wpack(const float* __restrict__ W, const float* __restrict__ s,
                                               int C, int O, ushortT* __restrict__ Bh, ushortT* __restrict__ Bl) {
    int i = blockIdx.x * 256 + threadIdx.x;
    if (i >= C * O) return;
    int k = i / O, o = i % O;
    float v = W[(size_t)o * 2 * C + k] * s[o];
    int ks = k >> 5, quad = (k >> 3) & 3, j = k & 7;
    int nt = o >> 4, lane = quad * 16 + (o & 15);
    int NT = O / 16;
    size_t idx = (((size_t)(ks * NT + nt)) * 64 + lane) * 8 + j;
    unsigned u = __float_as_uint(v);
    Bh[idx] = (ushortT)(u >> 16);
    float r = v - __uint_as_float(u & 0xffff0000u);
    Bl[idx] = (ushortT)(__float_as_uint(r) >> 16);
}

// cb[n][o] = sum_c ctr[n][c]*WdsT[c][o] + b[o].  32 points per block.
template<int C, int O, int OPT>
__global__ __launch_bounds__(256) void k_ctr(const float* __restrict__ Xpm, const float* __restrict__ WdsT,
                                             const float* __restrict__ bg, float* __restrict__ cb) {
    constexpr int OG = O / OPT, MG = 256 / OG, MPT = 32 / MG;
    constexpr int C4 = C / 4;
    __shared__ float xs[32][C];
    int b = blockIdx.x / (Np / 32);
    int n0 = (blockIdx.x % (Np / 32)) * 32;
    int t = threadIdx.x;
    const float4* Xp4 = (const float4*)Xpm;
    for (int e = t; e < 32 * C4; e += 256) {
        int pt = e / C4, c4 = e % C4;
        *(float4*)&xs[pt][4 * c4] = Xp4[((size_t)b * Np + n0 + pt) * C4 + c4];
    }
    __syncthreads();
    int og = t % OG, mg = t / OG;
    int o0 = og * OPT;
    float acc[MPT][OPT] = {};
    for (int c = 0; c < C; ++c) {
        float wv[OPT];
        #pragma unroll
        for (int p4 = 0; p4 < OPT / 4; ++p4)
            *(float4*)&wv[4 * p4] = *(const float4*)&WdsT[(size_t)c * O + o0 + 4 * p4];
        #pragma unroll
        for (int m = 0; m < MPT; ++m) {
            float xv = xs[mg * MPT + m][c];
            #pragma unroll
            for (int p = 0; p < OPT; ++p) acc[m][p] = fmaf(wv[p], xv, acc[m][p]);
        }
    }
    #pragma unroll
    for (int m = 0; m < MPT; ++m) {
        #pragma unroll
        for (int p = 0; p < OPT; ++p) {
            int o = o0 + p;
            cb[((size_t)b * Np + n0 + mg * MPT + m) * O + o] = acc[m][p] + bg[o];
        }
    }
}

// MFMA EdgeConv GEMM (split-bf16), max over k, + center term, lrelu.
template<int C, int O, int PTS>
__global__ __launch_bounds__(256) void k_ec3(const float* __restrict__ Xpm, const int* __restrict__ idxg,
                                             const ushortT* __restrict__ Bh, const ushortT* __restrict__ Bl,
                                             const float* __restrict__ cb,
                                             float* __restrict__ Ypm) {
    static_assert(PTS == 2, "M=64 mapping");
    constexpr int M = 64, NT = O / 16, KS = C / 32, C4 = C / 4, CP = C + 8;
    __shared__ ushortT Ah[M][CP];
    __shared__ ushortT Al[M][CP];
    __shared__ float red[PTS][2][O];
    int b = blockIdx.x / (Np / PTS);
    int n0 = (blockIdx.x % (Np / PTS)) * PTS;
    int t = threadIdx.x;
    const int* ip = idxg + ((size_t)b * Np + n0) * Kn;
    const float4* Xp4 = (const float4*)Xpm;
    for (int e = t; e < M * C4; e += 256) {
        int row = e / C4, c4 = e % C4;
        float4 v = Xp4[((size_t)b * Np + ip[row]) * C4 + c4];
        unsigned h0, l0, h1, l1;
        cvt2u(v.x, v.y, h0, l0);
        cvt2u(v.z, v.w, h1, l1);
        *(uint2*)&Ah[row][4 * c4] = make_uint2(h0, h1);
        *(uint2*)&Al[row][4 * c4] = make_uint2(l0, l1);
    }
    __syncthreads();
    int w = t >> 6, lane = t & 63;
    int quad = lane >> 4, col = lane & 15;
    int mrow = w * 16 + col;
    f32x4 acc[NT];
    #pragma unroll
    for (int nt = 0; nt < NT; ++nt) acc[nt] = (f32x4){0.f, 0.f, 0.f, 0.f};
    for (int ks = 0; ks < KS; ++ks) {
        int kb = ks * 32 + quad * 8;
        short8 ah = *(const short8*)&Ah[mrow][kb];
        short8 al = *(const short8*)&Al[mrow][kb];
        #pragma unroll
        for (int nt = 0; nt < NT; ++nt) {
            size_t bi = (((size_t)(ks * NT + nt)) * 64 + lane) * 8;
            short8 bh = *(const short8*)(Bh + bi);
            short8 bl = *(const short8*)(Bl + bi);
            acc[nt] = __builtin_amdgcn_mfma_f32_16x16x32_bf16(ah, bh, acc[nt], 0, 0, 0);
            acc[nt] = __builtin_amdgcn_mfma_f32_16x16x32_bf16(ah, bl, acc[nt], 0, 0, 0);
            acc[nt] = __builtin_amdgcn_mfma_f32_16x16x32_bf16(al, bh, acc[nt], 0, 0, 0);
        }
    }
    int pt = w >> 1, wi = w & 1;
    #pragma unroll
    for (int nt = 0; nt < NT; ++nt) {
        float m = fmaxf(fmaxf(acc[nt][0], acc[nt][1]), fmaxf(acc[nt][2], acc[nt][3]));
        m = fmaxf(m, __shfl_xor(m, 16, 64));
        m = fmaxf(m, __shfl_xor(m, 32, 64));
        if (lane < 16) red[pt][wi][nt * 16 + col] = m;
    }
    __syncthreads();
    for (int idx = t; idx < PTS * O; idx += 256) {
        int pp = idx / O, o = idx % O;
        float m = fmaxf(red[pp][0][o], red[pp][1][o]);
        size_t ni = (size_t)b * Np + n0 + pp;
        Ypm[ni * O + o] = lrelu(m + cb[ni * O + o]);
    }
}

// Legacy fused EdgeConv for layer 1 (C=3)
template<int C, int CPAD, int O, int OPT, int KPT, int PTS>
__global__ __launch_bounds__(256) void k_edgeconv(
    const float* __restrict__ Xpm, const int* __restrict__ idxg,
    const float* __restrict__ W, const float* __restrict__ sg, const float* __restrict__ bg,
    float* __restrict__ Ypm)
{
    constexpr int OG = O / OPT;
    constexpr int NKG = 256 / OG;
    constexpr int CL = CPAD + 4;
    static_assert(NKG * KPT == Kn, "k mapping");
    __shared__ float nbr[PTS][Kn][CL];
    __shared__ float ctr[PTS][CPAD];
    __shared__ float red[PTS][OPT][4][OG];
    int blk = blockIdx.x;
    int b = blk / (Np / PTS);
    int n0 = (blk % (Np / PTS)) * PTS;
    int t = threadIdx.x;
    int lane = t & 63, wid = t >> 6;
    const int* ip = idxg + ((size_t)b * Np + n0) * Kn;
    const float4* Xp4 = (const float4*)Xpm;
    constexpr int C4 = CPAD / 4;
    for (int e = t; e < PTS * C4; e += 256) {
        int pt = e / C4, c4 = e % C4;
        *(float4*)&ctr[pt][4 * c4] = Xp4[((size_t)b * Np + n0 + pt) * C4 + c4];
    }
    for (int e = t; e < PTS * Kn * C4; e += 256) {
        int pt = e / (Kn * C4);
        int r = e % (Kn * C4);
        int k = r / C4, c4 = r % C4;
        int nb = ip[pt * Kn + k];
        *(float4*)&nbr[pt][k][4 * c4] = Xp4[((size_t)b * Np + nb) * C4 + c4];
    }
    __syncthreads();
    int og = t % OG, kg = t / OG;
    float acc[PTS][OPT][KPT] = {};
    float ctt[PTS][OPT] = {};
    for (int c0 = 0; c0 < CPAD; c0 += 4) {
        float wn[OPT][4], wd[OPT][4];
        #pragma unroll
        for (int p = 0; p < OPT; ++p) {
            #pragma unroll
            for (int cc = 0; cc < 4; ++cc) {
                int c = c0 + cc;
                float a = (c < C) ? W[(size_t)(og + p * OG) * (2 * C) + c] : 0.f;
                float q = (c < C) ? W[(size_t)(og + p * OG) * (2 * C) + C + c] : 0.f;
                wn[p][cc] = a; wd[p][cc] = q - a;
            }
        }
        #pragma unroll
        for (int pt = 0; pt < PTS; ++pt) {
            float4 cv = *(const float4*)&ctr[pt][c0];
            #pragma unroll
            for (int p = 0; p < OPT; ++p) {
                ctt[pt][p] = fmaf(wd[p][0], cv.x, ctt[pt][p]);
                ctt[pt][p] = fmaf(wd[p][1], cv.y, ctt[pt][p]);
                ctt[pt][p] = fmaf(wd[p][2], cv.z, ctt[pt][p]);
                ctt[pt][p] = fmaf(wd[p][3], cv.w, ctt[pt][p]);
            }
        }
        #pragma unroll
        for (int pt = 0; pt < PTS; ++pt) {
            #pragma unroll
            for (int k = 0; k < KPT; ++k) {
                float4 nv = *(const float4*)&nbr[pt][kg * KPT + k][c0];
                #pragma unroll
                for (int p = 0; p < OPT; ++p) {
                    acc[pt][p][k] = fmaf(wn[p][0], nv.x, acc[pt][p][k]);
                    acc[pt][p][k] = fmaf(wn[p][1], nv.y, acc[pt][p][k]);
                    acc[pt][p][k] = fmaf(wn[p][2], nv.z, acc[pt][p][k]);
                    acc[pt][p][k] = fmaf(wn[p][3], nv.w, acc[pt][p][k]);
                }
            }
        }
    }
    #pragma unroll
    for (int pt = 0; pt < PTS; ++pt) {
        #pragma unroll
        for (int p = 0; p < OPT; ++p) {
            int o = og + p * OG;
            float sv = sg[o], bv = bg[o];
            float m = -INFINITY;
            #pragma unroll
            for (int k = 0; k < KPT; ++k) {
                float hv = fmaf(acc[pt][p][k] + ctt[pt][p], sv, bv);
                m = fmaxf(m, lrelu(hv));
            }
            #pragma unroll
            for (int s = OG; s < 64; s <<= 1) m = fmaxf(m, __shfl_xor(m, s, 64));
            if (lane < OG) red[pt][p][wid][lane] = m;
        }
    }
    __syncthreads();
    if (t < OG) {
        #pragma unroll
        for (int pt = 0; pt < PTS; ++pt) {
            #pragma unroll
            for (int p = 0; p < OPT; ++p) {
                float m = fmaxf(fmaxf(red[pt][p][0][t], red[pt][p][1][t]),
                                fmaxf(red[pt][p][2][t], red[pt][p][3][t]));
                int o = t + p * OG;
                Ypm[((size_t)b * Np + n0 + pt) * O + o] = m;
            }
        }
    }
}

// W5 transpose [1024][512] -> [512][1024]
__global__ __launch_bounds__(256) void k_w5t(const float* __restrict__ W5, float* __restrict__ W5t) {
    __shared__ float tile[32][33];
    int o0 = (blockIdx.x & 31) * 32;
    int c0 = (blockIdx.x >> 5) * 32;
    int lr = threadIdx.x >> 5, lc = threadIdx.x & 31;
    #pragma unroll
    for (int j = 0; j < 4; ++j) {
        int r = lr + 8 * j;
        tile[r][lc] = W5[(size_t)(o0 + r) * 512 + c0 + lc];
    }
    __syncthreads();
    #pragma unroll
    for (int j = 0; j < 4; ++j) {
        int r = lr + 8 * j;
        W5t[(size_t)(c0 + r) * 1024 + o0 + lc] = tile[lc][r];
    }
}

// W5 + BN + LeakyReLU + per-block max/sum over 32 points -> partials.
__global__ __launch_bounds__(256) void k_w5pool(
    const float* __restrict__ x1, const float* __restrict__ x2,
    const float* __restrict__ x3, const float* __restrict__ x4,
    const float* __restrict__ W5t, const float* __restrict__ s5, const float* __restrict__ b5,
    float* __restrict__ pmax, float* __restrict__ psum)
{
    constexpr int PP = 16;
    __shared__ float cat[PP][512];
    int blk = blockIdx.x;
    int b = blk >> 6;
    int chunk = blk & 63;
    int n0 = chunk * 32;
    int t = threadIdx.x;
    float mx[4] = {-INFINITY, -INFINITY, -INFINITY, -INFINITY};
    float sm[4] = {};
    for (int pass = 0; pass < 2; ++pass) {
        __syncthreads();
        for (int e = t; e < PP * 128; e += 256) {
            int pt = e >> 7, c4 = e & 127;
            size_t pi = (size_t)b * Np + n0 + pass * PP + pt;
            float4 v;
            if (c4 < 16)      v = ((const float4*)x1)[pi * 16 + c4];
            else if (c4 < 32) v = ((const float4*)x2)[pi * 16 + (c4 - 16)];
            else if (c4 < 64) v = ((const float4*)x3)[pi * 32 + (c4 - 32)];
            else              v = ((const float4*)x4)[pi * 64 + (c4 - 64)];
            *(float4*)&cat[pt][4 * c4] = v;
        }
        __syncthreads();
        float acc[4][PP] = {};
        for (int c0 = 0; c0 < 512; c0 += 4) {
            float wv[4][4];
            #pragma unroll
            for (int j = 0; j < 4; ++j) {
                const float* row = W5t + (size_t)(c0 + j) * 1024 + t;
                #pragma unroll
                for (int r = 0; r < 4; ++r) wv[j][r] = row[256 * r];
            }
            #pragma unroll
            for (int pt = 0; pt < PP; ++pt) {
                float4 cv = *(const float4*)&cat[pt][c0];
                #pragma unroll
                for (int r = 0; r < 4; ++r) {
                    acc[r][pt] = fmaf(wv[0][r], cv.x, acc[r][pt]);
                    acc[r][pt] = fmaf(wv[1][r], cv.y, acc[r][pt]);
                    acc[r][pt] = fmaf(wv[2][r], cv.z, acc[r][pt]);
                    acc[r][pt] = fmaf(wv[3][r], cv.w, acc[r][pt]);
                }
            }
        }
        #pragma unroll
        for (int r = 0; r < 4; ++r) {
            int o = t + 256 * r;
            float sv = s5[o], bv = b5[o];
            #pragma unroll
            for (int pt = 0; pt < PP; ++pt) {
                float v = lrelu(fmaf(acc[r][pt], sv, bv));
                mx[r] = fmaxf(mx[r], v);
                sm[r] += v;
            }
        }
    }
    #pragma unroll
    for (int r = 0; r < 4; ++r) {
        int o = t + 256 * r;
        pmax[((size_t)(b * 64 + chunk)) * 1024 + o] = mx[r];
        psum[((size_t)(b * 64 + chunk)) * 1024 + o] = sm[r];
    }
}

__global__ __launch_bounds__(256) void k_poolred(const float* __restrict__ pmax, const float* __restrict__ psum,
                                                 float* __restrict__ g0) {
    int i = blockIdx.x * 256 + threadIdx.x;
    int b = i >> 10, o = i & 1023;
    float mx = -INFINITY, sm = 0.f;
    for (int ch = 0; ch < 64; ++ch) {
        size_t idx = ((size_t)(b * 64 + ch)) * 1024 + o;
        mx = fmaxf(mx, pmax[idx]);
        sm += psum[idx];
    }
    g0[(size_t)b * 2048 + o] = mx;
    g0[(size_t)b * 2048 + 1024 + o] = sm * (1.f / Np);
}

__global__ __launch_bounds__(256) void k_fc(const float* __restrict__ In, int ldIn, int C,
                                            const float* __restrict__ Wm,
                                            const float* __restrict__ bias,
                                            const float* __restrict__ sc, const float* __restrict__ bnb,
                                            int leaky, float* __restrict__ Out, int ldOut, int O) {
    int wid = threadIdx.x >> 6, lane = threadIdx.x & 63;
    int o = blockIdx.x * 4 + wid;
    int b = blockIdx.y;
    if (o >= O) return;
    const float* in = In + (size_t)b * ldIn;
    const float* wr = Wm + (size_t)o * C;
    float acc = 0.f;
    for (int c = lane; c < C; c += 64) acc = fmaf(in[c], wr[c], acc);
    #pragma unroll
    for (int off = 32; off; off >>= 1) acc += __shfl_down(acc, off, 64);
    if (lane == 0) {
        float v = acc + (bias ? bias[o] : 0.f);
        if (sc) v = fmaf(v, sc[o], bnb[o]);
        if (leaky) v = lrelu(v);
        Out[(size_t)b * ldOut + o] = v;
    }
}

extern "C" void kernel_launch(void* const* d_in, const int* in_sizes, int n_in,
                              void* d_out, int out_size, void* d_ws, size_t ws_size,
                              hipStream_t stream) {
    const float* x   = (const float*)d_in[0];
    const float* W1  = (const float*)d_in[1];
    const float* s1  = (const float*)d_in[2];
    const float* b1  = (const float*)d_in[3];
    const float* W2  = (const float*)d_in[4];
    const float* s2  = (const float*)d_in[5];
    const float* b2  = (const float*)d_in[6];
    const float* W3  = (const float*)d_in[7];
    const float* s3  = (const float*)d_in[8];
    const float* b3  = (const float*)d_in[9];
    const float* W4  = (const float*)d_in[10];
    const float* s4  = (const float*)d_in[11];
    const float* b4  = (const float*)d_in[12];
    const float* W5  = (const float*)d_in[13];
    const float* s5  = (const float*)d_in[14];
    const float* b5  = (const float*)d_in[15];
    const float* L1w = (const float*)d_in[16];
    const float* s6  = (const float*)d_in[17];
    const float* b6  = (const float*)d_in[18];
    const float* L2w = (const float*)d_in[19];
    const float* L2b = (const float*)d_in[20];
    const float* s7  = (const float*)d_in[21];
    const float* b7  = (const float*)d_in[22];
    const float* L3w = (const float*)d_in[23];
    const float* L3b = (const float*)d_in[24];
    const float* F1w = (const float*)d_in[25];
    const float* s8  = (const float*)d_in[26];
    const float* b8  = (const float*)d_in[27];
    const float* F2w = (const float*)d_in[28];
    const float* F2b = (const float*)d_in[29];
    const float* s9  = (const float*)d_in[30];
    const float* b9  = (const float*)d_in[31];
    const float* F3w = (const float*)d_in[32];
    const float* F3b = (const float*)d_in[33];

    float* ws = (float*)d_ws;
    size_t off = 0;
    auto alloc = [&](size_t n) { float* p = ws + off; off += n; return p; };
    float* pts  = alloc((size_t)Bn * Np * 4);
    float* x1   = alloc((size_t)Bn * Np * 64);
    float* x2   = alloc((size_t)Bn * Np * 64);
    float* x3   = alloc((size_t)Bn * Np * 128);
    float* x4   = alloc((size_t)Bn * Np * 256);
    float* xcm  = alloc((size_t)Bn * Np * 128);   // aliased: W5t / pmax / psum
    float* xxb  = alloc((size_t)Bn * Np);
    int*   idxb = (int*)alloc((size_t)Bn * Np * Kn);
    float* g0   = alloc((size_t)Bn * 2048);
    float* g1   = alloc((size_t)Bn * 512);
    float* g2   = alloc((size_t)Bn * 256);
    float* y1   = alloc((size_t)Bn * 512);
    float* y2   = alloc((size_t)Bn * 256);
    float* WnsT2 = alloc(64 * 64);
    float* WdsT2 = alloc(64 * 64);
    float* WnsT3 = alloc(64 * 128);
    float* WdsT3 = alloc(64 * 128);
    float* WnsT4 = alloc(128 * 256);
    float* WdsT4 = alloc(128 * 256);
    ushortT* Bh2 = (ushortT*)alloc(64 * 64 / 2);
    ushortT* Bl2 = (ushortT*)alloc(64 * 64 / 2);
    ushortT* Bh3 = (ushortT*)alloc(64 * 128 / 2);
    ushortT* Bl3 = (ushortT*)alloc(64 * 128 / 2);
    ushortT* Bh4 = (ushortT*)alloc(128 * 256 / 2);
    ushortT* Bl4 = (ushortT*)alloc(128 * 256 / 2);
    ushortT* BhK = (ushortT*)alloc(1048576);   // knn B-frag hi (max C=128: 2M shorts)
    ushortT* BlK = (ushortT*)alloc(1048576);
    float* W5t  = xcm;
    float* pmax = xcm + 524288;
    float* psum = xcm + 1048576;
    float* cb2 = x2;
    float* cb3 = x3;
    float* cb4 = x4;

    // dynamic-LDS opt-in for knn2 (139,968 B max); idempotent, safe pre-capture too
    auto shsz = [](int CP) { return 16 * CP * 2 * 2 + 64 + 16 * 2050 * 4; };
    int sh3 = shsz(40), sh64 = shsz(72), sh128 = shsz(136);
    hipFuncSetAttribute((const void*)k_knn2<3, 32, 4>, hipFuncAttributeMaxDynamicSharedMemorySize, sh3);
    hipFuncSetAttribute((const void*)k_knn2<64, 64, 64>, hipFuncAttributeMaxDynamicSharedMemorySize, sh64);
    hipFuncSetAttribute((const void*)k_knn2<128, 128, 128>, hipFuncAttributeMaxDynamicSharedMemorySize, sh128);

    k_transpose<<<Bn * Np / 256, 256, 0, stream>>>(x, pts);
    k_wsplit<<<16, 256, 0, stream>>>(W2, s2, 64, 64, WnsT2, WdsT2);
    k_wsplit<<<32, 256, 0, stream>>>(W3, s3, 64, 128, WnsT3, WdsT3);
    k_wsplit<<<128, 256, 0, stream>>>(W4, s4, 128, 256, WnsT4, WdsT4);
    k_wpack<<<16, 256, 0, stream>>>(W2, s2, 64, 64, Bh2, Bl2);
    k_wpack<<<32, 256, 0, stream>>>(W3, s3, 64, 128, Bh3, Bl3);
    k_wpack<<<128, 256, 0, stream>>>(W4, s4, 128, 256, Bh4, Bl4);

    // Layer 1: C=3
    k_xx<<<Bn * Np / 4, 256, 0, stream>>>(pts, xxb, 3, 4);
    k_bpack<3, 32, 4><<<2048, 256, 0, stream>>>(pts, BhK, BlK);
    k_knn2<3, 32, 4><<<Bn * Np / 16, 512, sh3, stream>>>(pts, BhK, BlK, xxb, idxb);
    k_edgeconv<3, 4, 64, 1, 8, 4><<<Bn * Np / 4, 256, 0, stream>>>(pts, idxb, W1, s1, b1, x1);

    // Layer 2: C=64 -> O=64
    k_xx<<<Bn * Np / 4, 256, 0, stream>>>(x1, xxb, 64, 64);
    k_bpack<64, 64, 64><<<4096, 256, 0, stream>>>(x1, BhK, BlK);
    k_knn2<64, 64, 64><<<Bn * Np / 16, 512, sh64, stream>>>(x1, BhK, BlK, xxb, idxb);
    k_ctr<64, 64, 4><<<Bn * Np / 32, 256, 0, stream>>>(x1, WdsT2, b2, cb2);
    k_ec3<64, 64, 2><<<Bn * Np / 2, 256, 0, stream>>>(x1, idxb, Bh2, Bl2, cb2, x2);

    // Layer 3: C=64 -> O=128
    k_xx<<<Bn * Np / 4, 256, 0, stream>>>(x2, xxb, 64, 64);
    k_bpack<64, 64, 64><<<4096, 256, 0, stream>>>(x2, BhK, BlK);
    k_knn2<64, 64, 64><<<Bn * Np / 16, 512, sh64, stream>>>(x2, BhK, BlK, xxb, idxb);
    k_ctr<64, 128, 8><<<Bn * Np / 32, 256, 0, stream>>>(x2, WdsT3, b3, cb3);
    k_ec3<64, 128, 2><<<Bn * Np / 2, 256, 0, stream>>>(x2, idxb, Bh3, Bl3, cb3, x3);

    // Layer 4: C=128 -> O=256
    k_xx<<<Bn * Np / 4, 256, 0, stream>>>(x3, xxb, 128, 128);
    k_bpack<128, 128, 128><<<8192, 256, 0, stream>>>(x3, BhK, BlK);
    k_knn2<128, 128, 128><<<Bn * Np / 16, 512, sh128, stream>>>(x3, BhK, BlK, xxb, idxb);
    k_w5t<<<512, 256, 0, stream>>>(W5, W5t);
    k_ctr<128, 256, 8><<<Bn * Np / 32, 256, 0, stream>>>(x3, WdsT4, b4, cb4);
    k_ec3<128, 256, 2><<<Bn * Np / 2, 256, 0, stream>>>(x3, idxb, Bh4, Bl4, cb4, x4);

    // W5 + pooling
    k_w5pool<<<Bn * 64, 256, 0, stream>>>(x1, x2, x3, x4, W5t, s5, b5, pmax, psum);
    k_poolred<<<Bn * 1024 / 256, 256, 0, stream>>>(pmax, psum, g0);

    float* out = (float*)d_out;
    k_fc<<<dim3(128, Bn), 256, 0, stream>>>(g0, 2048, 2048, L1w, nullptr, s6, b6, 1, g1, 512, 512);
    k_fc<<<dim3(64, Bn), 256, 0, stream>>>(g1, 512, 512, L2w, L2b, s7, b7, 1, g2, 256, 256);
    k_fc<<<dim3(2, Bn), 256, 0, stream>>>(g2, 256, 256, L3w, L3b, nullptr, nullptr, 0, out, 5, 5);
    k_fc<<<dim3(128, Bn), 256, 0, stream>>>(g0, 2048, 1024, F1w, nullptr, s8, b8, 1, y1, 512, 512);
    k_fc<<<dim3(64, Bn), 256, 0, stream>>>(y1, 512, 512, F2w, F2b, s9, b9, 1, y2, 256, 256);
    k_fc<<<dim3(2, Bn), 256, 0, stream>>>(y2, 256, 256, F3w, F3b, nullptr, nullptr, 0, out + 40, 5, 5);
}

// Round 7
// 1728.658 us; speedup vs baseline: 2.4852x; 2.4852x over previous
//
#include <hip/hip_runtime.h>
#include <math.h>

constexpr int Bn = 8;
constexpr int Np = 2048;
constexpr int Kn = 32;
constexpr float NEGS = 0.2f;

typedef __attribute__((ext_vector_type(8))) short short8;
typedef __attribute__((ext_vector_type(4))) float f32x4;
typedef unsigned short ushortT;

__device__ __forceinline__ float lrelu(float v) { return v > 0.f ? v : NEGS * v; }

// split fp32 -> bf16 hi (truncate) + bf16 lo (residual, truncate); packed 2-at-a-time
__device__ __forceinline__ void cvt2u(float a, float b, unsigned& h, unsigned& l) {
    unsigned ua = __float_as_uint(a), ub = __float_as_uint(b);
    h = (ua >> 16) | (ub & 0xffff0000u);
    float ra = a - __uint_as_float(ua & 0xffff0000u);
    float rb = b - __uint_as_float(ub & 0xffff0000u);
    l = (__float_as_uint(ra) >> 16) | (__float_as_uint(rb) & 0xffff0000u);
}

// x [B,3,N] -> pts point-major [B*N, 4] (pad lane = 0)
__global__ __launch_bounds__(256) void k_transpose(const float* __restrict__ x, float* __restrict__ pts) {
    int i = blockIdx.x * 256 + threadIdx.x;
    int b = i / Np, n = i % Np;
    float p0 = x[((size_t)b * 3 + 0) * Np + n];
    float p1 = x[((size_t)b * 3 + 1) * Np + n];
    float p2 = x[((size_t)b * 3 + 2) * Np + n];
    float4 v = make_float4(p0, p1, p2, 0.f);
    *(float4*)&pts[(size_t)i * 4] = v;
}

// xx[i] = sum_c pm[i*ld+c]^2 ; one wave per point, 4 points per block
__global__ __launch_bounds__(256) void k_xx(const float* __restrict__ pm, float* __restrict__ xxg, int C, int ld) {
    int wid = threadIdx.x >> 6, lane = threadIdx.x & 63;
    int pt = blockIdx.x * 4 + wid;
    const float* row = pm + (size_t)pt * ld;
    float acc = 0.f;
    for (int c = lane; c < C; c += 64) { float v = row[c]; acc = fmaf(v, v, acc); }
    #pragma unroll
    for (int off = 32; off; off >>= 1) acc += __shfl_down(acc, off, 64);
    if (lane == 0) xxg[pt] = acc;
}

// Pack points into mfma_16x16x32 B-fragment order (bf16 hi/lo), per batch.
template<int C, int CK, int LD>
__global__ __launch_bounds__(256) void k_bpack(const float* __restrict__ Xpm,
                                               ushortT* __restrict__ Bh, ushortT* __restrict__ Bl) {
    constexpr int KS = CK / 32;
    int i = blockIdx.x * 256 + threadIdx.x;
    int j = i & 7;
    int lane = (i >> 3) & 63;
    int nt = (i >> 9) & 127;
    int rest = i >> 16;
    int ks = rest % KS;
    int b = rest / KS;
    int k = ks * 32 + (lane >> 4) * 8 + j;
    int n = nt * 16 + (lane & 15);
    float v = (k < C) ? Xpm[((size_t)b * Np + n) * LD + k] : 0.f;
    unsigned u = __float_as_uint(v);
    Bh[i] = (ushortT)(u >> 16);
    float r = v - __uint_as_float(u & 0xffff0000u);
    Bl[i] = (ushortT)(__float_as_uint(r) >> 16);
}

// MFMA kNN v4: 1024 threads = 16 waves; 16 query rows/block; wave w computes cols [w*128,(w+1)*128)
// via split-bf16 MFMA -> float distances in LDS (stride 2050). Selection restores round-5's EXACT
// sequential argmax semantics (value desc, lowest global index on ties == lax.top_k) but with
// group-of-8 (value,index) caches in scalar vars, static-indexed clear, readfirstlane scalarization
// -> zero dynamic register indexing -> zero scratch.
template<int C, int CK, int LD>
__global__ __launch_bounds__(1024) void k_knn4(const float* __restrict__ Xpm,
                                               const ushortT* __restrict__ Bh, const ushortT* __restrict__ Bl,
                                               const float* __restrict__ xxg, int* __restrict__ idxo) {
    constexpr int KS = CK / 32, CP = CK + 8, CK4 = CK / 4, C4src = LD / 4;
    constexpr int SD = 2050;
    extern __shared__ char smem[];
    ushortT* Ah = (ushortT*)smem;              // [16][CP]
    ushortT* Al = Ah + 16 * CP;                // [16][CP]
    float* xxm = (float*)(Al + 16 * CP);       // [16]
    float* dl = xxm + 16;                      // [16][SD] distances
    int b = blockIdx.x / (Np / 16);
    int n0 = (blockIdx.x % (Np / 16)) * 16;
    int t = threadIdx.x;
    const float4* Xp4 = (const float4*)Xpm;
    for (int e = t; e < 16 * CK4; e += 1024) {
        int r = e / CK4, c4 = e % CK4;
        float4 v = (c4 < C4src) ? Xp4[((size_t)b * Np + n0 + r) * C4src + c4] : make_float4(0.f, 0.f, 0.f, 0.f);
        unsigned h0, l0, h1, l1;
        cvt2u(v.x, v.y, h0, l0);
        cvt2u(v.z, v.w, h1, l1);
        *(uint2*)&Ah[r * CP + 4 * c4] = make_uint2(h0, h1);
        *(uint2*)&Al[r * CP + 4 * c4] = make_uint2(l0, l1);
    }
    if (t < 16) xxm[t] = xxg[b * Np + n0 + t];
    __syncthreads();

    int w = t >> 6, lane = t & 63;
    int quad = lane >> 4, col = lane & 15;
    short8 ah[KS], al[KS];
    #pragma unroll
    for (int ks = 0; ks < KS; ++ks) {
        ah[ks] = *(const short8*)&Ah[col * CP + ks * 32 + quad * 8];
        al[ks] = *(const short8*)&Al[col * CP + ks * 32 + quad * 8];
    }
    float xmr[4];
    #pragma unroll
    for (int r = 0; r < 4; ++r) xmr[r] = xxm[quad * 4 + r];

    // MFMA: 8 n-tiles per wave, 2 at a time
    for (int i = 0; i < 4; ++i) {
        int nt0 = w * 8 + 2 * i, nt1 = nt0 + 1;
        f32x4 a0 = (f32x4){0.f, 0.f, 0.f, 0.f};
        f32x4 a1 = (f32x4){0.f, 0.f, 0.f, 0.f};
        #pragma unroll
        for (int ks = 0; ks < KS; ++ks) {
            int bi0 = (((b * KS + ks) * 128 + nt0) * 64 + lane) * 8;
            int bi1 = (((b * KS + ks) * 128 + nt1) * 64 + lane) * 8;
            short8 bh0 = *(const short8*)(Bh + bi0);
            short8 bl0 = *(const short8*)(Bl + bi0);
            short8 bh1 = *(const short8*)(Bh + bi1);
            short8 bl1 = *(const short8*)(Bl + bi1);
            a0 = __builtin_amdgcn_mfma_f32_16x16x32_bf16(ah[ks], bh0, a0, 0, 0, 0);
            a1 = __builtin_amdgcn_mfma_f32_16x16x32_bf16(ah[ks], bh1, a1, 0, 0, 0);
            a0 = __builtin_amdgcn_mfma_f32_16x16x32_bf16(ah[ks], bl0, a0, 0, 0, 0);
            a1 = __builtin_amdgcn_mfma_f32_16x16x32_bf16(ah[ks], bl1, a1, 0, 0, 0);
            a0 = __builtin_amdgcn_mfma_f32_16x16x32_bf16(al[ks], bh0, a0, 0, 0, 0);
            a1 = __builtin_amdgcn_mfma_f32_16x16x32_bf16(al[ks], bh1, a1, 0, 0, 0);
        }
        float xn0 = xxg[b * Np + nt0 * 16 + col];
        float xn1 = xxg[b * Np + nt1 * 16 + col];
        #pragma unroll
        for (int r = 0; r < 4; ++r) {
            int m = quad * 4 + r;
            dl[m * SD + nt0 * 16 + col] = 2.f * a0[r] - xmr[r] - xn0;
            dl[m * SD + nt1 * 16 + col] = 2.f * a1[r] - xmr[r] - xn1;
        }
    }
    __syncthreads();

    // ---- selection: wave w owns row w; exact sequential top-32 ----
    const float* drow = dl + w * SD;
    float v[32];
    #pragma unroll
    for (int j = 0; j < 32; ++j) v[j] = drow[lane + 64 * j];
    float gv0, gv1, gv2, gv3;
    int gj0, gj1, gj2, gj3;
    gv0 = v[0]; gj0 = 0;
    #pragma unroll
    for (int e = 1; e < 8; ++e) if (v[e] > gv0) { gv0 = v[e]; gj0 = e; }
    gv1 = v[8]; gj1 = 8;
    #pragma unroll
    for (int e = 1; e < 8; ++e) if (v[8 + e] > gv1) { gv1 = v[8 + e]; gj1 = 8 + e; }
    gv2 = v[16]; gj2 = 16;
    #pragma unroll
    for (int e = 1; e < 8; ++e) if (v[16 + e] > gv2) { gv2 = v[16 + e]; gj2 = 16 + e; }
    gv3 = v[24]; gj3 = 24;
    #pragma unroll
    for (int e = 1; e < 8; ++e) if (v[24 + e] > gv3) { gv3 = v[24 + e]; gj3 = 24 + e; }

    size_t ob = ((size_t)b * Np + n0 + w) * Kn;
    for (int it = 0; it < Kn; ++it) {
        // local pick (strict > keeps lowest j, groups ordered by j)
        float lv = gv0; int lj = gj0;
        if (gv1 > lv) { lv = gv1; lj = gj1; }
        if (gv2 > lv) { lv = gv2; lj = gj2; }
        if (gv3 > lv) { lv = gv3; lj = gj3; }
        float bv = lv;
        int bn = lane + 64 * lj;
        #pragma unroll
        for (int off = 1; off < 64; off <<= 1) {
            float ov = __shfl_xor(bv, off, 64);
            int on = __shfl_xor(bn, off, 64);
            if (ov > bv || (ov == bv && on < bn)) { bv = ov; bn = on; }
        }
        int ns = __builtin_amdgcn_readfirstlane(bn);   // all lanes converged; scalarize
        if (lane == 0) idxo[ob + it] = ns;
        int js = ns >> 6;
        if (lane == (ns & 63)) {
            #pragma unroll
            for (int j = 0; j < 32; ++j) if (j == js) v[j] = -INFINITY;
            int gg = js >> 3;
            if (gg == 0) {
                gv0 = v[0]; gj0 = 0;
                #pragma unroll
                for (int e = 1; e < 8; ++e) if (v[e] > gv0) { gv0 = v[e]; gj0 = e; }
            } else if (gg == 1) {
                gv1 = v[8]; gj1 = 8;
                #pragma unroll
                for (int e = 1; e < 8; ++e) if (v[8 + e] > gv1) { gv1 = v[8 + e]; gj1 = 8 + e; }
            } else if (gg == 2) {
                gv2 = v[16]; gj2 = 16;
                #pragma unroll
                for (int e = 1; e < 8; ++e) if (v[16 + e] > gv2) { gv2 = v[16 + e]; gj2 = 16 + e; }
            } else {
                gv3 = v[24]; gj3 = 24;
                #pragma unroll
                for (int e = 1; e < 8; ++e) if (v[24 + e] > gv3) { gv3 = v[24 + e]; gj3 = 24 + e; }
            }
        }
    }
}

// W split+scale+transpose (fp32, for k_ctr): WdsT[c][o] = (W[o][C+c]-W[o][c])*s[o]
__global__ __launch_bounds__(256) void k_wsplit(const float* __restrict__ W, const float* __restrict__ s,
                                                int C, int O, float* __restrict__ WnsT, float* __restrict__ WdsT) {
    int i = blockIdx.x * 256 + threadIdx.x;
    if (i >= C * O) return;
    int c = i / O, o = i % O;
    float a = W[(size_t)o * 2 * C + c];
    float q = W[(size_t)o * 2 * C + C + c];
    float sv = s[o];
    WnsT[i] = a * sv;
    WdsT[i] = (q - a) * sv;
}

// Pack neighbor-half of W (scaled) into mfma_16x16x32 B-fragment order, split bf16 hi/lo.
__global__ __launch_bounds__(256) void k_wpack(const float* __restrict__ W, const float* __restrict__ s,
                                               int C, int O, ushortT* __restrict__ Bh, ushortT* __restrict__ Bl) {
    int i = blockIdx.x * 256 + threadIdx.x;
    if (i >= C * O) return;
    int k = i / O, o = i % O;
    float v = W[(size_t)o * 2 * C + k] * s[o];
    int ks = k >> 5, quad = (k >> 3) & 3, j = k & 7;
    int nt = o >> 4, lane = quad * 16 + (o & 15);
    int NT = O / 16;
    size_t idx = (((size_t)(ks * NT + nt)) * 64 + lane) * 8 + j;
    unsigned u = __float_as_uint(v);
    Bh[idx] = (ushortT)(u >> 16);
    float r = v - __uint_as_float(u & 0xffff0000u);
    Bl[idx] = (ushortT)(__float_as_uint(r) >> 16);
}

// cb[n][o] = sum_c ctr[n][c]*WdsT[c][o] + b[o].  32 points per block.
template<int C, int O, int OPT>
__global__ __launch_bounds__(256) void k_ctr(const float* __restrict__ Xpm, const float* __restrict__ WdsT,
                                             const float* __restrict__ bg, float* __restrict__ cb) {
    constexpr int OG = O / OPT, MG = 256 / OG, MPT = 32 / MG;
    constexpr int C4 = C / 4;
    __shared__ float xs[32][C];
    int b = blockIdx.x / (Np / 32);
    int n0 = (blockIdx.x % (Np / 32)) * 32;
    int t = threadIdx.x;
    const float4* Xp4 = (const float4*)Xpm;
    for (int e = t; e < 32 * C4; e += 256) {
        int pt = e / C4, c4 = e % C4;
        *(float4*)&xs[pt][4 * c4] = Xp4[((size_t)b * Np + n0 + pt) * C4 + c4];
    }
    __syncthreads();
    int og = t % OG, mg = t / OG;
    int o0 = og * OPT;
    float acc[MPT][OPT] = {};
    for (int c = 0; c < C; ++c) {
        float wv[OPT];
        #pragma unroll
        for (int p4 = 0; p4 < OPT / 4; ++p4)
            *(float4*)&wv[4 * p4] = *(const float4*)&WdsT[(size_t)c * O + o0 + 4 * p4];
        #pragma unroll
        for (int m = 0; m < MPT; ++m) {
            float xv = xs[mg * MPT + m][c];
            #pragma unroll
            for (int p = 0; p < OPT; ++p) acc[m][p] = fmaf(wv[p], xv, acc[m][p]);
        }
    }
    #pragma unroll
    for (int m = 0; m < MPT; ++m) {
        #pragma unroll
        for (int p = 0; p < OPT; ++p) {
            int o = o0 + p;
            cb[((size_t)b * Np + n0 + mg * MPT + m) * O + o] = acc[m][p] + bg[o];
        }
    }
}

// MFMA EdgeConv GEMM (split-bf16), max over k, + center term, lrelu.
template<int C, int O, int PTS>
__global__ __launch_bounds__(256) void k_ec3(const float* __restrict__ Xpm, const int* __restrict__ idxg,
                                             const ushortT* __restrict__ Bh, const ushortT* __restrict__ Bl,
                                             const float* __restrict__ cb,
                                             float* __restrict__ Ypm) {
    static_assert(PTS == 2, "M=64 mapping");
    constexpr int M = 64, NT = O / 16, KS = C / 32, C4 = C / 4, CP = C + 8;
    __shared__ ushortT Ah[M][CP];
    __shared__ ushortT Al[M][CP];
    __shared__ float red[PTS][2][O];
    int b = blockIdx.x / (Np / PTS);
    int n0 = (blockIdx.x % (Np / PTS)) * PTS;
    int t = threadIdx.x;
    const int* ip = idxg + ((size_t)b * Np + n0) * Kn;
    const float4* Xp4 = (const float4*)Xpm;
    for (int e = t; e < M * C4; e += 256) {
        int row = e / C4, c4 = e % C4;
        float4 v = Xp4[((size_t)b * Np + ip[row]) * C4 + c4];
        unsigned h0, l0, h1, l1;
        cvt2u(v.x, v.y, h0, l0);
        cvt2u(v.z, v.w, h1, l1);
        *(uint2*)&Ah[row][4 * c4] = make_uint2(h0, h1);
        *(uint2*)&Al[row][4 * c4] = make_uint2(l0, l1);
    }
    __syncthreads();
    int w = t >> 6, lane = t & 63;
    int quad = lane >> 4, col = lane & 15;
    int mrow = w * 16 + col;
    f32x4 acc[NT];
    #pragma unroll
    for (int nt = 0; nt < NT; ++nt) acc[nt] = (f32x4){0.f, 0.f, 0.f, 0.f};
    for (int ks = 0; ks < KS; ++ks) {
        int kb = ks * 32 + quad * 8;
        short8 ah = *(const short8*)&Ah[mrow][kb];
        short8 al = *(const short8*)&Al[mrow][kb];
        #pragma unroll
        for (int nt = 0; nt < NT; ++nt) {
            size_t bi = (((size_t)(ks * NT + nt)) * 64 + lane) * 8;
            short8 bh = *(const short8*)(Bh + bi);
            short8 bl = *(const short8*)(Bl + bi);
            acc[nt] = __builtin_amdgcn_mfma_f32_16x16x32_bf16(ah, bh, acc[nt], 0, 0, 0);
            acc[nt] = __builtin_amdgcn_mfma_f32_16x16x32_bf16(ah, bl, acc[nt], 0, 0, 0);
            acc[nt] = __builtin_amdgcn_mfma_f32_16x16x32_bf16(al, bh, acc[nt], 0, 0, 0);
        }
    }
    int pt = w >> 1, wi = w & 1;
    #pragma unroll
    for (int nt = 0; nt < NT; ++nt) {
        float m = fmaxf(fmaxf(acc[nt][0], acc[nt][1]), fmaxf(acc[nt][2], acc[nt][3]));
        m = fmaxf(m, __shfl_xor(m, 16, 64));
        m = fmaxf(m, __shfl_xor(m, 32, 64));
        if (lane < 16) red[pt][wi][nt * 16 + col] = m;
    }
    __syncthreads();
    for (int idx = t; idx < PTS * O; idx += 256) {
        int pp = idx / O, o = idx % O;
        float m = fmaxf(red[pp][0][o], red[pp][1][o]);
        size_t ni = (size_t)b * Np + n0 + pp;
        Ypm[ni * O + o] = lrelu(m + cb[ni * O + o]);
    }
}

// Legacy fused EdgeConv for layer 1 (C=3)
template<int C, int CPAD, int O, int OPT, int KPT, int PTS>
__global__ __launch_bounds__(256) void k_edgeconv(
    const float* __restrict__ Xpm, const int* __restrict__ idxg,
    const float* __restrict__ W, const float* __restrict__ sg, const float* __restrict__ bg,
    float* __restrict__ Ypm)
{
    constexpr int OG = O / OPT;
    constexpr int NKG = 256 / OG;
    constexpr int CL = CPAD + 4;
    static_assert(NKG * KPT == Kn, "k mapping");
    __shared__ float nbr[PTS][Kn][CL];
    __shared__ float ctr[PTS][CPAD];
    __shared__ float red[PTS][OPT][4][OG];
    int blk = blockIdx.x;
    int b = blk / (Np / PTS);
    int n0 = (blk % (Np / PTS)) * PTS;
    int t = threadIdx.x;
    int lane = t & 63, wid = t >> 6;
    const int* ip = idxg + ((size_t)b * Np + n0) * Kn;
    const float4* Xp4 = (const float4*)Xpm;
    constexpr int C4 = CPAD / 4;
    for (int e = t; e < PTS * C4; e += 256) {
        int pt = e / C4, c4 = e % C4;
        *(float4*)&ctr[pt][4 * c4] = Xp4[((size_t)b * Np + n0 + pt) * C4 + c4];
    }
    for (int e = t; e < PTS * Kn * C4; e += 256) {
        int pt = e / (Kn * C4);
        int r = e % (Kn * C4);
        int k = r / C4, c4 = r % C4;
        int nb = ip[pt * Kn + k];
        *(float4*)&nbr[pt][k][4 * c4] = Xp4[((size_t)b * Np + nb) * C4 + c4];
    }
    __syncthreads();
    int og = t % OG, kg = t / OG;
    float acc[PTS][OPT][KPT] = {};
    float ctt[PTS][OPT] = {};
    for (int c0 = 0; c0 < CPAD; c0 += 4) {
        float wn[OPT][4], wd[OPT][4];
        #pragma unroll
        for (int p = 0; p < OPT; ++p) {
            #pragma unroll
            for (int cc = 0; cc < 4; ++cc) {
                int c = c0 + cc;
                float a = (c < C) ? W[(size_t)(og + p * OG) * (2 * C) + c] : 0.f;
                float q = (c < C) ? W[(size_t)(og + p * OG) * (2 * C) + C + c] : 0.f;
                wn[p][cc] = a; wd[p][cc] = q - a;
            }
        }
        #pragma unroll
        for (int pt = 0; pt < PTS; ++pt) {
            float4 cv = *(const float4*)&ctr[pt][c0];
            #pragma unroll
            for (int p = 0; p < OPT; ++p) {
                ctt[pt][p] = fmaf(wd[p][0], cv.x, ctt[pt][p]);
                ctt[pt][p] = fmaf(wd[p][1], cv.y, ctt[pt][p]);
                ctt[pt][p] = fmaf(wd[p][2], cv.z, ctt[pt][p]);
                ctt[pt][p] = fmaf(wd[p][3], cv.w, ctt[pt][p]);
            }
        }
        #pragma unroll
        for (int pt = 0; pt < PTS; ++pt) {
            #pragma unroll
            for (int k = 0; k < KPT; ++k) {
                float4 nv = *(const float4*)&nbr[pt][kg * KPT + k][c0];
                #pragma unroll
                for (int p = 0; p < OPT; ++p) {
                    acc[pt][p][k] = fmaf(wn[p][0], nv.x, acc[pt][p][k]);
                    acc[pt][p][k] = fmaf(wn[p][1], nv.y, acc[pt][p][k]);
                    acc[pt][p][k] = fmaf(wn[p][2], nv.z, acc[pt][p][k]);
                    acc[pt][p][k] = fmaf(wn[p][3], nv.w, acc[pt][p][k]);
                }
            }
        }
    }
    #pragma unroll
    for (int pt = 0; pt < PTS; ++pt) {
        #pragma unroll
        for (int p = 0; p < OPT; ++p) {
            int o = og + p * OG;
            float sv = sg[o], bv = bg[o];
            float m = -INFINITY;
            #pragma unroll
            for (int k = 0; k < KPT; ++k) {
                float hv = fmaf(acc[pt][p][k] + ctt[pt][p], sv, bv);
                m = fmaxf(m, lrelu(hv));
            }
            #pragma unroll
            for (int s = OG; s < 64; s <<= 1) m = fmaxf(m, __shfl_xor(m, s, 64));
            if (lane < OG) red[pt][p][wid][lane] = m;
        }
    }
    __syncthreads();
    if (t < OG) {
        #pragma unroll
        for (int pt = 0; pt < PTS; ++pt) {
            #pragma unroll
            for (int p = 0; p < OPT; ++p) {
                float m = fmaxf(fmaxf(red[pt][p][0][t], red[pt][p][1][t]),
                                fmaxf(red[pt][p][2][t], red[pt][p][3][t]));
                int o = t + p * OG;
                Ypm[((size_t)b * Np + n0 + pt) * O + o] = m;
            }
        }
    }
}

// W5 transpose [1024][512] -> [512][1024]
__global__ __launch_bounds__(256) void k_w5t(const float* __restrict__ W5, float* __restrict__ W5t) {
    __shared__ float tile[32][33];
    int o0 = (blockIdx.x & 31) * 32;
    int c0 = (blockIdx.x >> 5) * 32;
    int lr = threadIdx.x >> 5, lc = threadIdx.x & 31;
    #pragma unroll
    for (int j = 0; j < 4; ++j) {
        int r = lr + 8 * j;
        tile[r][lc] = W5[(size_t)(o0 + r) * 512 + c0 + lc];
    }
    __syncthreads();
    #pragma unroll
    for (int j = 0; j < 4; ++j) {
        int r = lr + 8 * j;
        W5t[(size_t)(c0 + r) * 1024 + o0 + lc] = tile[lc][r];
    }
}

// W5 + BN + LeakyReLU + per-block max/sum over 32 points -> partials.
__global__ __launch_bounds__(256) void k_w5pool(
    const float* __restrict__ x1, const float* __restrict__ x2,
    const float* __restrict__ x3, const float* __restrict__ x4,
    const float* __restrict__ W5t, const float* __restrict__ s5, const float* __restrict__ b5,
    float* __restrict__ pmax, float* __restrict__ psum)
{
    constexpr int PP = 16;
    __shared__ float cat[PP][512];
    int blk = blockIdx.x;
    int b = blk >> 6;
    int chunk = blk & 63;
    int n0 = chunk * 32;
    int t = threadIdx.x;
    float mx[4] = {-INFINITY, -INFINITY, -INFINITY, -INFINITY};
    float sm[4] = {};
    for (int pass = 0; pass < 2; ++pass) {
        __syncthreads();
        for (int e = t; e < PP * 128; e += 256) {
            int pt = e >> 7, c4 = e & 127;
            size_t pi = (size_t)b * Np + n0 + pass * PP + pt;
            float4 v;
            if (c4 < 16)      v = ((const float4*)x1)[pi * 16 + c4];
            else if (c4 < 32) v = ((const float4*)x2)[pi * 16 + (c4 - 16)];
            else if (c4 < 64) v = ((const float4*)x3)[pi * 32 + (c4 - 32)];
            else              v = ((const float4*)x4)[pi * 64 + (c4 - 64)];
            *(float4*)&cat[pt][4 * c4] = v;
        }
        __syncthreads();
        float acc[4][PP] = {};
        for (int c0 = 0; c0 < 512; c0 += 4) {
            float wv[4][4];
            #pragma unroll
            for (int j = 0; j < 4; ++j) {
                const float* row = W5t + (size_t)(c0 + j) * 1024 + t;
                #pragma unroll
                for (int r = 0; r < 4; ++r) wv[j][r] = row[256 * r];
            }
            #pragma unroll
            for (int pt = 0; pt < PP; ++pt) {
                float4 cv = *(const float4*)&cat[pt][c0];
                #pragma unroll
                for (int r = 0; r < 4; ++r) {
                    acc[r][pt] = fmaf(wv[0][r], cv.x, acc[r][pt]);
                    acc[r][pt] = fmaf(wv[1][r], cv.y, acc[r][pt]);
                    acc[r][pt] = fmaf(wv[2][r], cv.z, acc[r][pt]);
                    acc[r][pt] = fmaf(wv[3][r], cv.w, acc[r][pt]);
                }
            }
        }
        #pragma unroll
        for (int r = 0; r < 4; ++r) {
            int o = t + 256 * r;
            float sv = s5[o], bv = b5[o];
            #pragma unroll
            for (int pt = 0; pt < PP; ++pt) {
                float v = lrelu(fmaf(acc[r][pt], sv, bv));
                mx[r] = fmaxf(mx[r], v);
                sm[r] += v;
            }
        }
    }
    #pragma unroll
    for (int r = 0; r < 4; ++r) {
        int o = t + 256 * r;
        pmax[((size_t)(b * 64 + chunk)) * 1024 + o] = mx[r];
        psum[((size_t)(b * 64 + chunk)) * 1024 + o] = sm[r];
    }
}

__global__ __launch_bounds__(256) void k_poolred(const float* __restrict__ pmax, const float* __restrict__ psum,
                                                 float* __restrict__ g0) {
    int i = blockIdx.x * 256 + threadIdx.x;
    int b = i >> 10, o = i & 1023;
    float mx = -INFINITY, sm = 0.f;
    for (int ch = 0; ch < 64; ++ch) {
        size_t idx = ((size_t)(b * 64 + ch)) * 1024 + o;
        mx = fmaxf(mx, pmax[idx]);
        sm += psum[idx];
    }
    g0[(size_t)b * 2048 + o] = mx;
    g0[(size_t)b * 2048 + 1024 + o] = sm * (1.f / Np);
}

__global__ __launch_bounds__(256) void k_fc(const float* __restrict__ In, int ldIn, int C,
                                            const float* __restrict__ Wm,
                                            const float* __restrict__ bias,
                                            const float* __restrict__ sc, const float* __restrict__ bnb,
                                            int leaky, float* __restrict__ Out, int ldOut, int O) {
    int wid = threadIdx.x >> 6, lane = threadIdx.x & 63;
    int o = blockIdx.x * 4 + wid;
    int b = blockIdx.y;
    if (o >= O) return;
    const float* in = In + (size_t)b * ldIn;
    const float* wr = Wm + (size_t)o * C;
    float acc = 0.f;
    for (int c = lane; c < C; c += 64) acc = fmaf(in[c], wr[c], acc);
    #pragma unroll
    for (int off = 32; off; off >>= 1) acc += __shfl_down(acc, off, 64);
    if (lane == 0) {
        float v = acc + (bias ? bias[o] : 0.f);
        if (sc) v = fmaf(v, sc[o], bnb[o]);
        if (leaky) v = lrelu(v);
        Out[(size_t)b * ldOut + o] = v;
    }
}

extern "C" void kernel_launch(void* const* d_in, const int* in_sizes, int n_in,
                              void* d_out, int out_size, void* d_ws, size_t ws_size,
                              hipStream_t stream) {
    const float* x   = (const float*)d_in[0];
    const float* W1  = (const float*)d_in[1];
    const float* s1  = (const float*)d_in[2];
    const float* b1  = (const float*)d_in[3];
    const float* W2  = (const float*)d_in[4];
    const float* s2  = (const float*)d_in[5];
    const float* b2  = (const float*)d_in[6];
    const float* W3  = (const float*)d_in[7];
    const float* s3  = (const float*)d_in[8];
    const float* b3  = (const float*)d_in[9];
    const float* W4  = (const float*)d_in[10];
    const float* s4  = (const float*)d_in[11];
    const float* b4  = (const float*)d_in[12];
    const float* W5  = (const float*)d_in[13];
    const float* s5  = (const float*)d_in[14];
    const float* b5  = (const float*)d_in[15];
    const float* L1w = (const float*)d_in[16];
    const float* s6  = (const float*)d_in[17];
    const float* b6  = (const float*)d_in[18];
    const float* L2w = (const float*)d_in[19];
    const float* L2b = (const float*)d_in[20];
    const float* s7  = (const float*)d_in[21];
    const float* b7  = (const float*)d_in[22];
    const float* L3w = (const float*)d_in[23];
    const float* L3b = (const float*)d_in[24];
    const float* F1w = (const float*)d_in[25];
    const float* s8  = (const float*)d_in[26];
    const float* b8  = (const float*)d_in[27];
    const float* F2w = (const float*)d_in[28];
    const float* F2b = (const float*)d_in[29];
    const float* s9  = (const float*)d_in[30];
    const float* b9  = (const float*)d_in[31];
    const float* F3w = (const float*)d_in[32];
    const float* F3b = (const float*)d_in[33];

    float* ws = (float*)d_ws;
    size_t off = 0;
    auto alloc = [&](size_t n) { float* p = ws + off; off += n; return p; };
    float* pts  = alloc((size_t)Bn * Np * 4);
    float* x1   = alloc((size_t)Bn * Np * 64);
    float* x2   = alloc((size_t)Bn * Np * 64);
    float* x3   = alloc((size_t)Bn * Np * 128);
    float* x4   = alloc((size_t)Bn * Np * 256);
    float* xcm  = alloc((size_t)Bn * Np * 128);   // aliased: W5t / pmax / psum
    float* xxb  = alloc((size_t)Bn * Np);
    int*   idxb = (int*)alloc((size_t)Bn * Np * Kn);
    float* g0   = alloc((size_t)Bn * 2048);
    float* g1   = alloc((size_t)Bn * 512);
    float* g2   = alloc((size_t)Bn * 256);
    float* y1   = alloc((size_t)Bn * 512);
    float* y2   = alloc((size_t)Bn * 256);
    float* WnsT2 = alloc(64 * 64);
    float* WdsT2 = alloc(64 * 64);
    float* WnsT3 = alloc(64 * 128);
    float* WdsT3 = alloc(64 * 128);
    float* WnsT4 = alloc(128 * 256);
    float* WdsT4 = alloc(128 * 256);
    ushortT* Bh2 = (ushortT*)alloc(64 * 64 / 2);
    ushortT* Bl2 = (ushortT*)alloc(64 * 64 / 2);
    ushortT* Bh3 = (ushortT*)alloc(64 * 128 / 2);
    ushortT* Bl3 = (ushortT*)alloc(64 * 128 / 2);
    ushortT* Bh4 = (ushortT*)alloc(128 * 256 / 2);
    ushortT* Bl4 = (ushortT*)alloc(128 * 256 / 2);
    ushortT* BhK = (ushortT*)alloc(1048576);   // knn B-frag hi (max C=128: 2M shorts)
    ushortT* BlK = (ushortT*)alloc(1048576);
    float* W5t  = xcm;
    float* pmax = xcm + 524288;
    float* psum = xcm + 1048576;
    float* cb2 = x2;
    float* cb3 = x3;
    float* cb4 = x4;

    // dynamic-LDS opt-in for knn4 (139,968 B max); idempotent, safe pre-capture too
    auto shsz = [](int CP) { return 16 * CP * 2 * 2 + 64 + 16 * 2050 * 4; };
    int sh3 = shsz(40), sh64 = shsz(72), sh128 = shsz(136);
    hipFuncSetAttribute((const void*)k_knn4<3, 32, 4>, hipFuncAttributeMaxDynamicSharedMemorySize, sh3);
    hipFuncSetAttribute((const void*)k_knn4<64, 64, 64>, hipFuncAttributeMaxDynamicSharedMemorySize, sh64);
    hipFuncSetAttribute((const void*)k_knn4<128, 128, 128>, hipFuncAttributeMaxDynamicSharedMemorySize, sh128);

    k_transpose<<<Bn * Np / 256, 256, 0, stream>>>(x, pts);
    k_wsplit<<<16, 256, 0, stream>>>(W2, s2, 64, 64, WnsT2, WdsT2);
    k_wsplit<<<32, 256, 0, stream>>>(W3, s3, 64, 128, WnsT3, WdsT3);
    k_wsplit<<<128, 256, 0, stream>>>(W4, s4, 128, 256, WnsT4, WdsT4);
    k_wpack<<<16, 256, 0, stream>>>(W2, s2, 64, 64, Bh2, Bl2);
    k_wpack<<<32, 256, 0, stream>>>(W3, s3, 64, 128, Bh3, Bl3);
    k_wpack<<<128, 256, 0, stream>>>(W4, s4, 128, 256, Bh4, Bl4);

    // Layer 1: C=3
    k_xx<<<Bn * Np / 4, 256, 0, stream>>>(pts, xxb, 3, 4);
    k_bpack<3, 32, 4><<<2048, 256, 0, stream>>>(pts, BhK, BlK);
    k_knn4<3, 32, 4><<<Bn * Np / 16, 1024, sh3, stream>>>(pts, BhK, BlK, xxb, idxb);
    k_edgeconv<3, 4, 64, 1, 8, 4><<<Bn * Np / 4, 256, 0, stream>>>(pts, idxb, W1, s1, b1, x1);

    // Layer 2: C=64 -> O=64
    k_xx<<<Bn * Np / 4, 256, 0, stream>>>(x1, xxb, 64, 64);
    k_bpack<64, 64, 64><<<4096, 256, 0, stream>>>(x1, BhK, BlK);
    k_knn4<64, 64, 64><<<Bn * Np / 16, 1024, sh64, stream>>>(x1, BhK, BlK, xxb, idxb);
    k_ctr<64, 64, 4><<<Bn * Np / 32, 256, 0, stream>>>(x1, WdsT2, b2, cb2);
    k_ec3<64, 64, 2><<<Bn * Np / 2, 256, 0, stream>>>(x1, idxb, Bh2, Bl2, cb2, x2);

    // Layer 3: C=64 -> O=128
    k_xx<<<Bn * Np / 4, 256, 0, stream>>>(x2, xxb, 64, 64);
    k_bpack<64, 64, 64><<<4096, 256, 0, stream>>>(x2, BhK, BlK);
    k_knn4<64, 64, 64><<<Bn * Np / 16, 1024, sh64, stream>>>(x2, BhK, BlK, xxb, idxb);
    k_ctr<64, 128, 8><<<Bn * Np / 32, 256, 0, stream>>>(x2, WdsT3, b3, cb3);
    k_ec3<64, 128, 2><<<Bn * Np / 2, 256, 0, stream>>>(x2, idxb, Bh3, Bl3, cb3, x3);

    // Layer 4: C=128 -> O=256
    k_xx<<<Bn * Np / 4, 256, 0, stream>>>(x3, xxb, 128, 128);
    k_bpack<128, 128, 128><<<8192, 256, 0, stream>>>(x3, BhK, BlK);
    k_knn4<128, 128, 128><<<Bn * Np / 16, 1024, sh128, stream>>>(x3, BhK, BlK, xxb, idxb);
    k_w5t<<<512, 256, 0, stream>>>(W5, W5t);
    k_ctr<128, 256, 8><<<Bn * Np / 32, 256, 0, stream>>>(x3, WdsT4, b4, cb4);
    k_ec3<128, 256, 2><<<Bn * Np / 2, 256, 0, stream>>>(x3, idxb, Bh4, Bl4, cb4, x4);

    // W5 + pooling
    k_w5pool<<<Bn * 64, 256, 0, stream>>>(x1, x2, x3, x4, W5t, s5, b5, pmax, psum);
    k_poolred<<<Bn * 1024 / 256, 256, 0, stream>>>(pmax, psum, g0);

    float* out = (float*)d_out;
    k_fc<<<dim3(128, Bn), 256, 0, stream>>>(g0, 2048, 2048, L1w, nullptr, s6, b6, 1, g1, 512, 512);
    k_fc<<<dim3(64, Bn), 256, 0, stream>>>(g1, 512, 512, L2w, L2b, s7, b7, 1, g2, 256, 256);
    k_fc<<<dim3(2, Bn), 256, 0, stream>>>(g2, 256, 256, L3w, L3b, nullptr, nullptr, 0, out, 5, 5);
    k_fc<<<dim3(128, Bn), 256, 0, stream>>>(g0, 2048, 1024, F1w, nullptr, s8, b8, 1, y1, 512, 512);
    k_fc<<<dim3(64, Bn), 256, 0, stream>>>(y1, 512, 512, F2w, F2b, s9, b9, 1, y2, 256, 256);
    k_fc<<<dim3(2, Bn), 256, 0, stream>>>(y2, 256, 256, F3w, F3b, nullptr, nullptr, 0, out + 40, 5, 5);
}

// Round 8
// 1652.367 us; speedup vs baseline: 2.6000x; 1.0462x over previous
//
#include <hip/hip_runtime.h>
#include <math.h>

constexpr int Bn = 8;
constexpr int Np = 2048;
constexpr int Kn = 32;
constexpr float NEGS = 0.2f;

typedef __attribute__((ext_vector_type(8))) short short8;
typedef __attribute__((ext_vector_type(4))) float f32x4;
typedef unsigned short ushortT;

__device__ __forceinline__ float lrelu(float v) { return v > 0.f ? v : NEGS * v; }

// split fp32 -> bf16 hi (truncate) + bf16 lo (residual, truncate); packed 2-at-a-time
__device__ __forceinline__ void cvt2u(float a, float b, unsigned& h, unsigned& l) {
    unsigned ua = __float_as_uint(a), ub = __float_as_uint(b);
    h = (ua >> 16) | (ub & 0xffff0000u);
    float ra = a - __uint_as_float(ua & 0xffff0000u);
    float rb = b - __uint_as_float(ub & 0xffff0000u);
    l = (__float_as_uint(ra) >> 16) | (__float_as_uint(rb) & 0xffff0000u);
}

// x [B,3,N] -> pts point-major [B*N, 4] (pad lane = 0)
__global__ __launch_bounds__(256) void k_transpose(const float* __restrict__ x, float* __restrict__ pts) {
    int i = blockIdx.x * 256 + threadIdx.x;
    int b = i / Np, n = i % Np;
    float p0 = x[((size_t)b * 3 + 0) * Np + n];
    float p1 = x[((size_t)b * 3 + 1) * Np + n];
    float p2 = x[((size_t)b * 3 + 2) * Np + n];
    float4 v = make_float4(p0, p1, p2, 0.f);
    *(float4*)&pts[(size_t)i * 4] = v;
}

// xx[i] = sum_c pm[i*ld+c]^2 ; one wave per point, 4 points per block
__global__ __launch_bounds__(256) void k_xx(const float* __restrict__ pm, float* __restrict__ xxg, int C, int ld) {
    int wid = threadIdx.x >> 6, lane = threadIdx.x & 63;
    int pt = blockIdx.x * 4 + wid;
    const float* row = pm + (size_t)pt * ld;
    float acc = 0.f;
    for (int c = lane; c < C; c += 64) { float v = row[c]; acc = fmaf(v, v, acc); }
    #pragma unroll
    for (int off = 32; off; off >>= 1) acc += __shfl_down(acc, off, 64);
    if (lane == 0) xxg[pt] = acc;
}

// Pack points into mfma_16x16x32 B-fragment order (bf16 hi/lo), per batch.
template<int C, int CK, int LD>
__global__ __launch_bounds__(256) void k_bpack(const float* __restrict__ Xpm,
                                               ushortT* __restrict__ Bh, ushortT* __restrict__ Bl) {
    constexpr int KS = CK / 32;
    int i = blockIdx.x * 256 + threadIdx.x;
    int j = i & 7;
    int lane = (i >> 3) & 63;
    int nt = (i >> 9) & 127;
    int rest = i >> 16;
    int ks = rest % KS;
    int b = rest / KS;
    int k = ks * 32 + (lane >> 4) * 8 + j;
    int n = nt * 16 + (lane & 15);
    float v = (k < C) ? Xpm[((size_t)b * Np + n) * LD + k] : 0.f;
    unsigned u = __float_as_uint(v);
    Bh[i] = (ushortT)(u >> 16);
    float r = v - __uint_as_float(u & 0xffff0000u);
    Bl[i] = (ushortT)(__float_as_uint(r) >> 16);
}

// MFMA kNN v4 (passing, unchanged from round 7)
template<int C, int CK, int LD>
__global__ __launch_bounds__(1024) void k_knn4(const float* __restrict__ Xpm,
                                               const ushortT* __restrict__ Bh, const ushortT* __restrict__ Bl,
                                               const float* __restrict__ xxg, int* __restrict__ idxo) {
    constexpr int KS = CK / 32, CP = CK + 8, CK4 = CK / 4, C4src = LD / 4;
    constexpr int SD = 2050;
    extern __shared__ char smem[];
    ushortT* Ah = (ushortT*)smem;              // [16][CP]
    ushortT* Al = Ah + 16 * CP;                // [16][CP]
    float* xxm = (float*)(Al + 16 * CP);       // [16]
    float* dl = xxm + 16;                      // [16][SD] distances
    int b = blockIdx.x / (Np / 16);
    int n0 = (blockIdx.x % (Np / 16)) * 16;
    int t = threadIdx.x;
    const float4* Xp4 = (const float4*)Xpm;
    for (int e = t; e < 16 * CK4; e += 1024) {
        int r = e / CK4, c4 = e % CK4;
        float4 v = (c4 < C4src) ? Xp4[((size_t)b * Np + n0 + r) * C4src + c4] : make_float4(0.f, 0.f, 0.f, 0.f);
        unsigned h0, l0, h1, l1;
        cvt2u(v.x, v.y, h0, l0);
        cvt2u(v.z, v.w, h1, l1);
        *(uint2*)&Ah[r * CP + 4 * c4] = make_uint2(h0, h1);
        *(uint2*)&Al[r * CP + 4 * c4] = make_uint2(l0, l1);
    }
    if (t < 16) xxm[t] = xxg[b * Np + n0 + t];
    __syncthreads();

    int w = t >> 6, lane = t & 63;
    int quad = lane >> 4, col = lane & 15;
    short8 ah[KS], al[KS];
    #pragma unroll
    for (int ks = 0; ks < KS; ++ks) {
        ah[ks] = *(const short8*)&Ah[col * CP + ks * 32 + quad * 8];
        al[ks] = *(const short8*)&Al[col * CP + ks * 32 + quad * 8];
    }
    float xmr[4];
    #pragma unroll
    for (int r = 0; r < 4; ++r) xmr[r] = xxm[quad * 4 + r];

    for (int i = 0; i < 4; ++i) {
        int nt0 = w * 8 + 2 * i, nt1 = nt0 + 1;
        f32x4 a0 = (f32x4){0.f, 0.f, 0.f, 0.f};
        f32x4 a1 = (f32x4){0.f, 0.f, 0.f, 0.f};
        #pragma unroll
        for (int ks = 0; ks < KS; ++ks) {
            int bi0 = (((b * KS + ks) * 128 + nt0) * 64 + lane) * 8;
            int bi1 = (((b * KS + ks) * 128 + nt1) * 64 + lane) * 8;
            short8 bh0 = *(const short8*)(Bh + bi0);
            short8 bl0 = *(const short8*)(Bl + bi0);
            short8 bh1 = *(const short8*)(Bh + bi1);
            short8 bl1 = *(const short8*)(Bl + bi1);
            a0 = __builtin_amdgcn_mfma_f32_16x16x32_bf16(ah[ks], bh0, a0, 0, 0, 0);
            a1 = __builtin_amdgcn_mfma_f32_16x16x32_bf16(ah[ks], bh1, a1, 0, 0, 0);
            a0 = __builtin_amdgcn_mfma_f32_16x16x32_bf16(ah[ks], bl0, a0, 0, 0, 0);
            a1 = __builtin_amdgcn_mfma_f32_16x16x32_bf16(ah[ks], bl1, a1, 0, 0, 0);
            a0 = __builtin_amdgcn_mfma_f32_16x16x32_bf16(al[ks], bh0, a0, 0, 0, 0);
            a1 = __builtin_amdgcn_mfma_f32_16x16x32_bf16(al[ks], bh1, a1, 0, 0, 0);
        }
        float xn0 = xxg[b * Np + nt0 * 16 + col];
        float xn1 = xxg[b * Np + nt1 * 16 + col];
        #pragma unroll
        for (int r = 0; r < 4; ++r) {
            int m = quad * 4 + r;
            dl[m * SD + nt0 * 16 + col] = 2.f * a0[r] - xmr[r] - xn0;
            dl[m * SD + nt1 * 16 + col] = 2.f * a1[r] - xmr[r] - xn1;
        }
    }
    __syncthreads();

    const float* drow = dl + w * SD;
    float v[32];
    #pragma unroll
    for (int j = 0; j < 32; ++j) v[j] = drow[lane + 64 * j];
    float gv0, gv1, gv2, gv3;
    int gj0, gj1, gj2, gj3;
    gv0 = v[0]; gj0 = 0;
    #pragma unroll
    for (int e = 1; e < 8; ++e) if (v[e] > gv0) { gv0 = v[e]; gj0 = e; }
    gv1 = v[8]; gj1 = 8;
    #pragma unroll
    for (int e = 1; e < 8; ++e) if (v[8 + e] > gv1) { gv1 = v[8 + e]; gj1 = 8 + e; }
    gv2 = v[16]; gj2 = 16;
    #pragma unroll
    for (int e = 1; e < 8; ++e) if (v[16 + e] > gv2) { gv2 = v[16 + e]; gj2 = 16 + e; }
    gv3 = v[24]; gj3 = 24;
    #pragma unroll
    for (int e = 1; e < 8; ++e) if (v[24 + e] > gv3) { gv3 = v[24 + e]; gj3 = 24 + e; }

    size_t ob = ((size_t)b * Np + n0 + w) * Kn;
    for (int it = 0; it < Kn; ++it) {
        float lv = gv0; int lj = gj0;
        if (gv1 > lv) { lv = gv1; lj = gj1; }
        if (gv2 > lv) { lv = gv2; lj = gj2; }
        if (gv3 > lv) { lv = gv3; lj = gj3; }
        float bv = lv;
        int bn = lane + 64 * lj;
        #pragma unroll
        for (int off = 1; off < 64; off <<= 1) {
            float ov = __shfl_xor(bv, off, 64);
            int on = __shfl_xor(bn, off, 64);
            if (ov > bv || (ov == bv && on < bn)) { bv = ov; bn = on; }
        }
        int ns = __builtin_amdgcn_readfirstlane(bn);
        if (lane == 0) idxo[ob + it] = ns;
        int js = ns >> 6;
        if (lane == (ns & 63)) {
            #pragma unroll
            for (int j = 0; j < 32; ++j) if (j == js) v[j] = -INFINITY;
            int gg = js >> 3;
            if (gg == 0) {
                gv0 = v[0]; gj0 = 0;
                #pragma unroll
                for (int e = 1; e < 8; ++e) if (v[e] > gv0) { gv0 = v[e]; gj0 = e; }
            } else if (gg == 1) {
                gv1 = v[8]; gj1 = 8;
                #pragma unroll
                for (int e = 1; e < 8; ++e) if (v[8 + e] > gv1) { gv1 = v[8 + e]; gj1 = 8 + e; }
            } else if (gg == 2) {
                gv2 = v[16]; gj2 = 16;
                #pragma unroll
                for (int e = 1; e < 8; ++e) if (v[16 + e] > gv2) { gv2 = v[16 + e]; gj2 = 16 + e; }
            } else {
                gv3 = v[24]; gj3 = 24;
                #pragma unroll
                for (int e = 1; e < 8; ++e) if (v[24 + e] > gv3) { gv3 = v[24 + e]; gj3 = 24 + e; }
            }
        }
    }
}

// W split+scale+transpose (fp32, for k_ctr): WdsT[c][o] = (W[o][C+c]-W[o][c])*s[o]
__global__ __launch_bounds__(256) void k_wsplit(const float* __restrict__ W, const float* __restrict__ s,
                                                int C, int O, float* __restrict__ WnsT, float* __restrict__ WdsT) {
    int i = blockIdx.x * 256 + threadIdx.x;
    if (i >= C * O) return;
    int c = i / O, o = i % O;
    float a = W[(size_t)o * 2 * C + c];
    float q = W[(size_t)o * 2 * C + C + c];
    float sv = s[o];
    WnsT[i] = a * sv;
    WdsT[i] = (q - a) * sv;
}

// Pack neighbor-half of W (scaled) into mfma_16x16x32 B-fragment order, split bf16 hi/lo.
__global__ __launch_bounds__(256) void k_wpack(const float* __restrict__ W, const float* __restrict__ s,
                                               int C, int O, ushortT* __restrict__ Bh, ushortT* __restrict__ Bl) {
    int i = blockIdx.x * 256 + threadIdx.x;
    if (i >= C * O) return;
    int k = i / O, o = i % O;
    float v = W[(size_t)o * 2 * C + k] * s[o];
    int ks = k >> 5, quad = (k >> 3) & 3, j = k & 7;
    int nt = o >> 4, lane = quad * 16 + (o & 15);
    int NT = O / 16;
    size_t idx = (((size_t)(ks * NT + nt)) * 64 + lane) * 8 + j;
    unsigned u = __float_as_uint(v);
    Bh[idx] = (ushortT)(u >> 16);
    float r = v - __uint_as_float(u & 0xffff0000u);
    Bl[idx] = (ushortT)(__float_as_uint(r) >> 16);
}

// Pack W5 (scaled by s5) [1024][512] into fragment order: KS=16, NT=64.
__global__ __launch_bounds__(256) void k_w5pack(const float* __restrict__ W5, const float* __restrict__ s5,
                                                ushortT* __restrict__ Bh, ushortT* __restrict__ Bl) {
    int i = blockIdx.x * 256 + threadIdx.x;   // 512*1024
    int k = i >> 10, o = i & 1023;
    float v = W5[(size_t)o * 512 + k] * s5[o];
    int ks = k >> 5, quad = (k >> 3) & 3, j = k & 7;
    int nt = o >> 4, lane = quad * 16 + (o & 15);
    size_t idx = (((size_t)(ks * 64 + nt)) * 64 + lane) * 8 + j;
    unsigned u = __float_as_uint(v);
    Bh[idx] = (ushortT)(u >> 16);
    float r = v - __uint_as_float(u & 0xffff0000u);
    Bl[idx] = (ushortT)(__float_as_uint(r) >> 16);
}

// cb[n][o] = sum_c ctr[n][c]*WdsT[c][o] + b[o].  32 points per block.
template<int C, int O, int OPT>
__global__ __launch_bounds__(256) void k_ctr(const float* __restrict__ Xpm, const float* __restrict__ WdsT,
                                             const float* __restrict__ bg, float* __restrict__ cb) {
    constexpr int OG = O / OPT, MG = 256 / OG, MPT = 32 / MG;
    constexpr int C4 = C / 4;
    __shared__ float xs[32][C];
    int b = blockIdx.x / (Np / 32);
    int n0 = (blockIdx.x % (Np / 32)) * 32;
    int t = threadIdx.x;
    const float4* Xp4 = (const float4*)Xpm;
    for (int e = t; e < 32 * C4; e += 256) {
        int pt = e / C4, c4 = e % C4;
        *(float4*)&xs[pt][4 * c4] = Xp4[((size_t)b * Np + n0 + pt) * C4 + c4];
    }
    __syncthreads();
    int og = t % OG, mg = t / OG;
    int o0 = og * OPT;
    float acc[MPT][OPT] = {};
    for (int c = 0; c < C; ++c) {
        float wv[OPT];
        #pragma unroll
        for (int p4 = 0; p4 < OPT / 4; ++p4)
            *(float4*)&wv[4 * p4] = *(const float4*)&WdsT[(size_t)c * O + o0 + 4 * p4];
        #pragma unroll
        for (int m = 0; m < MPT; ++m) {
            float xv = xs[mg * MPT + m][c];
            #pragma unroll
            for (int p = 0; p < OPT; ++p) acc[m][p] = fmaf(wv[p], xv, acc[m][p]);
        }
    }
    #pragma unroll
    for (int m = 0; m < MPT; ++m) {
        #pragma unroll
        for (int p = 0; p < OPT; ++p) {
            int o = o0 + p;
            cb[((size_t)b * Np + n0 + mg * MPT + m) * O + o] = acc[m][p] + bg[o];
        }
    }
}

// MFMA EdgeConv GEMM (split-bf16), max over k, + center term, lrelu.
template<int C, int O, int PTS>
__global__ __launch_bounds__(256) void k_ec3(const float* __restrict__ Xpm, const int* __restrict__ idxg,
                                             const ushortT* __restrict__ Bh, const ushortT* __restrict__ Bl,
                                             const float* __restrict__ cb,
                                             float* __restrict__ Ypm) {
    static_assert(PTS == 2, "M=64 mapping");
    constexpr int M = 64, NT = O / 16, KS = C / 32, C4 = C / 4, CP = C + 8;
    __shared__ ushortT Ah[M][CP];
    __shared__ ushortT Al[M][CP];
    __shared__ float red[PTS][2][O];
    int b = blockIdx.x / (Np / PTS);
    int n0 = (blockIdx.x % (Np / PTS)) * PTS;
    int t = threadIdx.x;
    const int* ip = idxg + ((size_t)b * Np + n0) * Kn;
    const float4* Xp4 = (const float4*)Xpm;
    for (int e = t; e < M * C4; e += 256) {
        int row = e / C4, c4 = e % C4;
        float4 v = Xp4[((size_t)b * Np + ip[row]) * C4 + c4];
        unsigned h0, l0, h1, l1;
        cvt2u(v.x, v.y, h0, l0);
        cvt2u(v.z, v.w, h1, l1);
        *(uint2*)&Ah[row][4 * c4] = make_uint2(h0, h1);
        *(uint2*)&Al[row][4 * c4] = make_uint2(l0, l1);
    }
    __syncthreads();
    int w = t >> 6, lane = t & 63;
    int quad = lane >> 4, col = lane & 15;
    int mrow = w * 16 + col;
    f32x4 acc[NT];
    #pragma unroll
    for (int nt = 0; nt < NT; ++nt) acc[nt] = (f32x4){0.f, 0.f, 0.f, 0.f};
    for (int ks = 0; ks < KS; ++ks) {
        int kb = ks * 32 + quad * 8;
        short8 ah = *(const short8*)&Ah[mrow][kb];
        short8 al = *(const short8*)&Al[mrow][kb];
        #pragma unroll
        for (int nt = 0; nt < NT; ++nt) {
            size_t bi = (((size_t)(ks * NT + nt)) * 64 + lane) * 8;
            short8 bh = *(const short8*)(Bh + bi);
            short8 bl = *(const short8*)(Bl + bi);
            acc[nt] = __builtin_amdgcn_mfma_f32_16x16x32_bf16(ah, bh, acc[nt], 0, 0, 0);
            acc[nt] = __builtin_amdgcn_mfma_f32_16x16x32_bf16(ah, bl, acc[nt], 0, 0, 0);
            acc[nt] = __builtin_amdgcn_mfma_f32_16x16x32_bf16(al, bh, acc[nt], 0, 0, 0);
        }
    }
    int pt = w >> 1, wi = w & 1;
    #pragma unroll
    for (int nt = 0; nt < NT; ++nt) {
        float m = fmaxf(fmaxf(acc[nt][0], acc[nt][1]), fmaxf(acc[nt][2], acc[nt][3]));
        m = fmaxf(m, __shfl_xor(m, 16, 64));
        m = fmaxf(m, __shfl_xor(m, 32, 64));
        if (lane < 16) red[pt][wi][nt * 16 + col] = m;
    }
    __syncthreads();
    for (int idx = t; idx < PTS * O; idx += 256) {
        int pp = idx / O, o = idx % O;
        float m = fmaxf(red[pp][0][o], red[pp][1][o]);
        size_t ni = (size_t)b * Np + n0 + pp;
        Ypm[ni * O + o] = lrelu(m + cb[ni * O + o]);
    }
}

// Legacy fused EdgeConv for layer 1 (C=3)
template<int C, int CPAD, int O, int OPT, int KPT, int PTS>
__global__ __launch_bounds__(256) void k_edgeconv(
    const float* __restrict__ Xpm, const int* __restrict__ idxg,
    const float* __restrict__ W, const float* __restrict__ sg, const float* __restrict__ bg,
    float* __restrict__ Ypm)
{
    constexpr int OG = O / OPT;
    constexpr int NKG = 256 / OG;
    constexpr int CL = CPAD + 4;
    static_assert(NKG * KPT == Kn, "k mapping");
    __shared__ float nbr[PTS][Kn][CL];
    __shared__ float ctr[PTS][CPAD];
    __shared__ float red[PTS][OPT][4][OG];
    int blk = blockIdx.x;
    int b = blk / (Np / PTS);
    int n0 = (blk % (Np / PTS)) * PTS;
    int t = threadIdx.x;
    int lane = t & 63, wid = t >> 6;
    const int* ip = idxg + ((size_t)b * Np + n0) * Kn;
    const float4* Xp4 = (const float4*)Xpm;
    constexpr int C4 = CPAD / 4;
    for (int e = t; e < PTS * C4; e += 256) {
        int pt = e / C4, c4 = e % C4;
        *(float4*)&ctr[pt][4 * c4] = Xp4[((size_t)b * Np + n0 + pt) * C4 + c4];
    }
    for (int e = t; e < PTS * Kn * C4; e += 256) {
        int pt = e / (Kn * C4);
        int r = e % (Kn * C4);
        int k = r / C4, c4 = r % C4;
        int nb = ip[pt * Kn + k];
        *(float4*)&nbr[pt][k][4 * c4] = Xp4[((size_t)b * Np + nb) * C4 + c4];
    }
    __syncthreads();
    int og = t % OG, kg = t / OG;
    float acc[PTS][OPT][KPT] = {};
    float ctt[PTS][OPT] = {};
    for (int c0 = 0; c0 < CPAD; c0 += 4) {
        float wn[OPT][4], wd[OPT][4];
        #pragma unroll
        for (int p = 0; p < OPT; ++p) {
            #pragma unroll
            for (int cc = 0; cc < 4; ++cc) {
                int c = c0 + cc;
                float a = (c < C) ? W[(size_t)(og + p * OG) * (2 * C) + c] : 0.f;
                float q = (c < C) ? W[(size_t)(og + p * OG) * (2 * C) + C + c] : 0.f;
                wn[p][cc] = a; wd[p][cc] = q - a;
            }
        }
        #pragma unroll
        for (int pt = 0; pt < PTS; ++pt) {
            float4 cv = *(const float4*)&ctr[pt][c0];
            #pragma unroll
            for (int p = 0; p < OPT; ++p) {
                ctt[pt][p] = fmaf(wd[p][0], cv.x, ctt[pt][p]);
                ctt[pt][p] = fmaf(wd[p][1], cv.y, ctt[pt][p]);
                ctt[pt][p] = fmaf(wd[p][2], cv.z, ctt[pt][p]);
                ctt[pt][p] = fmaf(wd[p][3], cv.w, ctt[pt][p]);
            }
        }
        #pragma unroll
        for (int pt = 0; pt < PTS; ++pt) {
            #pragma unroll
            for (int k = 0; k < KPT; ++k) {
                float4 nv = *(const float4*)&nbr[pt][kg * KPT + k][c0];
                #pragma unroll
                for (int p = 0; p < OPT; ++p) {
                    acc[pt][p][k] = fmaf(wn[p][0], nv.x, acc[pt][p][k]);
                    acc[pt][p][k] = fmaf(wn[p][1], nv.y, acc[pt][p][k]);
                    acc[pt][p][k] = fmaf(wn[p][2], nv.z, acc[pt][p][k]);
                    acc[pt][p][k] = fmaf(wn[p][3], nv.w, acc[pt][p][k]);
                }
            }
        }
    }
    #pragma unroll
    for (int pt = 0; pt < PTS; ++pt) {
        #pragma unroll
        for (int p = 0; p < OPT; ++p) {
            int o = og + p * OG;
            float sv = sg[o], bv = bg[o];
            float m = -INFINITY;
            #pragma unroll
            for (int k = 0; k < KPT; ++k) {
                float hv = fmaf(acc[pt][p][k] + ctt[pt][p], sv, bv);
                m = fmaxf(m, lrelu(hv));
            }
            #pragma unroll
            for (int s = OG; s < 64; s <<= 1) m = fmaxf(m, __shfl_xor(m, s, 64));
            if (lane < OG) red[pt][p][wid][lane] = m;
        }
    }
    __syncthreads();
    if (t < OG) {
        #pragma unroll
        for (int pt = 0; pt < PTS; ++pt) {
            #pragma unroll
            for (int p = 0; p < OPT; ++p) {
                float m = fmaxf(fmaxf(red[pt][p][0][t], red[pt][p][1][t]),
                                fmaxf(red[pt][p][2][t], red[pt][p][3][t]));
                int o = t + p * OG;
                Ypm[((size_t)b * Np + n0 + pt) * O + o] = m;
            }
        }
    }
}

// MFMA W5 (K=512, O=1024) + bias + LeakyReLU + max/sum pool over 32 points -> partials [64 chunks].
// 4 waves; wave w owns o-tiles [w*16, w*16+16), loops over them (acc stays 8 VGPRs).
__global__ __launch_bounds__(256) void k_w5mfma(
    const float* __restrict__ x1, const float* __restrict__ x2,
    const float* __restrict__ x3, const float* __restrict__ x4,
    const ushortT* __restrict__ Bh, const ushortT* __restrict__ Bl,
    const float* __restrict__ b5,
    float* __restrict__ pmax, float* __restrict__ psum)
{
    constexpr int CP = 520;                 // 512 + 8 pad
    extern __shared__ char smem[];
    ushortT* Ah = (ushortT*)smem;           // [32][CP]
    ushortT* Al = Ah + 32 * CP;             // [32][CP]
    int b = blockIdx.x >> 6;
    int chunk = blockIdx.x & 63;
    int n0 = chunk * 32;
    int t = threadIdx.x;
    for (int e = t; e < 32 * 128; e += 256) {
        int pt = e >> 7, c4 = e & 127;
        size_t pi = (size_t)b * Np + n0 + pt;
        float4 v;
        if (c4 < 16)      v = ((const float4*)x1)[pi * 16 + c4];
        else if (c4 < 32) v = ((const float4*)x2)[pi * 16 + (c4 - 16)];
        else if (c4 < 64) v = ((const float4*)x3)[pi * 32 + (c4 - 32)];
        else              v = ((const float4*)x4)[pi * 64 + (c4 - 64)];
        unsigned h0, l0, h1, l1;
        cvt2u(v.x, v.y, h0, l0);
        cvt2u(v.z, v.w, h1, l1);
        *(uint2*)&Ah[pt * CP + 4 * c4] = make_uint2(h0, h1);
        *(uint2*)&Al[pt * CP + 4 * c4] = make_uint2(l0, l1);
    }
    __syncthreads();
    int w = t >> 6, lane = t & 63;
    int quad = lane >> 4, col = lane & 15;
    size_t pb = ((size_t)(b * 64 + chunk)) * 1024;
    for (int oi = 0; oi < 16; ++oi) {
        int nt = w * 16 + oi;
        f32x4 a0 = (f32x4){0.f, 0.f, 0.f, 0.f};
        f32x4 a1 = (f32x4){0.f, 0.f, 0.f, 0.f};
        for (int ks = 0; ks < 16; ++ks) {
            size_t bi = (((size_t)(ks * 64 + nt)) * 64 + lane) * 8;
            short8 bh = *(const short8*)(Bh + bi);
            short8 bl = *(const short8*)(Bl + bi);
            int ao = ks * 32 + quad * 8;
            short8 ah0 = *(const short8*)&Ah[col * CP + ao];
            short8 al0 = *(const short8*)&Al[col * CP + ao];
            short8 ah1 = *(const short8*)&Ah[(16 + col) * CP + ao];
            short8 al1 = *(const short8*)&Al[(16 + col) * CP + ao];
            a0 = __builtin_amdgcn_mfma_f32_16x16x32_bf16(ah0, bh, a0, 0, 0, 0);
            a1 = __builtin_amdgcn_mfma_f32_16x16x32_bf16(ah1, bh, a1, 0, 0, 0);
            a0 = __builtin_amdgcn_mfma_f32_16x16x32_bf16(ah0, bl, a0, 0, 0, 0);
            a1 = __builtin_amdgcn_mfma_f32_16x16x32_bf16(ah1, bl, a1, 0, 0, 0);
            a0 = __builtin_amdgcn_mfma_f32_16x16x32_bf16(al0, bh, a0, 0, 0, 0);
            a1 = __builtin_amdgcn_mfma_f32_16x16x32_bf16(al1, bh, a1, 0, 0, 0);
        }
        float bb = b5[nt * 16 + col];
        float mx = -INFINITY, sm = 0.f;
        #pragma unroll
        for (int r = 0; r < 4; ++r) {
            float v0 = lrelu(a0[r] + bb);
            float v1 = lrelu(a1[r] + bb);
            mx = fmaxf(mx, fmaxf(v0, v1));
            sm += v0 + v1;
        }
        mx = fmaxf(mx, __shfl_xor(mx, 16, 64));
        mx = fmaxf(mx, __shfl_xor(mx, 32, 64));
        sm += __shfl_xor(sm, 16, 64);
        sm += __shfl_xor(sm, 32, 64);
        if (lane < 16) {
            pmax[pb + nt * 16 + col] = mx;
            psum[pb + nt * 16 + col] = sm;
        }
    }
}

__global__ __launch_bounds__(256) void k_poolred(const float* __restrict__ pmax, const float* __restrict__ psum,
                                                 float* __restrict__ g0) {
    int i = blockIdx.x * 256 + threadIdx.x;
    int b = i >> 10, o = i & 1023;
    float mx = -INFINITY, sm = 0.f;
    for (int ch = 0; ch < 64; ++ch) {
        size_t idx = ((size_t)(b * 64 + ch)) * 1024 + o;
        mx = fmaxf(mx, pmax[idx]);
        sm += psum[idx];
    }
    g0[(size_t)b * 2048 + o] = mx;
    g0[(size_t)b * 2048 + 1024 + o] = sm * (1.f / Np);
}

__global__ __launch_bounds__(256) void k_fc(const float* __restrict__ In, int ldIn, int C,
                                            const float* __restrict__ Wm,
                                            const float* __restrict__ bias,
                                            const float* __restrict__ sc, const float* __restrict__ bnb,
                                            int leaky, float* __restrict__ Out, int ldOut, int O) {
    int wid = threadIdx.x >> 6, lane = threadIdx.x & 63;
    int o = blockIdx.x * 4 + wid;
    int b = blockIdx.y;
    if (o >= O) return;
    const float* in = In + (size_t)b * ldIn;
    const float* wr = Wm + (size_t)o * C;
    float acc = 0.f;
    for (int c = lane; c < C; c += 64) acc = fmaf(in[c], wr[c], acc);
    #pragma unroll
    for (int off = 32; off; off >>= 1) acc += __shfl_down(acc, off, 64);
    if (lane == 0) {
        float v = acc + (bias ? bias[o] : 0.f);
        if (sc) v = fmaf(v, sc[o], bnb[o]);
        if (leaky) v = lrelu(v);
        Out[(size_t)b * ldOut + o] = v;
    }
}

extern "C" void kernel_launch(void* const* d_in, const int* in_sizes, int n_in,
                              void* d_out, int out_size, void* d_ws, size_t ws_size,
                              hipStream_t stream) {
    const float* x   = (const float*)d_in[0];
    const float* W1  = (const float*)d_in[1];
    const float* s1  = (const float*)d_in[2];
    const float* b1  = (const float*)d_in[3];
    const float* W2  = (const float*)d_in[4];
    const float* s2  = (const float*)d_in[5];
    const float* b2  = (const float*)d_in[6];
    const float* W3  = (const float*)d_in[7];
    const float* s3  = (const float*)d_in[8];
    const float* b3  = (const float*)d_in[9];
    const float* W4  = (const float*)d_in[10];
    const float* s4  = (const float*)d_in[11];
    const float* b4  = (const float*)d_in[12];
    const float* W5  = (const float*)d_in[13];
    const float* s5  = (const float*)d_in[14];
    const float* b5  = (const float*)d_in[15];
    const float* L1w = (const float*)d_in[16];
    const float* s6  = (const float*)d_in[17];
    const float* b6  = (const float*)d_in[18];
    const float* L2w = (const float*)d_in[19];
    const float* L2b = (const float*)d_in[20];
    const float* s7  = (const float*)d_in[21];
    const float* b7  = (const float*)d_in[22];
    const float* L3w = (const float*)d_in[23];
    const float* L3b = (const float*)d_in[24];
    const float* F1w = (const float*)d_in[25];
    const float* s8  = (const float*)d_in[26];
    const float* b8  = (const float*)d_in[27];
    const float* F2w = (const float*)d_in[28];
    const float* F2b = (const float*)d_in[29];
    const float* s9  = (const float*)d_in[30];
    const float* b9  = (const float*)d_in[31];
    const float* F3w = (const float*)d_in[32];
    const float* F3b = (const float*)d_in[33];

    float* ws = (float*)d_ws;
    size_t off = 0;
    auto alloc = [&](size_t n) { float* p = ws + off; off += n; return p; };
    float* pts  = alloc((size_t)Bn * Np * 4);
    float* x1   = alloc((size_t)Bn * Np * 64);
    float* x2   = alloc((size_t)Bn * Np * 64);
    float* x3   = alloc((size_t)Bn * Np * 128);
    float* x4   = alloc((size_t)Bn * Np * 256);
    float* xcm  = alloc((size_t)Bn * Np * 128);   // aliased: pmax / psum
    float* xxb  = alloc((size_t)Bn * Np);
    int*   idxb = (int*)alloc((size_t)Bn * Np * Kn);
    float* g0   = alloc((size_t)Bn * 2048);
    float* g1   = alloc((size_t)Bn * 512);
    float* g2   = alloc((size_t)Bn * 256);
    float* y1   = alloc((size_t)Bn * 512);
    float* y2   = alloc((size_t)Bn * 256);
    float* WnsT2 = alloc(64 * 64);
    float* WdsT2 = alloc(64 * 64);
    float* WnsT3 = alloc(64 * 128);
    float* WdsT3 = alloc(64 * 128);
    float* WnsT4 = alloc(128 * 256);
    float* WdsT4 = alloc(128 * 256);
    ushortT* Bh2 = (ushortT*)alloc(64 * 64 / 2);
    ushortT* Bl2 = (ushortT*)alloc(64 * 64 / 2);
    ushortT* Bh3 = (ushortT*)alloc(64 * 128 / 2);
    ushortT* Bl3 = (ushortT*)alloc(64 * 128 / 2);
    ushortT* Bh4 = (ushortT*)alloc(128 * 256 / 2);
    ushortT* Bl4 = (ushortT*)alloc(128 * 256 / 2);
    ushortT* BhK = (ushortT*)alloc(1048576);   // knn B-frag hi (max C=128: 2M shorts)
    ushortT* BlK = (ushortT*)alloc(1048576);
    ushortT* Bh5 = (ushortT*)alloc(262144);    // W5 frag hi: 512K shorts
    ushortT* Bl5 = (ushortT*)alloc(262144);
    float* pmax = xcm;
    float* psum = xcm + 524288;
    float* cb2 = x2;
    float* cb3 = x3;
    float* cb4 = x4;

    // dynamic-LDS opt-ins (idempotent, safe pre-capture)
    auto shsz = [](int CP) { return 16 * CP * 2 * 2 + 64 + 16 * 2050 * 4; };
    int sh3 = shsz(40), sh64 = shsz(72), sh128 = shsz(136);
    int shw5 = 32 * 520 * 2 * 2;
    hipFuncSetAttribute((const void*)k_knn4<3, 32, 4>, hipFuncAttributeMaxDynamicSharedMemorySize, sh3);
    hipFuncSetAttribute((const void*)k_knn4<64, 64, 64>, hipFuncAttributeMaxDynamicSharedMemorySize, sh64);
    hipFuncSetAttribute((const void*)k_knn4<128, 128, 128>, hipFuncAttributeMaxDynamicSharedMemorySize, sh128);
    hipFuncSetAttribute((const void*)k_w5mfma, hipFuncAttributeMaxDynamicSharedMemorySize, shw5);

    k_transpose<<<Bn * Np / 256, 256, 0, stream>>>(x, pts);
    k_wsplit<<<16, 256, 0, stream>>>(W2, s2, 64, 64, WnsT2, WdsT2);
    k_wsplit<<<32, 256, 0, stream>>>(W3, s3, 64, 128, WnsT3, WdsT3);
    k_wsplit<<<128, 256, 0, stream>>>(W4, s4, 128, 256, WnsT4, WdsT4);
    k_wpack<<<16, 256, 0, stream>>>(W2, s2, 64, 64, Bh2, Bl2);
    k_wpack<<<32, 256, 0, stream>>>(W3, s3, 64, 128, Bh3, Bl3);
    k_wpack<<<128, 256, 0, stream>>>(W4, s4, 128, 256, Bh4, Bl4);
    k_w5pack<<<2048, 256, 0, stream>>>(W5, s5, Bh5, Bl5);

    // Layer 1: C=3
    k_xx<<<Bn * Np / 4, 256, 0, stream>>>(pts, xxb, 3, 4);
    k_bpack<3, 32, 4><<<2048, 256, 0, stream>>>(pts, BhK, BlK);
    k_knn4<3, 32, 4><<<Bn * Np / 16, 1024, sh3, stream>>>(pts, BhK, BlK, xxb, idxb);
    k_edgeconv<3, 4, 64, 1, 8, 4><<<Bn * Np / 4, 256, 0, stream>>>(pts, idxb, W1, s1, b1, x1);

    // Layer 2: C=64 -> O=64
    k_xx<<<Bn * Np / 4, 256, 0, stream>>>(x1, xxb, 64, 64);
    k_bpack<64, 64, 64><<<4096, 256, 0, stream>>>(x1, BhK, BlK);
    k_knn4<64, 64, 64><<<Bn * Np / 16, 1024, sh64, stream>>>(x1, BhK, BlK, xxb, idxb);
    k_ctr<64, 64, 4><<<Bn * Np / 32, 256, 0, stream>>>(x1, WdsT2, b2, cb2);
    k_ec3<64, 64, 2><<<Bn * Np / 2, 256, 0, stream>>>(x1, idxb, Bh2, Bl2, cb2, x2);

    // Layer 3: C=64 -> O=128
    k_xx<<<Bn * Np / 4, 256, 0, stream>>>(x2, xxb, 64, 64);
    k_bpack<64, 64, 64><<<4096, 256, 0, stream>>>(x2, BhK, BlK);
    k_knn4<64, 64, 64><<<Bn * Np / 16, 1024, sh64, stream>>>(x2, BhK, BlK, xxb, idxb);
    k_ctr<64, 128, 8><<<Bn * Np / 32, 256, 0, stream>>>(x2, WdsT3, b3, cb3);
    k_ec3<64, 128, 2><<<Bn * Np / 2, 256, 0, stream>>>(x2, idxb, Bh3, Bl3, cb3, x3);

    // Layer 4: C=128 -> O=256
    k_xx<<<Bn * Np / 4, 256, 0, stream>>>(x3, xxb, 128, 128);
    k_bpack<128, 128, 128><<<8192, 256, 0, stream>>>(x3, BhK, BlK);
    k_knn4<128, 128, 128><<<Bn * Np / 16, 1024, sh128, stream>>>(x3, BhK, BlK, xxb, idxb);
    k_ctr<128, 256, 8><<<Bn * Np / 32, 256, 0, stream>>>(x3, WdsT4, b4, cb4);
    k_ec3<128, 256, 2><<<Bn * Np / 2, 256, 0, stream>>>(x3, idxb, Bh4, Bl4, cb4, x4);

    // W5 + pooling (MFMA)
    k_w5mfma<<<Bn * 64, 256, shw5, stream>>>(x1, x2, x3, x4, Bh5, Bl5, b5, pmax, psum);
    k_poolred<<<Bn * 1024 / 256, 256, 0, stream>>>(pmax, psum, g0);

    float* out = (float*)d_out;
    k_fc<<<dim3(128, Bn), 256, 0, stream>>>(g0, 2048, 2048, L1w, nullptr, s6, b6, 1, g1, 512, 512);
    k_fc<<<dim3(64, Bn), 256, 0, stream>>>(g1, 512, 512, L2w, L2b, s7, b7, 1, g2, 256, 256);
    k_fc<<<dim3(2, Bn), 256, 0, stream>>>(g2, 256, 256, L3w, L3b, nullptr, nullptr, 0, out, 5, 5);
    k_fc<<<dim3(128, Bn), 256, 0, stream>>>(g0, 2048, 1024, F1w, nullptr, s8, b8, 1, y1, 512, 512);
    k_fc<<<dim3(64, Bn), 256, 0, stream>>>(y1, 512, 512, F2w, F2b, s9, b9, 1, y2, 256, 256);
    k_fc<<<dim3(2, Bn), 256, 0, stream>>>(y2, 256, 256, F3w, F3b, nullptr, nullptr, 0, out + 40, 5, 5);
}

// Round 9
// 1190.680 us; speedup vs baseline: 3.6081x; 1.3878x over previous
//
#include <hip/hip_runtime.h>
#include <math.h>

constexpr int Bn = 8;
constexpr int Np = 2048;
constexpr int Kn = 32;
constexpr float NEGS = 0.2f;

typedef __attribute__((ext_vector_type(8))) short short8;
typedef __attribute__((ext_vector_type(4))) float f32x4;
typedef unsigned short ushortT;

__device__ __forceinline__ float lrelu(float v) { return v > 0.f ? v : NEGS * v; }

// split fp32 -> bf16 hi (truncate) + bf16 lo (residual, truncate); packed 2-at-a-time
__device__ __forceinline__ void cvt2u(float a, float b, unsigned& h, unsigned& l) {
    unsigned ua = __float_as_uint(a), ub = __float_as_uint(b);
    h = (ua >> 16) | (ub & 0xffff0000u);
    float ra = a - __uint_as_float(ua & 0xffff0000u);
    float rb = b - __uint_as_float(ub & 0xffff0000u);
    l = (__float_as_uint(ra) >> 16) | (__float_as_uint(rb) & 0xffff0000u);
}

// x [B,3,N] -> pts point-major [B*N, 4] (pad lane = 0)
__global__ __launch_bounds__(256) void k_transpose(const float* __restrict__ x, float* __restrict__ pts) {
    int i = blockIdx.x * 256 + threadIdx.x;
    int b = i / Np, n = i % Np;
    float p0 = x[((size_t)b * 3 + 0) * Np + n];
    float p1 = x[((size_t)b * 3 + 1) * Np + n];
    float p2 = x[((size_t)b * 3 + 2) * Np + n];
    float4 v = make_float4(p0, p1, p2, 0.f);
    *(float4*)&pts[(size_t)i * 4] = v;
}

// xx[i] = sum_c pm[i*ld+c]^2 ; one wave per point, 4 points per block
__global__ __launch_bounds__(256) void k_xx(const float* __restrict__ pm, float* __restrict__ xxg, int C, int ld) {
    int wid = threadIdx.x >> 6, lane = threadIdx.x & 63;
    int pt = blockIdx.x * 4 + wid;
    const float* row = pm + (size_t)pt * ld;
    float acc = 0.f;
    for (int c = lane; c < C; c += 64) { float v = row[c]; acc = fmaf(v, v, acc); }
    #pragma unroll
    for (int off = 32; off; off >>= 1) acc += __shfl_down(acc, off, 64);
    if (lane == 0) xxg[pt] = acc;
}

// Pack points into mfma_16x16x32 B-fragment order (bf16 hi/lo), per batch.
template<int C, int CK, int LD>
__global__ __launch_bounds__(256) void k_bpack(const float* __restrict__ Xpm,
                                               ushortT* __restrict__ Bh, ushortT* __restrict__ Bl) {
    constexpr int KS = CK / 32;
    int i = blockIdx.x * 256 + threadIdx.x;
    int j = i & 7;
    int lane = (i >> 3) & 63;
    int nt = (i >> 9) & 127;
    int rest = i >> 16;
    int ks = rest % KS;
    int b = rest / KS;
    int k = ks * 32 + (lane >> 4) * 8 + j;
    int n = nt * 16 + (lane & 15);
    float v = (k < C) ? Xpm[((size_t)b * Np + n) * LD + k] : 0.f;
    unsigned u = __float_as_uint(v);
    Bh[i] = (ushortT)(u >> 16);
    float r = v - __uint_as_float(u & 0xffff0000u);
    Bl[i] = (ushortT)(__float_as_uint(r) >> 16);
}

// MFMA kNN v5: distance phase identical to v4; selection uses value-only butterfly +
// ballot owner resolution (ties across lanes: measure-zero for random input).
template<int C, int CK, int LD>
__global__ __launch_bounds__(1024) void k_knn4(const float* __restrict__ Xpm,
                                               const ushortT* __restrict__ Bh, const ushortT* __restrict__ Bl,
                                               const float* __restrict__ xxg, int* __restrict__ idxo) {
    constexpr int KS = CK / 32, CP = CK + 8, CK4 = CK / 4, C4src = LD / 4;
    constexpr int SD = 2050;
    extern __shared__ char smem[];
    ushortT* Ah = (ushortT*)smem;              // [16][CP]
    ushortT* Al = Ah + 16 * CP;                // [16][CP]
    float* xxm = (float*)(Al + 16 * CP);       // [16]
    float* dl = xxm + 16;                      // [16][SD] distances
    int b = blockIdx.x / (Np / 16);
    int n0 = (blockIdx.x % (Np / 16)) * 16;
    int t = threadIdx.x;
    const float4* Xp4 = (const float4*)Xpm;
    for (int e = t; e < 16 * CK4; e += 1024) {
        int r = e / CK4, c4 = e % CK4;
        float4 v = (c4 < C4src) ? Xp4[((size_t)b * Np + n0 + r) * C4src + c4] : make_float4(0.f, 0.f, 0.f, 0.f);
        unsigned h0, l0, h1, l1;
        cvt2u(v.x, v.y, h0, l0);
        cvt2u(v.z, v.w, h1, l1);
        *(uint2*)&Ah[r * CP + 4 * c4] = make_uint2(h0, h1);
        *(uint2*)&Al[r * CP + 4 * c4] = make_uint2(l0, l1);
    }
    if (t < 16) xxm[t] = xxg[b * Np + n0 + t];
    __syncthreads();

    int w = t >> 6, lane = t & 63;
    int quad = lane >> 4, col = lane & 15;
    short8 ah[KS], al[KS];
    #pragma unroll
    for (int ks = 0; ks < KS; ++ks) {
        ah[ks] = *(const short8*)&Ah[col * CP + ks * 32 + quad * 8];
        al[ks] = *(const short8*)&Al[col * CP + ks * 32 + quad * 8];
    }
    float xmr[4];
    #pragma unroll
    for (int r = 0; r < 4; ++r) xmr[r] = xxm[quad * 4 + r];

    for (int i = 0; i < 4; ++i) {
        int nt0 = w * 8 + 2 * i, nt1 = nt0 + 1;
        f32x4 a0 = (f32x4){0.f, 0.f, 0.f, 0.f};
        f32x4 a1 = (f32x4){0.f, 0.f, 0.f, 0.f};
        #pragma unroll
        for (int ks = 0; ks < KS; ++ks) {
            int bi0 = (((b * KS + ks) * 128 + nt0) * 64 + lane) * 8;
            int bi1 = (((b * KS + ks) * 128 + nt1) * 64 + lane) * 8;
            short8 bh0 = *(const short8*)(Bh + bi0);
            short8 bl0 = *(const short8*)(Bl + bi0);
            short8 bh1 = *(const short8*)(Bh + bi1);
            short8 bl1 = *(const short8*)(Bl + bi1);
            a0 = __builtin_amdgcn_mfma_f32_16x16x32_bf16(ah[ks], bh0, a0, 0, 0, 0);
            a1 = __builtin_amdgcn_mfma_f32_16x16x32_bf16(ah[ks], bh1, a1, 0, 0, 0);
            a0 = __builtin_amdgcn_mfma_f32_16x16x32_bf16(ah[ks], bl0, a0, 0, 0, 0);
            a1 = __builtin_amdgcn_mfma_f32_16x16x32_bf16(ah[ks], bl1, a1, 0, 0, 0);
            a0 = __builtin_amdgcn_mfma_f32_16x16x32_bf16(al[ks], bh0, a0, 0, 0, 0);
            a1 = __builtin_amdgcn_mfma_f32_16x16x32_bf16(al[ks], bh1, a1, 0, 0, 0);
        }
        float xn0 = xxg[b * Np + nt0 * 16 + col];
        float xn1 = xxg[b * Np + nt1 * 16 + col];
        #pragma unroll
        for (int r = 0; r < 4; ++r) {
            int m = quad * 4 + r;
            dl[m * SD + nt0 * 16 + col] = 2.f * a0[r] - xmr[r] - xn0;
            dl[m * SD + nt1 * 16 + col] = 2.f * a1[r] - xmr[r] - xn1;
        }
    }
    __syncthreads();

    // ---- selection: wave w owns row w ----
    const float* drow = dl + w * SD;
    float v[32];
    #pragma unroll
    for (int j = 0; j < 32; ++j) v[j] = drow[lane + 64 * j];
    float gv0, gv1, gv2, gv3;
    int gj0, gj1, gj2, gj3;
    gv0 = v[0]; gj0 = 0;
    #pragma unroll
    for (int e = 1; e < 8; ++e) if (v[e] > gv0) { gv0 = v[e]; gj0 = e; }
    gv1 = v[8]; gj1 = 8;
    #pragma unroll
    for (int e = 1; e < 8; ++e) if (v[8 + e] > gv1) { gv1 = v[8 + e]; gj1 = 8 + e; }
    gv2 = v[16]; gj2 = 16;
    #pragma unroll
    for (int e = 1; e < 8; ++e) if (v[16 + e] > gv2) { gv2 = v[16 + e]; gj2 = 16 + e; }
    gv3 = v[24]; gj3 = 24;
    #pragma unroll
    for (int e = 1; e < 8; ++e) if (v[24 + e] > gv3) { gv3 = v[24 + e]; gj3 = 24 + e; }

    size_t ob = ((size_t)b * Np + n0 + w) * Kn;
    for (int it = 0; it < Kn; ++it) {
        float lv = fmaxf(fmaxf(gv0, gv1), fmaxf(gv2, gv3));
        float Wv = lv;
        #pragma unroll
        for (int off = 1; off < 64; off <<= 1) Wv = fmaxf(Wv, __shfl_xor(Wv, off, 64));
        unsigned long long mk = __ballot(lv == Wv);
        int owner = __ffsll(mk) - 1;
        if (lane == owner) {
            int lj;
            if (gv0 == Wv) lj = gj0;
            else if (gv1 == Wv) lj = gj1;
            else if (gv2 == Wv) lj = gj2;
            else lj = gj3;
            idxo[ob + it] = lane + 64 * lj;
            int gg = lj >> 3;
            if (gg == 0) {
                #pragma unroll
                for (int e = 0; e < 8; ++e) if (e == lj) v[e] = -INFINITY;
                gv0 = v[0]; gj0 = 0;
                #pragma unroll
                for (int e = 1; e < 8; ++e) if (v[e] > gv0) { gv0 = v[e]; gj0 = e; }
            } else if (gg == 1) {
                #pragma unroll
                for (int e = 0; e < 8; ++e) if (8 + e == lj) v[8 + e] = -INFINITY;
                gv1 = v[8]; gj1 = 8;
                #pragma unroll
                for (int e = 1; e < 8; ++e) if (v[8 + e] > gv1) { gv1 = v[8 + e]; gj1 = 8 + e; }
            } else if (gg == 2) {
                #pragma unroll
                for (int e = 0; e < 8; ++e) if (16 + e == lj) v[16 + e] = -INFINITY;
                gv2 = v[16]; gj2 = 16;
                #pragma unroll
                for (int e = 1; e < 8; ++e) if (v[16 + e] > gv2) { gv2 = v[16 + e]; gj2 = 16 + e; }
            } else {
                #pragma unroll
                for (int e = 0; e < 8; ++e) if (24 + e == lj) v[24 + e] = -INFINITY;
                gv3 = v[24]; gj3 = 24;
                #pragma unroll
                for (int e = 1; e < 8; ++e) if (v[24 + e] > gv3) { gv3 = v[24 + e]; gj3 = 24 + e; }
            }
        }
    }
}

// W split+scale+transpose (fp32, for k_ctr): WdsT[c][o] = (W[o][C+c]-W[o][c])*s[o]
__global__ __launch_bounds__(256) void k_wsplit(const float* __restrict__ W, const float* __restrict__ s,
                                                int C, int O, float* __restrict__ WnsT, float* __restrict__ WdsT) {
    int i = blockIdx.x * 256 + threadIdx.x;
    if (i >= C * O) return;
    int c = i / O, o = i % O;
    float a = W[(size_t)o * 2 * C + c];
    float q = W[(size_t)o * 2 * C + C + c];
    float sv = s[o];
    WnsT[i] = a * sv;
    WdsT[i] = (q - a) * sv;
}

// Pack neighbor-half of W (scaled) into mfma_16x16x32 B-fragment order, split bf16 hi/lo.
__global__ __launch_bounds__(256) void k_wpack(const float* __restrict__ W, const float* __restrict__ s,
                                               int C, int O, ushortT* __restrict__ Bh, ushortT* __restrict__ Bl) {
    int i = blockIdx.x * 256 + threadIdx.x;
    if (i >= C * O) return;
    int k = i / O, o = i % O;
    float v = W[(size_t)o * 2 * C + k] * s[o];
    int ks = k >> 5, quad = (k >> 3) & 3, j = k & 7;
    int nt = o >> 4, lane = quad * 16 + (o & 15);
    int NT = O / 16;
    size_t idx = (((size_t)(ks * NT + nt)) * 64 + lane) * 8 + j;
    unsigned u = __float_as_uint(v);
    Bh[idx] = (ushortT)(u >> 16);
    float r = v - __uint_as_float(u & 0xffff0000u);
    Bl[idx] = (ushortT)(__float_as_uint(r) >> 16);
}

// Pack W5 (scaled by s5) [1024][512] into fragment order: KS=16, NT=64.
__global__ __launch_bounds__(256) void k_w5pack(const float* __restrict__ W5, const float* __restrict__ s5,
                                                ushortT* __restrict__ Bh, ushortT* __restrict__ Bl) {
    int i = blockIdx.x * 256 + threadIdx.x;   // 512*1024
    int k = i >> 10, o = i & 1023;
    float v = W5[(size_t)o * 512 + k] * s5[o];
    int ks = k >> 5, quad = (k >> 3) & 3, j = k & 7;
    int nt = o >> 4, lane = quad * 16 + (o & 15);
    size_t idx = (((size_t)(ks * 64 + nt)) * 64 + lane) * 8 + j;
    unsigned u = __float_as_uint(v);
    Bh[idx] = (ushortT)(u >> 16);
    float r = v - __uint_as_float(u & 0xffff0000u);
    Bl[idx] = (ushortT)(__float_as_uint(r) >> 16);
}

// cb[n][o] = sum_c ctr[n][c]*WdsT[c][o] + b[o].  32 points per block.
template<int C, int O, int OPT>
__global__ __launch_bounds__(256) void k_ctr(const float* __restrict__ Xpm, const float* __restrict__ WdsT,
                                             const float* __restrict__ bg, float* __restrict__ cb) {
    constexpr int OG = O / OPT, MG = 256 / OG, MPT = 32 / MG;
    constexpr int C4 = C / 4;
    __shared__ float xs[32][C];
    int b = blockIdx.x / (Np / 32);
    int n0 = (blockIdx.x % (Np / 32)) * 32;
    int t = threadIdx.x;
    const float4* Xp4 = (const float4*)Xpm;
    for (int e = t; e < 32 * C4; e += 256) {
        int pt = e / C4, c4 = e % C4;
        *(float4*)&xs[pt][4 * c4] = Xp4[((size_t)b * Np + n0 + pt) * C4 + c4];
    }
    __syncthreads();
    int og = t % OG, mg = t / OG;
    int o0 = og * OPT;
    float acc[MPT][OPT] = {};
    for (int c = 0; c < C; ++c) {
        float wv[OPT];
        #pragma unroll
        for (int p4 = 0; p4 < OPT / 4; ++p4)
            *(float4*)&wv[4 * p4] = *(const float4*)&WdsT[(size_t)c * O + o0 + 4 * p4];
        #pragma unroll
        for (int m = 0; m < MPT; ++m) {
            float xv = xs[mg * MPT + m][c];
            #pragma unroll
            for (int p = 0; p < OPT; ++p) acc[m][p] = fmaf(wv[p], xv, acc[m][p]);
        }
    }
    #pragma unroll
    for (int m = 0; m < MPT; ++m) {
        #pragma unroll
        for (int p = 0; p < OPT; ++p) {
            int o = o0 + p;
            cb[((size_t)b * Np + n0 + mg * MPT + m) * O + o] = acc[m][p] + bg[o];
        }
    }
}

// MFMA EdgeConv GEMM (split-bf16), max over k, + center term, lrelu.
template<int C, int O, int PTS>
__global__ __launch_bounds__(256) void k_ec3(const float* __restrict__ Xpm, const int* __restrict__ idxg,
                                             const ushortT* __restrict__ Bh, const ushortT* __restrict__ Bl,
                                             const float* __restrict__ cb,
                                             float* __restrict__ Ypm) {
    static_assert(PTS == 2, "M=64 mapping");
    constexpr int M = 64, NT = O / 16, KS = C / 32, C4 = C / 4, CP = C + 8;
    __shared__ ushortT Ah[M][CP];
    __shared__ ushortT Al[M][CP];
    __shared__ float red[PTS][2][O];
    int b = blockIdx.x / (Np / PTS);
    int n0 = (blockIdx.x % (Np / PTS)) * PTS;
    int t = threadIdx.x;
    const int* ip = idxg + ((size_t)b * Np + n0) * Kn;
    const float4* Xp4 = (const float4*)Xpm;
    for (int e = t; e < M * C4; e += 256) {
        int row = e / C4, c4 = e % C4;
        float4 v = Xp4[((size_t)b * Np + ip[row]) * C4 + c4];
        unsigned h0, l0, h1, l1;
        cvt2u(v.x, v.y, h0, l0);
        cvt2u(v.z, v.w, h1, l1);
        *(uint2*)&Ah[row][4 * c4] = make_uint2(h0, h1);
        *(uint2*)&Al[row][4 * c4] = make_uint2(l0, l1);
    }
    __syncthreads();
    int w = t >> 6, lane = t & 63;
    int quad = lane >> 4, col = lane & 15;
    int mrow = w * 16 + col;
    f32x4 acc[NT];
    #pragma unroll
    for (int nt = 0; nt < NT; ++nt) acc[nt] = (f32x4){0.f, 0.f, 0.f, 0.f};
    for (int ks = 0; ks < KS; ++ks) {
        int kb = ks * 32 + quad * 8;
        short8 ah = *(const short8*)&Ah[mrow][kb];
        short8 al = *(const short8*)&Al[mrow][kb];
        #pragma unroll
        for (int nt = 0; nt < NT; ++nt) {
            size_t bi = (((size_t)(ks * NT + nt)) * 64 + lane) * 8;
            short8 bh = *(const short8*)(Bh + bi);
            short8 bl = *(const short8*)(Bl + bi);
            acc[nt] = __builtin_amdgcn_mfma_f32_16x16x32_bf16(ah, bh, acc[nt], 0, 0, 0);
            acc[nt] = __builtin_amdgcn_mfma_f32_16x16x32_bf16(ah, bl, acc[nt], 0, 0, 0);
            acc[nt] = __builtin_amdgcn_mfma_f32_16x16x32_bf16(al, bh, acc[nt], 0, 0, 0);
        }
    }
    int pt = w >> 1, wi = w & 1;
    #pragma unroll
    for (int nt = 0; nt < NT; ++nt) {
        float m = fmaxf(fmaxf(acc[nt][0], acc[nt][1]), fmaxf(acc[nt][2], acc[nt][3]));
        m = fmaxf(m, __shfl_xor(m, 16, 64));
        m = fmaxf(m, __shfl_xor(m, 32, 64));
        if (lane < 16) red[pt][wi][nt * 16 + col] = m;
    }
    __syncthreads();
    for (int idx = t; idx < PTS * O; idx += 256) {
        int pp = idx / O, o = idx % O;
        float m = fmaxf(red[pp][0][o], red[pp][1][o]);
        size_t ni = (size_t)b * Np + n0 + pp;
        Ypm[ni * O + o] = lrelu(m + cb[ni * O + o]);
    }
}

// Legacy fused EdgeConv for layer 1 (C=3)
template<int C, int CPAD, int O, int OPT, int KPT, int PTS>
__global__ __launch_bounds__(256) void k_edgeconv(
    const float* __restrict__ Xpm, const int* __restrict__ idxg,
    const float* __restrict__ W, const float* __restrict__ sg, const float* __restrict__ bg,
    float* __restrict__ Ypm)
{
    constexpr int OG = O / OPT;
    constexpr int NKG = 256 / OG;
    constexpr int CL = CPAD + 4;
    static_assert(NKG * KPT == Kn, "k mapping");
    __shared__ float nbr[PTS][Kn][CL];
    __shared__ float ctr[PTS][CPAD];
    __shared__ float red[PTS][OPT][4][OG];
    int blk = blockIdx.x;
    int b = blk / (Np / PTS);
    int n0 = (blk % (Np / PTS)) * PTS;
    int t = threadIdx.x;
    int lane = t & 63, wid = t >> 6;
    const int* ip = idxg + ((size_t)b * Np + n0) * Kn;
    const float4* Xp4 = (const float4*)Xpm;
    constexpr int C4 = CPAD / 4;
    for (int e = t; e < PTS * C4; e += 256) {
        int pt = e / C4, c4 = e % C4;
        *(float4*)&ctr[pt][4 * c4] = Xp4[((size_t)b * Np + n0 + pt) * C4 + c4];
    }
    for (int e = t; e < PTS * Kn * C4; e += 256) {
        int pt = e / (Kn * C4);
        int r = e % (Kn * C4);
        int k = r / C4, c4 = r % C4;
        int nb = ip[pt * Kn + k];
        *(float4*)&nbr[pt][k][4 * c4] = Xp4[((size_t)b * Np + nb) * C4 + c4];
    }
    __syncthreads();
    int og = t % OG, kg = t / OG;
    float acc[PTS][OPT][KPT] = {};
    float ctt[PTS][OPT] = {};
    for (int c0 = 0; c0 < CPAD; c0 += 4) {
        float wn[OPT][4], wd[OPT][4];
        #pragma unroll
        for (int p = 0; p < OPT; ++p) {
            #pragma unroll
            for (int cc = 0; cc < 4; ++cc) {
                int c = c0 + cc;
                float a = (c < C) ? W[(size_t)(og + p * OG) * (2 * C) + c] : 0.f;
                float q = (c < C) ? W[(size_t)(og + p * OG) * (2 * C) + C + c] : 0.f;
                wn[p][cc] = a; wd[p][cc] = q - a;
            }
        }
        #pragma unroll
        for (int pt = 0; pt < PTS; ++pt) {
            float4 cv = *(const float4*)&ctr[pt][c0];
            #pragma unroll
            for (int p = 0; p < OPT; ++p) {
                ctt[pt][p] = fmaf(wd[p][0], cv.x, ctt[pt][p]);
                ctt[pt][p] = fmaf(wd[p][1], cv.y, ctt[pt][p]);
                ctt[pt][p] = fmaf(wd[p][2], cv.z, ctt[pt][p]);
                ctt[pt][p] = fmaf(wd[p][3], cv.w, ctt[pt][p]);
            }
        }
        #pragma unroll
        for (int pt = 0; pt < PTS; ++pt) {
            #pragma unroll
            for (int k = 0; k < KPT; ++k) {
                float4 nv = *(const float4*)&nbr[pt][kg * KPT + k][c0];
                #pragma unroll
                for (int p = 0; p < OPT; ++p) {
                    acc[pt][p][k] = fmaf(wn[p][0], nv.x, acc[pt][p][k]);
                    acc[pt][p][k] = fmaf(wn[p][1], nv.y, acc[pt][p][k]);
                    acc[pt][p][k] = fmaf(wn[p][2], nv.z, acc[pt][p][k]);
                    acc[pt][p][k] = fmaf(wn[p][3], nv.w, acc[pt][p][k]);
                }
            }
        }
    }
    #pragma unroll
    for (int pt = 0; pt < PTS; ++pt) {
        #pragma unroll
        for (int p = 0; p < OPT; ++p) {
            int o = og + p * OG;
            float sv = sg[o], bv = bg[o];
            float m = -INFINITY;
            #pragma unroll
            for (int k = 0; k < KPT; ++k) {
                float hv = fmaf(acc[pt][p][k] + ctt[pt][p], sv, bv);
                m = fmaxf(m, lrelu(hv));
            }
            #pragma unroll
            for (int s = OG; s < 64; s <<= 1) m = fmaxf(m, __shfl_xor(m, s, 64));
            if (lane < OG) red[pt][p][wid][lane] = m;
        }
    }
    __syncthreads();
    if (t < OG) {
        #pragma unroll
        for (int pt = 0; pt < PTS; ++pt) {
            #pragma unroll
            for (int p = 0; p < OPT; ++p) {
                float m = fmaxf(fmaxf(red[pt][p][0][t], red[pt][p][1][t]),
                                fmaxf(red[pt][p][2][t], red[pt][p][3][t]));
                int o = t + p * OG;
                Ypm[((size_t)b * Np + n0 + pt) * O + o] = m;
            }
        }
    }
}

// MFMA W5 (K=512, O=1024) + bias + LeakyReLU + max/sum pool over 32 points -> partials [64 chunks].
__global__ __launch_bounds__(256) void k_w5mfma(
    const float* __restrict__ x1, const float* __restrict__ x2,
    const float* __restrict__ x3, const float* __restrict__ x4,
    const ushortT* __restrict__ Bh, const ushortT* __restrict__ Bl,
    const float* __restrict__ b5,
    float* __restrict__ pmax, float* __restrict__ psum)
{
    constexpr int CP = 520;                 // 512 + 8 pad
    extern __shared__ char smem[];
    ushortT* Ah = (ushortT*)smem;           // [32][CP]
    ushortT* Al = Ah + 32 * CP;             // [32][CP]
    int b = blockIdx.x >> 6;
    int chunk = blockIdx.x & 63;
    int n0 = chunk * 32;
    int t = threadIdx.x;
    for (int e = t; e < 32 * 128; e += 256) {
        int pt = e >> 7, c4 = e & 127;
        size_t pi = (size_t)b * Np + n0 + pt;
        float4 v;
        if (c4 < 16)      v = ((const float4*)x1)[pi * 16 + c4];
        else if (c4 < 32) v = ((const float4*)x2)[pi * 16 + (c4 - 16)];
        else if (c4 < 64) v = ((const float4*)x3)[pi * 32 + (c4 - 32)];
        else              v = ((const float4*)x4)[pi * 64 + (c4 - 64)];
        unsigned h0, l0, h1, l1;
        cvt2u(v.x, v.y, h0, l0);
        cvt2u(v.z, v.w, h1, l1);
        *(uint2*)&Ah[pt * CP + 4 * c4] = make_uint2(h0, h1);
        *(uint2*)&Al[pt * CP + 4 * c4] = make_uint2(l0, l1);
    }
    __syncthreads();
    int w = t >> 6, lane = t & 63;
    int quad = lane >> 4, col = lane & 15;
    size_t pb = ((size_t)(b * 64 + chunk)) * 1024;
    for (int oi = 0; oi < 16; ++oi) {
        int nt = w * 16 + oi;
        f32x4 a0 = (f32x4){0.f, 0.f, 0.f, 0.f};
        f32x4 a1 = (f32x4){0.f, 0.f, 0.f, 0.f};
        for (int ks = 0; ks < 16; ++ks) {
            size_t bi = (((size_t)(ks * 64 + nt)) * 64 + lane) * 8;
            short8 bh = *(const short8*)(Bh + bi);
            short8 bl = *(const short8*)(Bl + bi);
            int ao = ks * 32 + quad * 8;
            short8 ah0 = *(const short8*)&Ah[col * CP + ao];
            short8 al0 = *(const short8*)&Al[col * CP + ao];
            short8 ah1 = *(const short8*)&Ah[(16 + col) * CP + ao];
            short8 al1 = *(const short8*)&Al[(16 + col) * CP + ao];
            a0 = __builtin_amdgcn_mfma_f32_16x16x32_bf16(ah0, bh, a0, 0, 0, 0);
            a1 = __builtin_amdgcn_mfma_f32_16x16x32_bf16(ah1, bh, a1, 0, 0, 0);
            a0 = __builtin_amdgcn_mfma_f32_16x16x32_bf16(ah0, bl, a0, 0, 0, 0);
            a1 = __builtin_amdgcn_mfma_f32_16x16x32_bf16(ah1, bl, a1, 0, 0, 0);
            a0 = __builtin_amdgcn_mfma_f32_16x16x32_bf16(al0, bh, a0, 0, 0, 0);
            a1 = __builtin_amdgcn_mfma_f32_16x16x32_bf16(al1, bh, a1, 0, 0, 0);
        }
        float bb = b5[nt * 16 + col];
        float mx = -INFINITY, sm = 0.f;
        #pragma unroll
        for (int r = 0; r < 4; ++r) {
            float v0 = lrelu(a0[r] + bb);
            float v1 = lrelu(a1[r] + bb);
            mx = fmaxf(mx, fmaxf(v0, v1));
            sm += v0 + v1;
        }
        mx = fmaxf(mx, __shfl_xor(mx, 16, 64));
        mx = fmaxf(mx, __shfl_xor(mx, 32, 64));
        sm += __shfl_xor(sm, 16, 64);
        sm += __shfl_xor(sm, 32, 64);
        if (lane < 16) {
            pmax[pb + nt * 16 + col] = mx;
            psum[pb + nt * 16 + col] = sm;
        }
    }
}

__global__ __launch_bounds__(256) void k_poolred(const float* __restrict__ pmax, const float* __restrict__ psum,
                                                 float* __restrict__ g0) {
    int i = blockIdx.x * 256 + threadIdx.x;
    int b = i >> 10, o = i & 1023;
    float mx = -INFINITY, sm = 0.f;
    for (int ch = 0; ch < 64; ++ch) {
        size_t idx = ((size_t)(b * 64 + ch)) * 1024 + o;
        mx = fmaxf(mx, pmax[idx]);
        sm += psum[idx];
    }
    g0[(size_t)b * 2048 + o] = mx;
    g0[(size_t)b * 2048 + 1024 + o] = sm * (1.f / Np);
}

__global__ __launch_bounds__(256) void k_fc(const float* __restrict__ In, int ldIn, int C,
                                            const float* __restrict__ Wm,
                                            const float* __restrict__ bias,
                                            const float* __restrict__ sc, const float* __restrict__ bnb,
                                            int leaky, float* __restrict__ Out, int ldOut, int O) {
    int wid = threadIdx.x >> 6, lane = threadIdx.x & 63;
    int o = blockIdx.x * 4 + wid;
    int b = blockIdx.y;
    if (o >= O) return;
    const float* in = In + (size_t)b * ldIn;
    const float* wr = Wm + (size_t)o * C;
    float acc = 0.f;
    for (int c = lane; c < C; c += 64) acc = fmaf(in[c], wr[c], acc);
    #pragma unroll
    for (int off = 32; off; off >>= 1) acc += __shfl_down(acc, off, 64);
    if (lane == 0) {
        float v = acc + (bias ? bias[o] : 0.f);
        if (sc) v = fmaf(v, sc[o], bnb[o]);
        if (leaky) v = lrelu(v);
        Out[(size_t)b * ldOut + o] = v;
    }
}

extern "C" void kernel_launch(void* const* d_in, const int* in_sizes, int n_in,
                              void* d_out, int out_size, void* d_ws, size_t ws_size,
                              hipStream_t stream) {
    const float* x   = (const float*)d_in[0];
    const float* W1  = (const float*)d_in[1];
    const float* s1  = (const float*)d_in[2];
    const float* b1  = (const float*)d_in[3];
    const float* W2  = (const float*)d_in[4];
    const float* s2  = (const float*)d_in[5];
    const float* b2  = (const float*)d_in[6];
    const float* W3  = (const float*)d_in[7];
    const float* s3  = (const float*)d_in[8];
    const float* b3  = (const float*)d_in[9];
    const float* W4  = (const float*)d_in[10];
    const float* s4  = (const float*)d_in[11];
    const float* b4  = (const float*)d_in[12];
    const float* W5  = (const float*)d_in[13];
    const float* s5  = (const float*)d_in[14];
    const float* b5  = (const float*)d_in[15];
    const float* L1w = (const float*)d_in[16];
    const float* s6  = (const float*)d_in[17];
    const float* b6  = (const float*)d_in[18];
    const float* L2w = (const float*)d_in[19];
    const float* L2b = (const float*)d_in[20];
    const float* s7  = (const float*)d_in[21];
    const float* b7  = (const float*)d_in[22];
    const float* L3w = (const float*)d_in[23];
    const float* L3b = (const float*)d_in[24];
    const float* F1w = (const float*)d_in[25];
    const float* s8  = (const float*)d_in[26];
    const float* b8  = (const float*)d_in[27];
    const float* F2w = (const float*)d_in[28];
    const float* F2b = (const float*)d_in[29];
    const float* s9  = (const float*)d_in[30];
    const float* b9  = (const float*)d_in[31];
    const float* F3w = (const float*)d_in[32];
    const float* F3b = (const float*)d_in[33];

    float* ws = (float*)d_ws;
    size_t off = 0;
    auto alloc = [&](size_t n) { float* p = ws + off; off += n; return p; };
    float* pts  = alloc((size_t)Bn * Np * 4);
    float* x1   = alloc((size_t)Bn * Np * 64);
    float* x2   = alloc((size_t)Bn * Np * 64);
    float* x3   = alloc((size_t)Bn * Np * 128);
    float* x4   = alloc((size_t)Bn * Np * 256);
    float* xcm  = alloc((size_t)Bn * Np * 128);   // aliased: pmax / psum
    float* xxb  = alloc((size_t)Bn * Np);
    int*   idxb = (int*)alloc((size_t)Bn * Np * Kn);
    float* g0   = alloc((size_t)Bn * 2048);
    float* g1   = alloc((size_t)Bn * 512);
    float* g2   = alloc((size_t)Bn * 256);
    float* y1   = alloc((size_t)Bn * 512);
    float* y2   = alloc((size_t)Bn * 256);
    float* WnsT2 = alloc(64 * 64);
    float* WdsT2 = alloc(64 * 64);
    float* WnsT3 = alloc(64 * 128);
    float* WdsT3 = alloc(64 * 128);
    float* WnsT4 = alloc(128 * 256);
    float* WdsT4 = alloc(128 * 256);
    ushortT* Bh2 = (ushortT*)alloc(64 * 64 / 2);
    ushortT* Bl2 = (ushortT*)alloc(64 * 64 / 2);
    ushortT* Bh3 = (ushortT*)alloc(64 * 128 / 2);
    ushortT* Bl3 = (ushortT*)alloc(64 * 128 / 2);
    ushortT* Bh4 = (ushortT*)alloc(128 * 256 / 2);
    ushortT* Bl4 = (ushortT*)alloc(128 * 256 / 2);
    ushortT* BhK = (ushortT*)alloc(1048576);   // knn B-frag hi (max C=128: 2M shorts)
    ushortT* BlK = (ushortT*)alloc(1048576);
    ushortT* Bh5 = (ushortT*)alloc(262144);    // W5 frag hi: 512K shorts
    ushortT* Bl5 = (ushortT*)alloc(262144);
    float* pmax = xcm;
    float* psum = xcm + 524288;
    float* cb2 = x2;
    float* cb3 = x3;
    float* cb4 = x4;

    // dynamic-LDS opt-ins (idempotent, safe pre-capture)
    auto shsz = [](int CP) { return 16 * CP * 2 * 2 + 64 + 16 * 2050 * 4; };
    int sh3 = shsz(40), sh64 = shsz(72), sh128 = shsz(136);
    int shw5 = 32 * 520 * 2 * 2;
    hipFuncSetAttribute((const void*)k_knn4<3, 32, 4>, hipFuncAttributeMaxDynamicSharedMemorySize, sh3);
    hipFuncSetAttribute((const void*)k_knn4<64, 64, 64>, hipFuncAttributeMaxDynamicSharedMemorySize, sh64);
    hipFuncSetAttribute((const void*)k_knn4<128, 128, 128>, hipFuncAttributeMaxDynamicSharedMemorySize, sh128);
    hipFuncSetAttribute((const void*)k_w5mfma, hipFuncAttributeMaxDynamicSharedMemorySize, shw5);

    k_transpose<<<Bn * Np / 256, 256, 0, stream>>>(x, pts);
    k_wsplit<<<16, 256, 0, stream>>>(W2, s2, 64, 64, WnsT2, WdsT2);
    k_wsplit<<<32, 256, 0, stream>>>(W3, s3, 64, 128, WnsT3, WdsT3);
    k_wsplit<<<128, 256, 0, stream>>>(W4, s4, 128, 256, WnsT4, WdsT4);
    k_wpack<<<16, 256, 0, stream>>>(W2, s2, 64, 64, Bh2, Bl2);
    k_wpack<<<32, 256, 0, stream>>>(W3, s3, 64, 128, Bh3, Bl3);
    k_wpack<<<128, 256, 0, stream>>>(W4, s4, 128, 256, Bh4, Bl4);
    k_w5pack<<<2048, 256, 0, stream>>>(W5, s5, Bh5, Bl5);

    // Layer 1: C=3
    k_xx<<<Bn * Np / 4, 256, 0, stream>>>(pts, xxb, 3, 4);
    k_bpack<3, 32, 4><<<2048, 256, 0, stream>>>(pts, BhK, BlK);
    k_knn4<3, 32, 4><<<Bn * Np / 16, 1024, sh3, stream>>>(pts, BhK, BlK, xxb, idxb);
    k_edgeconv<3, 4, 64, 1, 8, 4><<<Bn * Np / 4, 256, 0, stream>>>(pts, idxb, W1, s1, b1, x1);

    // Layer 2: C=64 -> O=64
    k_xx<<<Bn * Np / 4, 256, 0, stream>>>(x1, xxb, 64, 64);
    k_bpack<64, 64, 64><<<4096, 256, 0, stream>>>(x1, BhK, BlK);
    k_knn4<64, 64, 64><<<Bn * Np / 16, 1024, sh64, stream>>>(x1, BhK, BlK, xxb, idxb);
    k_ctr<64, 64, 4><<<Bn * Np / 32, 256, 0, stream>>>(x1, WdsT2, b2, cb2);
    k_ec3<64, 64, 2><<<Bn * Np / 2, 256, 0, stream>>>(x1, idxb, Bh2, Bl2, cb2, x2);

    // Layer 3: C=64 -> O=128
    k_xx<<<Bn * Np / 4, 256, 0, stream>>>(x2, xxb, 64, 64);
    k_bpack<64, 64, 64><<<4096, 256, 0, stream>>>(x2, BhK, BlK);
    k_knn4<64, 64, 64><<<Bn * Np / 16, 1024, sh64, stream>>>(x2, BhK, BlK, xxb, idxb);
    k_ctr<64, 128, 8><<<Bn * Np / 32, 256, 0, stream>>>(x2, WdsT3, b3, cb3);
    k_ec3<64, 128, 2><<<Bn * Np / 2, 256, 0, stream>>>(x2, idxb, Bh3, Bl3, cb3, x3);

    // Layer 4: C=128 -> O=256
    k_xx<<<Bn * Np / 4, 256, 0, stream>>>(x3, xxb, 128, 128);
    k_bpack<128, 128, 128><<<8192, 256, 0, stream>>>(x3, BhK, BlK);
    k_knn4<128, 128, 128><<<Bn * Np / 16, 1024, sh128, stream>>>(x3, BhK, BlK, xxb, idxb);
    k_ctr<128, 256, 8><<<Bn * Np / 32, 256, 0, stream>>>(x3, WdsT4, b4, cb4);
    k_ec3<128, 256, 2><<<Bn * Np / 2, 256, 0, stream>>>(x3, idxb, Bh4, Bl4, cb4, x4);

    // W5 + pooling (MFMA)
    k_w5mfma<<<Bn * 64, 256, shw5, stream>>>(x1, x2, x3, x4, Bh5, Bl5, b5, pmax, psum);
    k_poolred<<<Bn * 1024 / 256, 256, 0, stream>>>(pmax, psum, g0);

    float* out = (float*)d_out;
    k_fc<<<dim3(128, Bn), 256, 0, stream>>>(g0, 2048, 2048, L1w, nullptr, s6, b6, 1, g1, 512, 512);
    k_fc<<<dim3(64, Bn), 256, 0, stream>>>(g1, 512, 512, L2w, L2b, s7, b7, 1, g2, 256, 256);
    k_fc<<<dim3(2, Bn), 256, 0, stream>>>(g2, 256, 256, L3w, L3b, nullptr, nullptr, 0, out, 5, 5);
    k_fc<<<dim3(128, Bn), 256, 0, stream>>>(g0, 2048, 1024, F1w, nullptr, s8, b8, 1, y1, 512, 512);
    k_fc<<<dim3(64, Bn), 256, 0, stream>>>(y1, 512, 512, F2w, F2b, s9, b9, 1, y2, 256, 256);
    k_fc<<<dim3(2, Bn), 256, 0, stream>>>(y2, 256, 256, F3w, F3b, nullptr, nullptr, 0, out + 40, 5, 5);
}

// Round 10
// 1047.513 us; speedup vs baseline: 4.1012x; 1.1367x over previous
//
#include <hip/hip_runtime.h>
#include <math.h>

constexpr int Bn = 8;
constexpr int Np = 2048;
constexpr int Kn = 32;
constexpr float NEGS = 0.2f;

typedef __attribute__((ext_vector_type(8))) short short8;
typedef __attribute__((ext_vector_type(4))) float f32x4;
typedef unsigned short ushortT;

__device__ __forceinline__ float lrelu(float v) { return v > 0.f ? v : NEGS * v; }

// split fp32 -> bf16 hi (truncate) + bf16 lo (residual, truncate); packed 2-at-a-time
__device__ __forceinline__ void cvt2u(float a, float b, unsigned& h, unsigned& l) {
    unsigned ua = __float_as_uint(a), ub = __float_as_uint(b);
    h = (ua >> 16) | (ub & 0xffff0000u);
    float ra = a - __uint_as_float(ua & 0xffff0000u);
    float rb = b - __uint_as_float(ub & 0xffff0000u);
    l = (__float_as_uint(ra) >> 16) | (__float_as_uint(rb) & 0xffff0000u);
}

// x [B,3,N] -> pts point-major [B*N, 4] (pad lane = 0)
__global__ __launch_bounds__(256) void k_transpose(const float* __restrict__ x, float* __restrict__ pts) {
    int i = blockIdx.x * 256 + threadIdx.x;
    int b = i / Np, n = i % Np;
    float p0 = x[((size_t)b * 3 + 0) * Np + n];
    float p1 = x[((size_t)b * 3 + 1) * Np + n];
    float p2 = x[((size_t)b * 3 + 2) * Np + n];
    float4 v = make_float4(p0, p1, p2, 0.f);
    *(float4*)&pts[(size_t)i * 4] = v;
}

// xx[i] = sum_c pm[i*ld+c]^2 ; one wave per point, 4 points per block
__global__ __launch_bounds__(256) void k_xx(const float* __restrict__ pm, float* __restrict__ xxg, int C, int ld) {
    int wid = threadIdx.x >> 6, lane = threadIdx.x & 63;
    int pt = blockIdx.x * 4 + wid;
    const float* row = pm + (size_t)pt * ld;
    float acc = 0.f;
    for (int c = lane; c < C; c += 64) { float v = row[c]; acc = fmaf(v, v, acc); }
    #pragma unroll
    for (int off = 32; off; off >>= 1) acc += __shfl_down(acc, off, 64);
    if (lane == 0) xxg[pt] = acc;
}

// Pack points into mfma_16x16x32 B-fragment order (bf16 hi/lo), per batch.
template<int C, int CK, int LD>
__global__ __launch_bounds__(256) void k_bpack(const float* __restrict__ Xpm,
                                               ushortT* __restrict__ Bh, ushortT* __restrict__ Bl) {
    constexpr int KS = CK / 32;
    int i = blockIdx.x * 256 + threadIdx.x;
    int j = i & 7;
    int lane = (i >> 3) & 63;
    int nt = (i >> 9) & 127;
    int rest = i >> 16;
    int ks = rest % KS;
    int b = rest / KS;
    int k = ks * 32 + (lane >> 4) * 8 + j;
    int n = nt * 16 + (lane & 15);
    float v = (k < C) ? Xpm[((size_t)b * Np + n) * LD + k] : 0.f;
    unsigned u = __float_as_uint(v);
    Bh[i] = (ushortT)(u >> 16);
    float r = v - __uint_as_float(u & 0xffff0000u);
    Bl[i] = (ushortT)(__float_as_uint(r) >> 16);
}

// MFMA kNN v5: distance phase split-bf16 MFMA; selection value-only butterfly + ballot owner.
template<int C, int CK, int LD>
__global__ __launch_bounds__(1024) void k_knn4(const float* __restrict__ Xpm,
                                               const ushortT* __restrict__ Bh, const ushortT* __restrict__ Bl,
                                               const float* __restrict__ xxg, int* __restrict__ idxo) {
    constexpr int KS = CK / 32, CP = CK + 8, CK4 = CK / 4, C4src = LD / 4;
    constexpr int SD = 2050;
    extern __shared__ char smem[];
    ushortT* Ah = (ushortT*)smem;              // [16][CP]
    ushortT* Al = Ah + 16 * CP;                // [16][CP]
    float* xxm = (float*)(Al + 16 * CP);       // [16]
    float* dl = xxm + 16;                      // [16][SD] distances
    int b = blockIdx.x / (Np / 16);
    int n0 = (blockIdx.x % (Np / 16)) * 16;
    int t = threadIdx.x;
    const float4* Xp4 = (const float4*)Xpm;
    for (int e = t; e < 16 * CK4; e += 1024) {
        int r = e / CK4, c4 = e % CK4;
        float4 v = (c4 < C4src) ? Xp4[((size_t)b * Np + n0 + r) * C4src + c4] : make_float4(0.f, 0.f, 0.f, 0.f);
        unsigned h0, l0, h1, l1;
        cvt2u(v.x, v.y, h0, l0);
        cvt2u(v.z, v.w, h1, l1);
        *(uint2*)&Ah[r * CP + 4 * c4] = make_uint2(h0, h1);
        *(uint2*)&Al[r * CP + 4 * c4] = make_uint2(l0, l1);
    }
    if (t < 16) xxm[t] = xxg[b * Np + n0 + t];
    __syncthreads();

    int w = t >> 6, lane = t & 63;
    int quad = lane >> 4, col = lane & 15;
    short8 ah[KS], al[KS];
    #pragma unroll
    for (int ks = 0; ks < KS; ++ks) {
        ah[ks] = *(const short8*)&Ah[col * CP + ks * 32 + quad * 8];
        al[ks] = *(const short8*)&Al[col * CP + ks * 32 + quad * 8];
    }
    float xmr[4];
    #pragma unroll
    for (int r = 0; r < 4; ++r) xmr[r] = xxm[quad * 4 + r];

    for (int i = 0; i < 4; ++i) {
        int nt0 = w * 8 + 2 * i, nt1 = nt0 + 1;
        f32x4 a0 = (f32x4){0.f, 0.f, 0.f, 0.f};
        f32x4 a1 = (f32x4){0.f, 0.f, 0.f, 0.f};
        #pragma unroll
        for (int ks = 0; ks < KS; ++ks) {
            int bi0 = (((b * KS + ks) * 128 + nt0) * 64 + lane) * 8;
            int bi1 = (((b * KS + ks) * 128 + nt1) * 64 + lane) * 8;
            short8 bh0 = *(const short8*)(Bh + bi0);
            short8 bl0 = *(const short8*)(Bl + bi0);
            short8 bh1 = *(const short8*)(Bh + bi1);
            short8 bl1 = *(const short8*)(Bl + bi1);
            a0 = __builtin_amdgcn_mfma_f32_16x16x32_bf16(ah[ks], bh0, a0, 0, 0, 0);
            a1 = __builtin_amdgcn_mfma_f32_16x16x32_bf16(ah[ks], bh1, a1, 0, 0, 0);
            a0 = __builtin_amdgcn_mfma_f32_16x16x32_bf16(ah[ks], bl0, a0, 0, 0, 0);
            a1 = __builtin_amdgcn_mfma_f32_16x16x32_bf16(ah[ks], bl1, a1, 0, 0, 0);
            a0 = __builtin_amdgcn_mfma_f32_16x16x32_bf16(al[ks], bh0, a0, 0, 0, 0);
            a1 = __builtin_amdgcn_mfma_f32_16x16x32_bf16(al[ks], bh1, a1, 0, 0, 0);
        }
        float xn0 = xxg[b * Np + nt0 * 16 + col];
        float xn1 = xxg[b * Np + nt1 * 16 + col];
        #pragma unroll
        for (int r = 0; r < 4; ++r) {
            int m = quad * 4 + r;
            dl[m * SD + nt0 * 16 + col] = 2.f * a0[r] - xmr[r] - xn0;
            dl[m * SD + nt1 * 16 + col] = 2.f * a1[r] - xmr[r] - xn1;
        }
    }
    __syncthreads();

    // ---- selection: wave w owns row w ----
    const float* drow = dl + w * SD;
    float v[32];
    #pragma unroll
    for (int j = 0; j < 32; ++j) v[j] = drow[lane + 64 * j];
    float gv0, gv1, gv2, gv3;
    int gj0, gj1, gj2, gj3;
    gv0 = v[0]; gj0 = 0;
    #pragma unroll
    for (int e = 1; e < 8; ++e) if (v[e] > gv0) { gv0 = v[e]; gj0 = e; }
    gv1 = v[8]; gj1 = 8;
    #pragma unroll
    for (int e = 1; e < 8; ++e) if (v[8 + e] > gv1) { gv1 = v[8 + e]; gj1 = 8 + e; }
    gv2 = v[16]; gj2 = 16;
    #pragma unroll
    for (int e = 1; e < 8; ++e) if (v[16 + e] > gv2) { gv2 = v[16 + e]; gj2 = 16 + e; }
    gv3 = v[24]; gj3 = 24;
    #pragma unroll
    for (int e = 1; e < 8; ++e) if (v[24 + e] > gv3) { gv3 = v[24 + e]; gj3 = 24 + e; }

    size_t ob = ((size_t)b * Np + n0 + w) * Kn;
    for (int it = 0; it < Kn; ++it) {
        float lv = fmaxf(fmaxf(gv0, gv1), fmaxf(gv2, gv3));
        float Wv = lv;
        #pragma unroll
        for (int off = 1; off < 64; off <<= 1) Wv = fmaxf(Wv, __shfl_xor(Wv, off, 64));
        unsigned long long mk = __ballot(lv == Wv);
        int owner = __ffsll(mk) - 1;
        if (lane == owner) {
            int lj;
            if (gv0 == Wv) lj = gj0;
            else if (gv1 == Wv) lj = gj1;
            else if (gv2 == Wv) lj = gj2;
            else lj = gj3;
            idxo[ob + it] = lane + 64 * lj;
            int gg = lj >> 3;
            if (gg == 0) {
                #pragma unroll
                for (int e = 0; e < 8; ++e) if (e == lj) v[e] = -INFINITY;
                gv0 = v[0]; gj0 = 0;
                #pragma unroll
                for (int e = 1; e < 8; ++e) if (v[e] > gv0) { gv0 = v[e]; gj0 = e; }
            } else if (gg == 1) {
                #pragma unroll
                for (int e = 0; e < 8; ++e) if (8 + e == lj) v[8 + e] = -INFINITY;
                gv1 = v[8]; gj1 = 8;
                #pragma unroll
                for (int e = 1; e < 8; ++e) if (v[8 + e] > gv1) { gv1 = v[8 + e]; gj1 = 8 + e; }
            } else if (gg == 2) {
                #pragma unroll
                for (int e = 0; e < 8; ++e) if (16 + e == lj) v[16 + e] = -INFINITY;
                gv2 = v[16]; gj2 = 16;
                #pragma unroll
                for (int e = 1; e < 8; ++e) if (v[16 + e] > gv2) { gv2 = v[16 + e]; gj2 = 16 + e; }
            } else {
                #pragma unroll
                for (int e = 0; e < 8; ++e) if (24 + e == lj) v[24 + e] = -INFINITY;
                gv3 = v[24]; gj3 = 24;
                #pragma unroll
                for (int e = 1; e < 8; ++e) if (v[24 + e] > gv3) { gv3 = v[24 + e]; gj3 = 24 + e; }
            }
        }
    }
}

// W split+scale+transpose (fp32, for k_ctr): WdsT[c][o] = (W[o][C+c]-W[o][c])*s[o]
__global__ __launch_bounds__(256) void k_wsplit(const float* __restrict__ W, const float* __restrict__ s,
                                                int C, int O, float* __restrict__ WnsT, float* __restrict__ WdsT) {
    int i = blockIdx.x * 256 + threadIdx.x;
    if (i >= C * O) return;
    int c = i / O, o = i % O;
    float a = W[(size_t)o * 2 * C + c];
    float q = W[(size_t)o * 2 * C + C + c];
    float sv = s[o];
    WnsT[i] = a * sv;
    WdsT[i] = (q - a) * sv;
}

// Pack neighbor-half of W (scaled) into mfma_16x16x32 B-fragment order, split bf16 hi/lo.
__global__ __launch_bounds__(256) void k_wpack(const float* __restrict__ W, const float* __restrict__ s,
                                               int C, int O, ushortT* __restrict__ Bh, ushortT* __restrict__ Bl) {
    int i = blockIdx.x * 256 + threadIdx.x;
    if (i >= C * O) return;
    int k = i / O, o = i % O;
    float v = W[(size_t)o * 2 * C + k] * s[o];
    int ks = k >> 5, quad = (k >> 3) & 3, j = k & 7;
    int nt = o >> 4, lane = quad * 16 + (o & 15);
    int NT = O / 16;
    size_t idx = (((size_t)(ks * NT + nt)) * 64 + lane) * 8 + j;
    unsigned u = __float_as_uint(v);
    Bh[idx] = (ushortT)(u >> 16);
    float r = v - __uint_as_float(u & 0xffff0000u);
    Bl[idx] = (ushortT)(__float_as_uint(r) >> 16);
}

// Pack W5 (scaled by s5) [1024][512] into fragment order: KS=16, NT=64.
__global__ __launch_bounds__(256) void k_w5pack(const float* __restrict__ W5, const float* __restrict__ s5,
                                                ushortT* __restrict__ Bh, ushortT* __restrict__ Bl) {
    int i = blockIdx.x * 256 + threadIdx.x;   // 512*1024
    int k = i >> 10, o = i & 1023;
    float v = W5[(size_t)o * 512 + k] * s5[o];
    int ks = k >> 5, quad = (k >> 3) & 3, j = k & 7;
    int nt = o >> 4, lane = quad * 16 + (o & 15);
    size_t idx = (((size_t)(ks * 64 + nt)) * 64 + lane) * 8 + j;
    unsigned u = __float_as_uint(v);
    Bh[idx] = (ushortT)(u >> 16);
    float r = v - __uint_as_float(u & 0xffff0000u);
    Bl[idx] = (ushortT)(__float_as_uint(r) >> 16);
}

// cb[n][o] = sum_c ctr[n][c]*WdsT[c][o] + b[o].  32 points per block.
template<int C, int O, int OPT>
__global__ __launch_bounds__(256) void k_ctr(const float* __restrict__ Xpm, const float* __restrict__ WdsT,
                                             const float* __restrict__ bg, float* __restrict__ cb) {
    constexpr int OG = O / OPT, MG = 256 / OG, MPT = 32 / MG;
    constexpr int C4 = C / 4;
    __shared__ float xs[32][C];
    int b = blockIdx.x / (Np / 32);
    int n0 = (blockIdx.x % (Np / 32)) * 32;
    int t = threadIdx.x;
    const float4* Xp4 = (const float4*)Xpm;
    for (int e = t; e < 32 * C4; e += 256) {
        int pt = e / C4, c4 = e % C4;
        *(float4*)&xs[pt][4 * c4] = Xp4[((size_t)b * Np + n0 + pt) * C4 + c4];
    }
    __syncthreads();
    int og = t % OG, mg = t / OG;
    int o0 = og * OPT;
    float acc[MPT][OPT] = {};
    for (int c = 0; c < C; ++c) {
        float wv[OPT];
        #pragma unroll
        for (int p4 = 0; p4 < OPT / 4; ++p4)
            *(float4*)&wv[4 * p4] = *(const float4*)&WdsT[(size_t)c * O + o0 + 4 * p4];
        #pragma unroll
        for (int m = 0; m < MPT; ++m) {
            float xv = xs[mg * MPT + m][c];
            #pragma unroll
            for (int p = 0; p < OPT; ++p) acc[m][p] = fmaf(wv[p], xv, acc[m][p]);
        }
    }
    #pragma unroll
    for (int m = 0; m < MPT; ++m) {
        #pragma unroll
        for (int p = 0; p < OPT; ++p) {
            int o = o0 + p;
            cb[((size_t)b * Np + n0 + mg * MPT + m) * O + o] = acc[m][p] + bg[o];
        }
    }
}

// MFMA EdgeConv GEMM (split-bf16), max over k, + center term, lrelu.
template<int C, int O, int PTS>
__global__ __launch_bounds__(256) void k_ec3(const float* __restrict__ Xpm, const int* __restrict__ idxg,
                                             const ushortT* __restrict__ Bh, const ushortT* __restrict__ Bl,
                                             const float* __restrict__ cb,
                                             float* __restrict__ Ypm) {
    static_assert(PTS == 2, "M=64 mapping");
    constexpr int M = 64, NT = O / 16, KS = C / 32, C4 = C / 4, CP = C + 8;
    __shared__ ushortT Ah[M][CP];
    __shared__ ushortT Al[M][CP];
    __shared__ float red[PTS][2][O];
    int b = blockIdx.x / (Np / PTS);
    int n0 = (blockIdx.x % (Np / PTS)) * PTS;
    int t = threadIdx.x;
    const int* ip = idxg + ((size_t)b * Np + n0) * Kn;
    const float4* Xp4 = (const float4*)Xpm;
    for (int e = t; e < M * C4; e += 256) {
        int row = e / C4, c4 = e % C4;
        float4 v = Xp4[((size_t)b * Np + ip[row]) * C4 + c4];
        unsigned h0, l0, h1, l1;
        cvt2u(v.x, v.y, h0, l0);
        cvt2u(v.z, v.w, h1, l1);
        *(uint2*)&Ah[row][4 * c4] = make_uint2(h0, h1);
        *(uint2*)&Al[row][4 * c4] = make_uint2(l0, l1);
    }
    __syncthreads();
    int w = t >> 6, lane = t & 63;
    int quad = lane >> 4, col = lane & 15;
    int mrow = w * 16 + col;
    f32x4 acc[NT];
    #pragma unroll
    for (int nt = 0; nt < NT; ++nt) acc[nt] = (f32x4){0.f, 0.f, 0.f, 0.f};
    for (int ks = 0; ks < KS; ++ks) {
        int kb = ks * 32 + quad * 8;
        short8 ah = *(const short8*)&Ah[mrow][kb];
        short8 al = *(const short8*)&Al[mrow][kb];
        #pragma unroll
        for (int nt = 0; nt < NT; ++nt) {
            size_t bi = (((size_t)(ks * NT + nt)) * 64 + lane) * 8;
            short8 bh = *(const short8*)(Bh + bi);
            short8 bl = *(const short8*)(Bl + bi);
            acc[nt] = __builtin_amdgcn_mfma_f32_16x16x32_bf16(ah, bh, acc[nt], 0, 0, 0);
            acc[nt] = __builtin_amdgcn_mfma_f32_16x16x32_bf16(ah, bl, acc[nt], 0, 0, 0);
            acc[nt] = __builtin_amdgcn_mfma_f32_16x16x32_bf16(al, bh, acc[nt], 0, 0, 0);
        }
    }
    int pt = w >> 1, wi = w & 1;
    #pragma unroll
    for (int nt = 0; nt < NT; ++nt) {
        float m = fmaxf(fmaxf(acc[nt][0], acc[nt][1]), fmaxf(acc[nt][2], acc[nt][3]));
        m = fmaxf(m, __shfl_xor(m, 16, 64));
        m = fmaxf(m, __shfl_xor(m, 32, 64));
        if (lane < 16) red[pt][wi][nt * 16 + col] = m;
    }
    __syncthreads();
    for (int idx = t; idx < PTS * O; idx += 256) {
        int pp = idx / O, o = idx % O;
        float m = fmaxf(red[pp][0][o], red[pp][1][o]);
        size_t ni = (size_t)b * Np + n0 + pp;
        Ypm[ni * O + o] = lrelu(m + cb[ni * O + o]);
    }
}

// Legacy fused EdgeConv for layer 1 (C=3)
template<int C, int CPAD, int O, int OPT, int KPT, int PTS>
__global__ __launch_bounds__(256) void k_edgeconv(
    const float* __restrict__ Xpm, const int* __restrict__ idxg,
    const float* __restrict__ W, const float* __restrict__ sg, const float* __restrict__ bg,
    float* __restrict__ Ypm)
{
    constexpr int OG = O / OPT;
    constexpr int NKG = 256 / OG;
    constexpr int CL = CPAD + 4;
    static_assert(NKG * KPT == Kn, "k mapping");
    __shared__ float nbr[PTS][Kn][CL];
    __shared__ float ctr[PTS][CPAD];
    __shared__ float red[PTS][OPT][4][OG];
    int blk = blockIdx.x;
    int b = blk / (Np / PTS);
    int n0 = (blk % (Np / PTS)) * PTS;
    int t = threadIdx.x;
    int lane = t & 63, wid = t >> 6;
    const int* ip = idxg + ((size_t)b * Np + n0) * Kn;
    const float4* Xp4 = (const float4*)Xpm;
    constexpr int C4 = CPAD / 4;
    for (int e = t; e < PTS * C4; e += 256) {
        int pt = e / C4, c4 = e % C4;
        *(float4*)&ctr[pt][4 * c4] = Xp4[((size_t)b * Np + n0 + pt) * C4 + c4];
    }
    for (int e = t; e < PTS * Kn * C4; e += 256) {
        int pt = e / (Kn * C4);
        int r = e % (Kn * C4);
        int k = r / C4, c4 = r % C4;
        int nb = ip[pt * Kn + k];
        *(float4*)&nbr[pt][k][4 * c4] = Xp4[((size_t)b * Np + nb) * C4 + c4];
    }
    __syncthreads();
    int og = t % OG, kg = t / OG;
    float acc[PTS][OPT][KPT] = {};
    float ctt[PTS][OPT] = {};
    for (int c0 = 0; c0 < CPAD; c0 += 4) {
        float wn[OPT][4], wd[OPT][4];
        #pragma unroll
        for (int p = 0; p < OPT; ++p) {
            #pragma unroll
            for (int cc = 0; cc < 4; ++cc) {
                int c = c0 + cc;
                float a = (c < C) ? W[(size_t)(og + p * OG) * (2 * C) + c] : 0.f;
                float q = (c < C) ? W[(size_t)(og + p * OG) * (2 * C) + C + c] : 0.f;
                wn[p][cc] = a; wd[p][cc] = q - a;
            }
        }
        #pragma unroll
        for (int pt = 0; pt < PTS; ++pt) {
            float4 cv = *(const float4*)&ctr[pt][c0];
            #pragma unroll
            for (int p = 0; p < OPT; ++p) {
                ctt[pt][p] = fmaf(wd[p][0], cv.x, ctt[pt][p]);
                ctt[pt][p] = fmaf(wd[p][1], cv.y, ctt[pt][p]);
                ctt[pt][p] = fmaf(wd[p][2], cv.z, ctt[pt][p]);
                ctt[pt][p] = fmaf(wd[p][3], cv.w, ctt[pt][p]);
            }
        }
        #pragma unroll
        for (int pt = 0; pt < PTS; ++pt) {
            #pragma unroll
            for (int k = 0; k < KPT; ++k) {
                float4 nv = *(const float4*)&nbr[pt][kg * KPT + k][c0];
                #pragma unroll
                for (int p = 0; p < OPT; ++p) {
                    acc[pt][p][k] = fmaf(wn[p][0], nv.x, acc[pt][p][k]);
                    acc[pt][p][k] = fmaf(wn[p][1], nv.y, acc[pt][p][k]);
                    acc[pt][p][k] = fmaf(wn[p][2], nv.z, acc[pt][p][k]);
                    acc[pt][p][k] = fmaf(wn[p][3], nv.w, acc[pt][p][k]);
                }
            }
        }
    }
    #pragma unroll
    for (int pt = 0; pt < PTS; ++pt) {
        #pragma unroll
        for (int p = 0; p < OPT; ++p) {
            int o = og + p * OG;
            float sv = sg[o], bv = bg[o];
            float m = -INFINITY;
            #pragma unroll
            for (int k = 0; k < KPT; ++k) {
                float hv = fmaf(acc[pt][p][k] + ctt[pt][p], sv, bv);
                m = fmaxf(m, lrelu(hv));
            }
            #pragma unroll
            for (int s = OG; s < 64; s <<= 1) m = fmaxf(m, __shfl_xor(m, s, 64));
            if (lane < OG) red[pt][p][wid][lane] = m;
        }
    }
    __syncthreads();
    if (t < OG) {
        #pragma unroll
        for (int pt = 0; pt < PTS; ++pt) {
            #pragma unroll
            for (int p = 0; p < OPT; ++p) {
                float m = fmaxf(fmaxf(red[pt][p][0][t], red[pt][p][1][t]),
                                fmaxf(red[pt][p][2][t], red[pt][p][3][t]));
                int o = t + p * OG;
                Ypm[((size_t)b * Np + n0 + pt) * O + o] = m;
            }
        }
    }
}

// MFMA W5 (K=512, O=1024) + bias + LeakyReLU + max/sum pool over 32 points -> partials.
// v2: 1024 threads / 16 waves, each wave owns 4 o-tiles; __launch_bounds__(1024,4) caps VGPR<=128
// so the 16-wave block fits at 4 waves/SIMD -> 16 waves/CU (2x round-9 occupancy).
__global__ __launch_bounds__(1024, 4) void k_w5mfma(
    const float* __restrict__ x1, const float* __restrict__ x2,
    const float* __restrict__ x3, const float* __restrict__ x4,
    const ushortT* __restrict__ Bh, const ushortT* __restrict__ Bl,
    const float* __restrict__ b5,
    float* __restrict__ pmax, float* __restrict__ psum)
{
    constexpr int CP = 520;                 // 512 + 8 pad
    extern __shared__ char smem[];
    ushortT* Ah = (ushortT*)smem;           // [32][CP]
    ushortT* Al = Ah + 32 * CP;             // [32][CP]
    int b = blockIdx.x >> 6;
    int chunk = blockIdx.x & 63;
    int n0 = chunk * 32;
    int t = threadIdx.x;
    for (int e = t; e < 32 * 128; e += 1024) {
        int pt = e >> 7, c4 = e & 127;
        size_t pi = (size_t)b * Np + n0 + pt;
        float4 v;
        if (c4 < 16)      v = ((const float4*)x1)[pi * 16 + c4];
        else if (c4 < 32) v = ((const float4*)x2)[pi * 16 + (c4 - 16)];
        else if (c4 < 64) v = ((const float4*)x3)[pi * 32 + (c4 - 32)];
        else              v = ((const float4*)x4)[pi * 64 + (c4 - 64)];
        unsigned h0, l0, h1, l1;
        cvt2u(v.x, v.y, h0, l0);
        cvt2u(v.z, v.w, h1, l1);
        *(uint2*)&Ah[pt * CP + 4 * c4] = make_uint2(h0, h1);
        *(uint2*)&Al[pt * CP + 4 * c4] = make_uint2(l0, l1);
    }
    __syncthreads();
    int w = t >> 6, lane = t & 63;
    int quad = lane >> 4, col = lane & 15;
    size_t pb = ((size_t)(b * 64 + chunk)) * 1024;
    for (int oi = 0; oi < 4; ++oi) {
        int nt = w * 4 + oi;
        f32x4 a0 = (f32x4){0.f, 0.f, 0.f, 0.f};
        f32x4 a1 = (f32x4){0.f, 0.f, 0.f, 0.f};
        #pragma unroll 2
        for (int ks = 0; ks < 16; ++ks) {
            size_t bi = (((size_t)(ks * 64 + nt)) * 64 + lane) * 8;
            short8 bh = *(const short8*)(Bh + bi);
            short8 bl = *(const short8*)(Bl + bi);
            int ao = ks * 32 + quad * 8;
            short8 ah0 = *(const short8*)&Ah[col * CP + ao];
            short8 al0 = *(const short8*)&Al[col * CP + ao];
            short8 ah1 = *(const short8*)&Ah[(16 + col) * CP + ao];
            short8 al1 = *(const short8*)&Al[(16 + col) * CP + ao];
            a0 = __builtin_amdgcn_mfma_f32_16x16x32_bf16(ah0, bh, a0, 0, 0, 0);
            a1 = __builtin_amdgcn_mfma_f32_16x16x32_bf16(ah1, bh, a1, 0, 0, 0);
            a0 = __builtin_amdgcn_mfma_f32_16x16x32_bf16(ah0, bl, a0, 0, 0, 0);
            a1 = __builtin_amdgcn_mfma_f32_16x16x32_bf16(ah1, bl, a1, 0, 0, 0);
            a0 = __builtin_amdgcn_mfma_f32_16x16x32_bf16(al0, bh, a0, 0, 0, 0);
            a1 = __builtin_amdgcn_mfma_f32_16x16x32_bf16(al1, bh, a1, 0, 0, 0);
        }
        float bb = b5[nt * 16 + col];
        float mx = -INFINITY, sm = 0.f;
        #pragma unroll
        for (int r = 0; r < 4; ++r) {
            float v0 = lrelu(a0[r] + bb);
            float v1 = lrelu(a1[r] + bb);
            mx = fmaxf(mx, fmaxf(v0, v1));
            sm += v0 + v1;
        }
        mx = fmaxf(mx, __shfl_xor(mx, 16, 64));
        mx = fmaxf(mx, __shfl_xor(mx, 32, 64));
        sm += __shfl_xor(sm, 16, 64);
        sm += __shfl_xor(sm, 32, 64);
        if (lane < 16) {
            pmax[pb + nt * 16 + col] = mx;
            psum[pb + nt * 16 + col] = sm;
        }
    }
}

__global__ __launch_bounds__(256) void k_poolred(const float* __restrict__ pmax, const float* __restrict__ psum,
                                                 float* __restrict__ g0) {
    int i = blockIdx.x * 256 + threadIdx.x;
    int b = i >> 10, o = i & 1023;
    float mx = -INFINITY, sm = 0.f;
    for (int ch = 0; ch < 64; ++ch) {
        size_t idx = ((size_t)(b * 64 + ch)) * 1024 + o;
        mx = fmaxf(mx, pmax[idx]);
        sm += psum[idx];
    }
    g0[(size_t)b * 2048 + o] = mx;
    g0[(size_t)b * 2048 + 1024 + o] = sm * (1.f / Np);
}

__global__ __launch_bounds__(256) void k_fc(const float* __restrict__ In, int ldIn, int C,
                                            const float* __restrict__ Wm,
                                            const float* __restrict__ bias,
                                            const float* __restrict__ sc, const float* __restrict__ bnb,
                                            int leaky, float* __restrict__ Out, int ldOut, int O) {
    int wid = threadIdx.x >> 6, lane = threadIdx.x & 63;
    int o = blockIdx.x * 4 + wid;
    int b = blockIdx.y;
    if (o >= O) return;
    const float* in = In + (size_t)b * ldIn;
    const float* wr = Wm + (size_t)o * C;
    float acc = 0.f;
    for (int c = lane; c < C; c += 64) acc = fmaf(in[c], wr[c], acc);
    #pragma unroll
    for (int off = 32; off; off >>= 1) acc += __shfl_down(acc, off, 64);
    if (lane == 0) {
        float v = acc + (bias ? bias[o] : 0.f);
        if (sc) v = fmaf(v, sc[o], bnb[o]);
        if (leaky) v = lrelu(v);
        Out[(size_t)b * ldOut + o] = v;
    }
}

extern "C" void kernel_launch(void* const* d_in, const int* in_sizes, int n_in,
                              void* d_out, int out_size, void* d_ws, size_t ws_size,
                              hipStream_t stream) {
    const float* x   = (const float*)d_in[0];
    const float* W1  = (const float*)d_in[1];
    const float* s1  = (const float*)d_in[2];
    const float* b1  = (const float*)d_in[3];
    const float* W2  = (const float*)d_in[4];
    const float* s2  = (const float*)d_in[5];
    const float* b2  = (const float*)d_in[6];
    const float* W3  = (const float*)d_in[7];
    const float* s3  = (const float*)d_in[8];
    const float* b3  = (const float*)d_in[9];
    const float* W4  = (const float*)d_in[10];
    const float* s4  = (const float*)d_in[11];
    const float* b4  = (const float*)d_in[12];
    const float* W5  = (const float*)d_in[13];
    const float* s5  = (const float*)d_in[14];
    const float* b5  = (const float*)d_in[15];
    const float* L1w = (const float*)d_in[16];
    const float* s6  = (const float*)d_in[17];
    const float* b6  = (const float*)d_in[18];
    const float* L2w = (const float*)d_in[19];
    const float* L2b = (const float*)d_in[20];
    const float* s7  = (const float*)d_in[21];
    const float* b7  = (const float*)d_in[22];
    const float* L3w = (const float*)d_in[23];
    const float* L3b = (const float*)d_in[24];
    const float* F1w = (const float*)d_in[25];
    const float* s8  = (const float*)d_in[26];
    const float* b8  = (const float*)d_in[27];
    const float* F2w = (const float*)d_in[28];
    const float* F2b = (const float*)d_in[29];
    const float* s9  = (const float*)d_in[30];
    const float* b9  = (const float*)d_in[31];
    const float* F3w = (const float*)d_in[32];
    const float* F3b = (const float*)d_in[33];

    float* ws = (float*)d_ws;
    size_t off = 0;
    auto alloc = [&](size_t n) { float* p = ws + off; off += n; return p; };
    float* pts  = alloc((size_t)Bn * Np * 4);
    float* x1   = alloc((size_t)Bn * Np * 64);
    float* x2   = alloc((size_t)Bn * Np * 64);
    float* x3   = alloc((size_t)Bn * Np * 128);
    float* x4   = alloc((size_t)Bn * Np * 256);
    float* xcm  = alloc((size_t)Bn * Np * 128);   // aliased: pmax / psum
    float* xxb  = alloc((size_t)Bn * Np);
    int*   idxb = (int*)alloc((size_t)Bn * Np * Kn);
    float* g0   = alloc((size_t)Bn * 2048);
    float* g1   = alloc((size_t)Bn * 512);
    float* g2   = alloc((size_t)Bn * 256);
    float* y1   = alloc((size_t)Bn * 512);
    float* y2   = alloc((size_t)Bn * 256);
    float* WnsT2 = alloc(64 * 64);
    float* WdsT2 = alloc(64 * 64);
    float* WnsT3 = alloc(64 * 128);
    float* WdsT3 = alloc(64 * 128);
    float* WnsT4 = alloc(128 * 256);
    float* WdsT4 = alloc(128 * 256);
    ushortT* Bh2 = (ushortT*)alloc(64 * 64 / 2);
    ushortT* Bl2 = (ushortT*)alloc(64 * 64 / 2);
    ushortT* Bh3 = (ushortT*)alloc(64 * 128 / 2);
    ushortT* Bl3 = (ushortT*)alloc(64 * 128 / 2);
    ushortT* Bh4 = (ushortT*)alloc(128 * 256 / 2);
    ushortT* Bl4 = (ushortT*)alloc(128 * 256 / 2);
    ushortT* BhK = (ushortT*)alloc(1048576);   // knn B-frag hi (max C=128: 2M shorts)
    ushortT* BlK = (ushortT*)alloc(1048576);
    ushortT* Bh5 = (ushortT*)alloc(262144);    // W5 frag hi: 512K shorts
    ushortT* Bl5 = (ushortT*)alloc(262144);
    float* pmax = xcm;
    float* psum = xcm + 524288;
    float* cb2 = x2;
    float* cb3 = x3;
    float* cb4 = x4;

    // dynamic-LDS opt-ins (idempotent, safe pre-capture)
    auto shsz = [](int CP) { return 16 * CP * 2 * 2 + 64 + 16 * 2050 * 4; };
    int sh3 = shsz(40), sh64 = shsz(72), sh128 = shsz(136);
    int shw5 = 32 * 520 * 2 * 2;
    hipFuncSetAttribute((const void*)k_knn4<3, 32, 4>, hipFuncAttributeMaxDynamicSharedMemorySize, sh3);
    hipFuncSetAttribute((const void*)k_knn4<64, 64, 64>, hipFuncAttributeMaxDynamicSharedMemorySize, sh64);
    hipFuncSetAttribute((const void*)k_knn4<128, 128, 128>, hipFuncAttributeMaxDynamicSharedMemorySize, sh128);
    hipFuncSetAttribute((const void*)k_w5mfma, hipFuncAttributeMaxDynamicSharedMemorySize, shw5);

    k_transpose<<<Bn * Np / 256, 256, 0, stream>>>(x, pts);
    k_wsplit<<<16, 256, 0, stream>>>(W2, s2, 64, 64, WnsT2, WdsT2);
    k_wsplit<<<32, 256, 0, stream>>>(W3, s3, 64, 128, WnsT3, WdsT3);
    k_wsplit<<<128, 256, 0, stream>>>(W4, s4, 128, 256, WnsT4, WdsT4);
    k_wpack<<<16, 256, 0, stream>>>(W2, s2, 64, 64, Bh2, Bl2);
    k_wpack<<<32, 256, 0, stream>>>(W3, s3, 64, 128, Bh3, Bl3);
    k_wpack<<<128, 256, 0, stream>>>(W4, s4, 128, 256, Bh4, Bl4);
    k_w5pack<<<2048, 256, 0, stream>>>(W5, s5, Bh5, Bl5);

    // Layer 1: C=3
    k_xx<<<Bn * Np / 4, 256, 0, stream>>>(pts, xxb, 3, 4);
    k_bpack<3, 32, 4><<<2048, 256, 0, stream>>>(pts, BhK, BlK);
    k_knn4<3, 32, 4><<<Bn * Np / 16, 1024, sh3, stream>>>(pts, BhK, BlK, xxb, idxb);
    k_edgeconv<3, 4, 64, 1, 8, 4><<<Bn * Np / 4, 256, 0, stream>>>(pts, idxb, W1, s1, b1, x1);

    // Layer 2: C=64 -> O=64
    k_xx<<<Bn * Np / 4, 256, 0, stream>>>(x1, xxb, 64, 64);
    k_bpack<64, 64, 64><<<4096, 256, 0, stream>>>(x1, BhK, BlK);
    k_knn4<64, 64, 64><<<Bn * Np / 16, 1024, sh64, stream>>>(x1, BhK, BlK, xxb, idxb);
    k_ctr<64, 64, 4><<<Bn * Np / 32, 256, 0, stream>>>(x1, WdsT2, b2, cb2);
    k_ec3<64, 64, 2><<<Bn * Np / 2, 256, 0, stream>>>(x1, idxb, Bh2, Bl2, cb2, x2);

    // Layer 3: C=64 -> O=128
    k_xx<<<Bn * Np / 4, 256, 0, stream>>>(x2, xxb, 64, 64);
    k_bpack<64, 64, 64><<<4096, 256, 0, stream>>>(x2, BhK, BlK);
    k_knn4<64, 64, 64><<<Bn * Np / 16, 1024, sh64, stream>>>(x2, BhK, BlK, xxb, idxb);
    k_ctr<64, 128, 8><<<Bn * Np / 32, 256, 0, stream>>>(x2, WdsT3, b3, cb3);
    k_ec3<64, 128, 2><<<Bn * Np / 2, 256, 0, stream>>>(x2, idxb, Bh3, Bl3, cb3, x3);

    // Layer 4: C=128 -> O=256
    k_xx<<<Bn * Np / 4, 256, 0, stream>>>(x3, xxb, 128, 128);
    k_bpack<128, 128, 128><<<8192, 256, 0, stream>>>(x3, BhK, BlK);
    k_knn4<128, 128, 128><<<Bn * Np / 16, 1024, sh128, stream>>>(x3, BhK, BlK, xxb, idxb);
    k_ctr<128, 256, 8><<<Bn * Np / 32, 256, 0, stream>>>(x3, WdsT4, b4, cb4);
    k_ec3<128, 256, 2><<<Bn * Np / 2, 256, 0, stream>>>(x3, idxb, Bh4, Bl4, cb4, x4);

    // W5 + pooling (MFMA, 16-wave blocks)
    k_w5mfma<<<Bn * 64, 1024, shw5, stream>>>(x1, x2, x3, x4, Bh5, Bl5, b5, pmax, psum);
    k_poolred<<<Bn * 1024 / 256, 256, 0, stream>>>(pmax, psum, g0);

    float* out = (float*)d_out;
    k_fc<<<dim3(128, Bn), 256, 0, stream>>>(g0, 2048, 2048, L1w, nullptr, s6, b6, 1, g1, 512, 512);
    k_fc<<<dim3(64, Bn), 256, 0, stream>>>(g1, 512, 512, L2w, L2b, s7, b7, 1, g2, 256, 256);
    k_fc<<<dim3(2, Bn), 256, 0, stream>>>(g2, 256, 256, L3w, L3b, nullptr, nullptr, 0, out, 5, 5);
    k_fc<<<dim3(128, Bn), 256, 0, stream>>>(g0, 2048, 1024, F1w, nullptr, s8, b8, 1, y1, 512, 512);
    k_fc<<<dim3(64, Bn), 256, 0, stream>>>(y1, 512, 512, F2w, F2b, s9, b9, 1, y2, 256, 256);
    k_fc<<<dim3(2, Bn), 256, 0, stream>>>(y2, 256, 256, F3w, F3b, nullptr, nullptr, 0, out + 40, 5, 5);
}

// Round 11
// 974.473 us; speedup vs baseline: 4.4086x; 1.0750x over previous
//
#include <hip/hip_runtime.h>
#include <math.h>

constexpr int Bn = 8;
constexpr int Np = 2048;
constexpr int Kn = 32;
constexpr float NEGS = 0.2f;

typedef __attribute__((ext_vector_type(8))) short short8;
typedef __attribute__((ext_vector_type(4))) float f32x4;
typedef unsigned short ushortT;

__device__ __forceinline__ float lrelu(float v) { return v > 0.f ? v : NEGS * v; }

// split fp32 -> bf16 hi (truncate) + bf16 lo (residual, truncate); packed 2-at-a-time
__device__ __forceinline__ void cvt2u(float a, float b, unsigned& h, unsigned& l) {
    unsigned ua = __float_as_uint(a), ub = __float_as_uint(b);
    h = (ua >> 16) | (ub & 0xffff0000u);
    float ra = a - __uint_as_float(ua & 0xffff0000u);
    float rb = b - __uint_as_float(ub & 0xffff0000u);
    l = (__float_as_uint(ra) >> 16) | (__float_as_uint(rb) & 0xffff0000u);
}

// x [B,3,N] -> pts point-major [B*N, 4] (pad lane = 0)
__global__ __launch_bounds__(256) void k_transpose(const float* __restrict__ x, float* __restrict__ pts) {
    int i = blockIdx.x * 256 + threadIdx.x;
    int b = i / Np, n = i % Np;
    float p0 = x[((size_t)b * 3 + 0) * Np + n];
    float p1 = x[((size_t)b * 3 + 1) * Np + n];
    float p2 = x[((size_t)b * 3 + 2) * Np + n];
    float4 v = make_float4(p0, p1, p2, 0.f);
    *(float4*)&pts[(size_t)i * 4] = v;
}

// xx[i] = sum_c pm[i*ld+c]^2 ; one wave per point, 4 points per block
__global__ __launch_bounds__(256) void k_xx(const float* __restrict__ pm, float* __restrict__ xxg, int C, int ld) {
    int wid = threadIdx.x >> 6, lane = threadIdx.x & 63;
    int pt = blockIdx.x * 4 + wid;
    const float* row = pm + (size_t)pt * ld;
    float acc = 0.f;
    for (int c = lane; c < C; c += 64) { float v = row[c]; acc = fmaf(v, v, acc); }
    #pragma unroll
    for (int off = 32; off; off >>= 1) acc += __shfl_down(acc, off, 64);
    if (lane == 0) xxg[pt] = acc;
}

// Pack points into mfma_16x16x32 B-fragment order (bf16 hi/lo), per batch.
template<int C, int CK, int LD>
__global__ __launch_bounds__(256) void k_bpack(const float* __restrict__ Xpm,
                                               ushortT* __restrict__ Bh, ushortT* __restrict__ Bl) {
    constexpr int KS = CK / 32;
    int i = blockIdx.x * 256 + threadIdx.x;
    int j = i & 7;
    int lane = (i >> 3) & 63;
    int nt = (i >> 9) & 127;
    int rest = i >> 16;
    int ks = rest % KS;
    int b = rest / KS;
    int k = ks * 32 + (lane >> 4) * 8 + j;
    int n = nt * 16 + (lane & 15);
    float v = (k < C) ? Xpm[((size_t)b * Np + n) * LD + k] : 0.f;
    unsigned u = __float_as_uint(v);
    Bh[i] = (ushortT)(u >> 16);
    float r = v - __uint_as_float(u & 0xffff0000u);
    Bl[i] = (ushortT)(__float_as_uint(r) >> 16);
}

// MFMA kNN v5: distance phase split-bf16 MFMA; selection value-only butterfly + ballot owner.
template<int C, int CK, int LD>
__global__ __launch_bounds__(1024) void k_knn4(const float* __restrict__ Xpm,
                                               const ushortT* __restrict__ Bh, const ushortT* __restrict__ Bl,
                                               const float* __restrict__ xxg, int* __restrict__ idxo) {
    constexpr int KS = CK / 32, CP = CK + 8, CK4 = CK / 4, C4src = LD / 4;
    constexpr int SD = 2050;
    extern __shared__ char smem[];
    ushortT* Ah = (ushortT*)smem;              // [16][CP]
    ushortT* Al = Ah + 16 * CP;                // [16][CP]
    float* xxm = (float*)(Al + 16 * CP);       // [16]
    float* dl = xxm + 16;                      // [16][SD] distances
    int b = blockIdx.x / (Np / 16);
    int n0 = (blockIdx.x % (Np / 16)) * 16;
    int t = threadIdx.x;
    const float4* Xp4 = (const float4*)Xpm;
    for (int e = t; e < 16 * CK4; e += 1024) {
        int r = e / CK4, c4 = e % CK4;
        float4 v = (c4 < C4src) ? Xp4[((size_t)b * Np + n0 + r) * C4src + c4] : make_float4(0.f, 0.f, 0.f, 0.f);
        unsigned h0, l0, h1, l1;
        cvt2u(v.x, v.y, h0, l0);
        cvt2u(v.z, v.w, h1, l1);
        *(uint2*)&Ah[r * CP + 4 * c4] = make_uint2(h0, h1);
        *(uint2*)&Al[r * CP + 4 * c4] = make_uint2(l0, l1);
    }
    if (t < 16) xxm[t] = xxg[b * Np + n0 + t];
    __syncthreads();

    int w = t >> 6, lane = t & 63;
    int quad = lane >> 4, col = lane & 15;
    short8 ah[KS], al[KS];
    #pragma unroll
    for (int ks = 0; ks < KS; ++ks) {
        ah[ks] = *(const short8*)&Ah[col * CP + ks * 32 + quad * 8];
        al[ks] = *(const short8*)&Al[col * CP + ks * 32 + quad * 8];
    }
    float xmr[4];
    #pragma unroll
    for (int r = 0; r < 4; ++r) xmr[r] = xxm[quad * 4 + r];

    for (int i = 0; i < 4; ++i) {
        int nt0 = w * 8 + 2 * i, nt1 = nt0 + 1;
        f32x4 a0 = (f32x4){0.f, 0.f, 0.f, 0.f};
        f32x4 a1 = (f32x4){0.f, 0.f, 0.f, 0.f};
        #pragma unroll
        for (int ks = 0; ks < KS; ++ks) {
            int bi0 = (((b * KS + ks) * 128 + nt0) * 64 + lane) * 8;
            int bi1 = (((b * KS + ks) * 128 + nt1) * 64 + lane) * 8;
            short8 bh0 = *(const short8*)(Bh + bi0);
            short8 bl0 = *(const short8*)(Bl + bi0);
            short8 bh1 = *(const short8*)(Bh + bi1);
            short8 bl1 = *(const short8*)(Bl + bi1);
            a0 = __builtin_amdgcn_mfma_f32_16x16x32_bf16(ah[ks], bh0, a0, 0, 0, 0);
            a1 = __builtin_amdgcn_mfma_f32_16x16x32_bf16(ah[ks], bh1, a1, 0, 0, 0);
            a0 = __builtin_amdgcn_mfma_f32_16x16x32_bf16(ah[ks], bl0, a0, 0, 0, 0);
            a1 = __builtin_amdgcn_mfma_f32_16x16x32_bf16(ah[ks], bl1, a1, 0, 0, 0);
            a0 = __builtin_amdgcn_mfma_f32_16x16x32_bf16(al[ks], bh0, a0, 0, 0, 0);
            a1 = __builtin_amdgcn_mfma_f32_16x16x32_bf16(al[ks], bh1, a1, 0, 0, 0);
        }
        float xn0 = xxg[b * Np + nt0 * 16 + col];
        float xn1 = xxg[b * Np + nt1 * 16 + col];
        #pragma unroll
        for (int r = 0; r < 4; ++r) {
            int m = quad * 4 + r;
            dl[m * SD + nt0 * 16 + col] = 2.f * a0[r] - xmr[r] - xn0;
            dl[m * SD + nt1 * 16 + col] = 2.f * a1[r] - xmr[r] - xn1;
        }
    }
    __syncthreads();

    // ---- selection: wave w owns row w ----
    const float* drow = dl + w * SD;
    float v[32];
    #pragma unroll
    for (int j = 0; j < 32; ++j) v[j] = drow[lane + 64 * j];
    float gv0, gv1, gv2, gv3;
    int gj0, gj1, gj2, gj3;
    gv0 = v[0]; gj0 = 0;
    #pragma unroll
    for (int e = 1; e < 8; ++e) if (v[e] > gv0) { gv0 = v[e]; gj0 = e; }
    gv1 = v[8]; gj1 = 8;
    #pragma unroll
    for (int e = 1; e < 8; ++e) if (v[8 + e] > gv1) { gv1 = v[8 + e]; gj1 = 8 + e; }
    gv2 = v[16]; gj2 = 16;
    #pragma unroll
    for (int e = 1; e < 8; ++e) if (v[16 + e] > gv2) { gv2 = v[16 + e]; gj2 = 16 + e; }
    gv3 = v[24]; gj3 = 24;
    #pragma unroll
    for (int e = 1; e < 8; ++e) if (v[24 + e] > gv3) { gv3 = v[24 + e]; gj3 = 24 + e; }

    size_t ob = ((size_t)b * Np + n0 + w) * Kn;
    for (int it = 0; it < Kn; ++it) {
        float lv = fmaxf(fmaxf(gv0, gv1), fmaxf(gv2, gv3));
        float Wv = lv;
        #pragma unroll
        for (int off = 1; off < 64; off <<= 1) Wv = fmaxf(Wv, __shfl_xor(Wv, off, 64));
        unsigned long long mk = __ballot(lv == Wv);
        int owner = __ffsll(mk) - 1;
        if (lane == owner) {
            int lj;
            if (gv0 == Wv) lj = gj0;
            else if (gv1 == Wv) lj = gj1;
            else if (gv2 == Wv) lj = gj2;
            else lj = gj3;
            idxo[ob + it] = lane + 64 * lj;
            int gg = lj >> 3;
            if (gg == 0) {
                #pragma unroll
                for (int e = 0; e < 8; ++e) if (e == lj) v[e] = -INFINITY;
                gv0 = v[0]; gj0 = 0;
                #pragma unroll
                for (int e = 1; e < 8; ++e) if (v[e] > gv0) { gv0 = v[e]; gj0 = e; }
            } else if (gg == 1) {
                #pragma unroll
                for (int e = 0; e < 8; ++e) if (8 + e == lj) v[8 + e] = -INFINITY;
                gv1 = v[8]; gj1 = 8;
                #pragma unroll
                for (int e = 1; e < 8; ++e) if (v[8 + e] > gv1) { gv1 = v[8 + e]; gj1 = 8 + e; }
            } else if (gg == 2) {
                #pragma unroll
                for (int e = 0; e < 8; ++e) if (16 + e == lj) v[16 + e] = -INFINITY;
                gv2 = v[16]; gj2 = 16;
                #pragma unroll
                for (int e = 1; e < 8; ++e) if (v[16 + e] > gv2) { gv2 = v[16 + e]; gj2 = 16 + e; }
            } else {
                #pragma unroll
                for (int e = 0; e < 8; ++e) if (24 + e == lj) v[24 + e] = -INFINITY;
                gv3 = v[24]; gj3 = 24;
                #pragma unroll
                for (int e = 1; e < 8; ++e) if (v[24 + e] > gv3) { gv3 = v[24 + e]; gj3 = 24 + e; }
            }
        }
    }
}

// W split+scale+transpose (fp32, for k_ctr): WdsT[c][o] = (W[o][C+c]-W[o][c])*s[o]
__global__ __launch_bounds__(256) void k_wsplit(const float* __restrict__ W, const float* __restrict__ s,
                                                int C, int O, float* __restrict__ WnsT, float* __restrict__ WdsT) {
    int i = blockIdx.x * 256 + threadIdx.x;
    if (i >= C * O) return;
    int c = i / O, o = i % O;
    float a = W[(size_t)o * 2 * C + c];
    float q = W[(size_t)o * 2 * C + C + c];
    float sv = s[o];
    WnsT[i] = a * sv;
    WdsT[i] = (q - a) * sv;
}

// Pack neighbor-half of W (scaled) into mfma_16x16x32 B-fragment order, split bf16 hi/lo.
__global__ __launch_bounds__(256) void k_wpack(const float* __restrict__ W, const float* __restrict__ s,
                                               int C, int O, ushortT* __restrict__ Bh, ushortT* __restrict__ Bl) {
    int i = blockIdx.x * 256 + threadIdx.x;
    if (i >= C * O) return;
    int k = i / O, o = i % O;
    float v = W[(size_t)o * 2 * C + k] * s[o];
    int ks = k >> 5, quad = (k >> 3) & 3, j = k & 7;
    int nt = o >> 4, lane = quad * 16 + (o & 15);
    int NT = O / 16;
    size_t idx = (((size_t)(ks * NT + nt)) * 64 + lane) * 8 + j;
    unsigned u = __float_as_uint(v);
    Bh[idx] = (ushortT)(u >> 16);
    float r = v - __uint_as_float(u & 0xffff0000u);
    Bl[idx] = (ushortT)(__float_as_uint(r) >> 16);
}

// Pack W5 (scaled by s5) [1024][512] into fragment order: KS=16, NT=64.
__global__ __launch_bounds__(256) void k_w5pack(const float* __restrict__ W5, const float* __restrict__ s5,
                                                ushortT* __restrict__ Bh, ushortT* __restrict__ Bl) {
    int i = blockIdx.x * 256 + threadIdx.x;   // 512*1024
    int k = i >> 10, o = i & 1023;
    float v = W5[(size_t)o * 512 + k] * s5[o];
    int ks = k >> 5, quad = (k >> 3) & 3, j = k & 7;
    int nt = o >> 4, lane = quad * 16 + (o & 15);
    size_t idx = (((size_t)(ks * 64 + nt)) * 64 + lane) * 8 + j;
    unsigned u = __float_as_uint(v);
    Bh[idx] = (ushortT)(u >> 16);
    float r = v - __uint_as_float(u & 0xffff0000u);
    Bl[idx] = (ushortT)(__float_as_uint(r) >> 16);
}

// cb[n][o] = sum_c ctr[n][c]*WdsT[c][o] + b[o].  32 points per block.
template<int C, int O, int OPT>
__global__ __launch_bounds__(256) void k_ctr(const float* __restrict__ Xpm, const float* __restrict__ WdsT,
                                             const float* __restrict__ bg, float* __restrict__ cb) {
    constexpr int OG = O / OPT, MG = 256 / OG, MPT = 32 / MG;
    constexpr int C4 = C / 4;
    __shared__ float xs[32][C];
    int b = blockIdx.x / (Np / 32);
    int n0 = (blockIdx.x % (Np / 32)) * 32;
    int t = threadIdx.x;
    const float4* Xp4 = (const float4*)Xpm;
    for (int e = t; e < 32 * C4; e += 256) {
        int pt = e / C4, c4 = e % C4;
        *(float4*)&xs[pt][4 * c4] = Xp4[((size_t)b * Np + n0 + pt) * C4 + c4];
    }
    __syncthreads();
    int og = t % OG, mg = t / OG;
    int o0 = og * OPT;
    float acc[MPT][OPT] = {};
    for (int c = 0; c < C; ++c) {
        float wv[OPT];
        #pragma unroll
        for (int p4 = 0; p4 < OPT / 4; ++p4)
            *(float4*)&wv[4 * p4] = *(const float4*)&WdsT[(size_t)c * O + o0 + 4 * p4];
        #pragma unroll
        for (int m = 0; m < MPT; ++m) {
            float xv = xs[mg * MPT + m][c];
            #pragma unroll
            for (int p = 0; p < OPT; ++p) acc[m][p] = fmaf(wv[p], xv, acc[m][p]);
        }
    }
    #pragma unroll
    for (int m = 0; m < MPT; ++m) {
        #pragma unroll
        for (int p = 0; p < OPT; ++p) {
            int o = o0 + p;
            cb[((size_t)b * Np + n0 + mg * MPT + m) * O + o] = acc[m][p] + bg[o];
        }
    }
}

// MFMA EdgeConv GEMM v2 (split-bf16): waves split the O dimension (B fragments read ONCE
// per block), each wave loops all 4 m-tiles from LDS. Per-point k-max is wave-local
// (2 m-tiles + 4 regs + shfl 16/32) -> direct global write, no red[] LDS, one barrier.
template<int C, int O, int PTS>
__global__ __launch_bounds__(256, 4) void k_ec3(const float* __restrict__ Xpm, const int* __restrict__ idxg,
                                                const ushortT* __restrict__ Bh, const ushortT* __restrict__ Bl,
                                                const float* __restrict__ cb,
                                                float* __restrict__ Ypm) {
    static_assert(PTS == 2, "M=64 mapping");
    constexpr int M = 64, NT = O / 16, NT4 = NT / 4, KS = C / 32, C4 = C / 4, CP = C + 8;
    static_assert(NT4 >= 1, "O>=64");
    __shared__ ushortT Ah[M][CP];
    __shared__ ushortT Al[M][CP];
    int b = blockIdx.x / (Np / PTS);
    int n0 = (blockIdx.x % (Np / PTS)) * PTS;
    int t = threadIdx.x;
    const int* ip = idxg + ((size_t)b * Np + n0) * Kn;
    const float4* Xp4 = (const float4*)Xpm;
    for (int e = t; e < M * C4; e += 256) {
        int row = e / C4, c4 = e % C4;
        float4 v = Xp4[((size_t)b * Np + ip[row]) * C4 + c4];
        unsigned h0, l0, h1, l1;
        cvt2u(v.x, v.y, h0, l0);
        cvt2u(v.z, v.w, h1, l1);
        *(uint2*)&Ah[row][4 * c4] = make_uint2(h0, h1);
        *(uint2*)&Al[row][4 * c4] = make_uint2(l0, l1);
    }
    __syncthreads();
    int w = t >> 6, lane = t & 63;
    int quad = lane >> 4, col = lane & 15;
    f32x4 acc[4][NT4];
    #pragma unroll
    for (int mt = 0; mt < 4; ++mt)
        #pragma unroll
        for (int i = 0; i < NT4; ++i) acc[mt][i] = (f32x4){0.f, 0.f, 0.f, 0.f};
    for (int ks = 0; ks < KS; ++ks) {
        int kb = ks * 32 + quad * 8;
        short8 ah[4], al[4];
        #pragma unroll
        for (int mt = 0; mt < 4; ++mt) {
            ah[mt] = *(const short8*)&Ah[mt * 16 + col][kb];
            al[mt] = *(const short8*)&Al[mt * 16 + col][kb];
        }
        #pragma unroll
        for (int i = 0; i < NT4; ++i) {
            int nt = w * NT4 + i;
            size_t bi = (((size_t)(ks * NT + nt)) * 64 + lane) * 8;
            short8 bh = *(const short8*)(Bh + bi);
            short8 bl = *(const short8*)(Bl + bi);
            #pragma unroll
            for (int mt = 0; mt < 4; ++mt) {
                acc[mt][i] = __builtin_amdgcn_mfma_f32_16x16x32_bf16(ah[mt], bh, acc[mt][i], 0, 0, 0);
                acc[mt][i] = __builtin_amdgcn_mfma_f32_16x16x32_bf16(ah[mt], bl, acc[mt][i], 0, 0, 0);
                acc[mt][i] = __builtin_amdgcn_mfma_f32_16x16x32_bf16(al[mt], bh, acc[mt][i], 0, 0, 0);
            }
        }
    }
    // epilogue: per point pt, rows live in m-tiles {2pt, 2pt+1}; D row=quad*4+r, col=o.
    #pragma unroll
    for (int pt = 0; pt < PTS; ++pt) {
        size_t ni = (size_t)b * Np + n0 + pt;
        #pragma unroll
        for (int i = 0; i < NT4; ++i) {
            f32x4 a0 = acc[2 * pt][i], a1 = acc[2 * pt + 1][i];
            float m = fmaxf(fmaxf(fmaxf(a0[0], a0[1]), fmaxf(a0[2], a0[3])),
                            fmaxf(fmaxf(a1[0], a1[1]), fmaxf(a1[2], a1[3])));
            m = fmaxf(m, __shfl_xor(m, 16, 64));
            m = fmaxf(m, __shfl_xor(m, 32, 64));
            if (lane < 16) {
                int o = (w * NT4 + i) * 16 + col;
                Ypm[ni * O + o] = lrelu(m + cb[ni * O + o]);
            }
        }
    }
}

// Legacy fused EdgeConv for layer 1 (C=3)
template<int C, int CPAD, int O, int OPT, int KPT, int PTS>
__global__ __launch_bounds__(256) void k_edgeconv(
    const float* __restrict__ Xpm, const int* __restrict__ idxg,
    const float* __restrict__ W, const float* __restrict__ sg, const float* __restrict__ bg,
    float* __restrict__ Ypm)
{
    constexpr int OG = O / OPT;
    constexpr int NKG = 256 / OG;
    constexpr int CL = CPAD + 4;
    static_assert(NKG * KPT == Kn, "k mapping");
    __shared__ float nbr[PTS][Kn][CL];
    __shared__ float ctr[PTS][CPAD];
    __shared__ float red[PTS][OPT][4][OG];
    int blk = blockIdx.x;
    int b = blk / (Np / PTS);
    int n0 = (blk % (Np / PTS)) * PTS;
    int t = threadIdx.x;
    int lane = t & 63, wid = t >> 6;
    const int* ip = idxg + ((size_t)b * Np + n0) * Kn;
    const float4* Xp4 = (const float4*)Xpm;
    constexpr int C4 = CPAD / 4;
    for (int e = t; e < PTS * C4; e += 256) {
        int pt = e / C4, c4 = e % C4;
        *(float4*)&ctr[pt][4 * c4] = Xp4[((size_t)b * Np + n0 + pt) * C4 + c4];
    }
    for (int e = t; e < PTS * Kn * C4; e += 256) {
        int pt = e / (Kn * C4);
        int r = e % (Kn * C4);
        int k = r / C4, c4 = r % C4;
        int nb = ip[pt * Kn + k];
        *(float4*)&nbr[pt][k][4 * c4] = Xp4[((size_t)b * Np + nb) * C4 + c4];
    }
    __syncthreads();
    int og = t % OG, kg = t / OG;
    float acc[PTS][OPT][KPT] = {};
    float ctt[PTS][OPT] = {};
    for (int c0 = 0; c0 < CPAD; c0 += 4) {
        float wn[OPT][4], wd[OPT][4];
        #pragma unroll
        for (int p = 0; p < OPT; ++p) {
            #pragma unroll
            for (int cc = 0; cc < 4; ++cc) {
                int c = c0 + cc;
                float a = (c < C) ? W[(size_t)(og + p * OG) * (2 * C) + c] : 0.f;
                float q = (c < C) ? W[(size_t)(og + p * OG) * (2 * C) + C + c] : 0.f;
                wn[p][cc] = a; wd[p][cc] = q - a;
            }
        }
        #pragma unroll
        for (int pt = 0; pt < PTS; ++pt) {
            float4 cv = *(const float4*)&ctr[pt][c0];
            #pragma unroll
            for (int p = 0; p < OPT; ++p) {
                ctt[pt][p] = fmaf(wd[p][0], cv.x, ctt[pt][p]);
                ctt[pt][p] = fmaf(wd[p][1], cv.y, ctt[pt][p]);
                ctt[pt][p] = fmaf(wd[p][2], cv.z, ctt[pt][p]);
                ctt[pt][p] = fmaf(wd[p][3], cv.w, ctt[pt][p]);
            }
        }
        #pragma unroll
        for (int pt = 0; pt < PTS; ++pt) {
            #pragma unroll
            for (int k = 0; k < KPT; ++k) {
                float4 nv = *(const float4*)&nbr[pt][kg * KPT + k][c0];
                #pragma unroll
                for (int p = 0; p < OPT; ++p) {
                    acc[pt][p][k] = fmaf(wn[p][0], nv.x, acc[pt][p][k]);
                    acc[pt][p][k] = fmaf(wn[p][1], nv.y, acc[pt][p][k]);
                    acc[pt][p][k] = fmaf(wn[p][2], nv.z, acc[pt][p][k]);
                    acc[pt][p][k] = fmaf(wn[p][3], nv.w, acc[pt][p][k]);
                }
            }
        }
    }
    #pragma unroll
    for (int pt = 0; pt < PTS; ++pt) {
        #pragma unroll
        for (int p = 0; p < OPT; ++p) {
            int o = og + p * OG;
            float sv = sg[o], bv = bg[o];
            float m = -INFINITY;
            #pragma unroll
            for (int k = 0; k < KPT; ++k) {
                float hv = fmaf(acc[pt][p][k] + ctt[pt][p], sv, bv);
                m = fmaxf(m, lrelu(hv));
            }
            #pragma unroll
            for (int s = OG; s < 64; s <<= 1) m = fmaxf(m, __shfl_xor(m, s, 64));
            if (lane < OG) red[pt][p][wid][lane] = m;
        }
    }
    __syncthreads();
    if (t < OG) {
        #pragma unroll
        for (int pt = 0; pt < PTS; ++pt) {
            #pragma unroll
            for (int p = 0; p < OPT; ++p) {
                float m = fmaxf(fmaxf(red[pt][p][0][t], red[pt][p][1][t]),
                                fmaxf(red[pt][p][2][t], red[pt][p][3][t]));
                int o = t + p * OG;
                Ypm[((size_t)b * Np + n0 + pt) * O + o] = m;
            }
        }
    }
}

// MFMA W5 (K=512, O=1024) + bias + LeakyReLU + max/sum pool over 32 points -> partials.
__global__ __launch_bounds__(1024, 4) void k_w5mfma(
    const float* __restrict__ x1, const float* __restrict__ x2,
    const float* __restrict__ x3, const float* __restrict__ x4,
    const ushortT* __restrict__ Bh, const ushortT* __restrict__ Bl,
    const float* __restrict__ b5,
    float* __restrict__ pmax, float* __restrict__ psum)
{
    constexpr int CP = 520;                 // 512 + 8 pad
    extern __shared__ char smem[];
    ushortT* Ah = (ushortT*)smem;           // [32][CP]
    ushortT* Al = Ah + 32 * CP;             // [32][CP]
    int b = blockIdx.x >> 6;
    int chunk = blockIdx.x & 63;
    int n0 = chunk * 32;
    int t = threadIdx.x;
    for (int e = t; e < 32 * 128; e += 1024) {
        int pt = e >> 7, c4 = e & 127;
        size_t pi = (size_t)b * Np + n0 + pt;
        float4 v;
        if (c4 < 16)      v = ((const float4*)x1)[pi * 16 + c4];
        else if (c4 < 32) v = ((const float4*)x2)[pi * 16 + (c4 - 16)];
        else if (c4 < 64) v = ((const float4*)x3)[pi * 32 + (c4 - 32)];
        else              v = ((const float4*)x4)[pi * 64 + (c4 - 64)];
        unsigned h0, l0, h1, l1;
        cvt2u(v.x, v.y, h0, l0);
        cvt2u(v.z, v.w, h1, l1);
        *(uint2*)&Ah[pt * CP + 4 * c4] = make_uint2(h0, h1);
        *(uint2*)&Al[pt * CP + 4 * c4] = make_uint2(l0, l1);
    }
    __syncthreads();
    int w = t >> 6, lane = t & 63;
    int quad = lane >> 4, col = lane & 15;
    size_t pb = ((size_t)(b * 64 + chunk)) * 1024;
    for (int oi = 0; oi < 4; ++oi) {
        int nt = w * 4 + oi;
        f32x4 a0 = (f32x4){0.f, 0.f, 0.f, 0.f};
        f32x4 a1 = (f32x4){0.f, 0.f, 0.f, 0.f};
        #pragma unroll 2
        for (int ks = 0; ks < 16; ++ks) {
            size_t bi = (((size_t)(ks * 64 + nt)) * 64 + lane) * 8;
            short8 bh = *(const short8*)(Bh + bi);
            short8 bl = *(const short8*)(Bl + bi);
            int ao = ks * 32 + quad * 8;
            short8 ah0 = *(const short8*)&Ah[col * CP + ao];
            short8 al0 = *(const short8*)&Al[col * CP + ao];
            short8 ah1 = *(const short8*)&Ah[(16 + col) * CP + ao];
            short8 al1 = *(const short8*)&Al[(16 + col) * CP + ao];
            a0 = __builtin_amdgcn_mfma_f32_16x16x32_bf16(ah0, bh, a0, 0, 0, 0);
            a1 = __builtin_amdgcn_mfma_f32_16x16x32_bf16(ah1, bh, a1, 0, 0, 0);
            a0 = __builtin_amdgcn_mfma_f32_16x16x32_bf16(ah0, bl, a0, 0, 0, 0);
            a1 = __builtin_amdgcn_mfma_f32_16x16x32_bf16(ah1, bl, a1, 0, 0, 0);
            a0 = __builtin_amdgcn_mfma_f32_16x16x32_bf16(al0, bh, a0, 0, 0, 0);
            a1 = __builtin_amdgcn_mfma_f32_16x16x32_bf16(al1, bh, a1, 0, 0, 0);
        }
        float bb = b5[nt * 16 + col];
        float mx = -INFINITY, sm = 0.f;
        #pragma unroll
        for (int r = 0; r < 4; ++r) {
            float v0 = lrelu(a0[r] + bb);
            float v1 = lrelu(a1[r] + bb);
            mx = fmaxf(mx, fmaxf(v0, v1));
            sm += v0 + v1;
        }
        mx = fmaxf(mx, __shfl_xor(mx, 16, 64));
        mx = fmaxf(mx, __shfl_xor(mx, 32, 64));
        sm += __shfl_xor(sm, 16, 64);
        sm += __shfl_xor(sm, 32, 64);
        if (lane < 16) {
            pmax[pb + nt * 16 + col] = mx;
            psum[pb + nt * 16 + col] = sm;
        }
    }
}

__global__ __launch_bounds__(256) void k_poolred(const float* __restrict__ pmax, const float* __restrict__ psum,
                                                 float* __restrict__ g0) {
    int i = blockIdx.x * 256 + threadIdx.x;
    int b = i >> 10, o = i & 1023;
    float mx = -INFINITY, sm = 0.f;
    for (int ch = 0; ch < 64; ++ch) {
        size_t idx = ((size_t)(b * 64 + ch)) * 1024 + o;
        mx = fmaxf(mx, pmax[idx]);
        sm += psum[idx];
    }
    g0[(size_t)b * 2048 + o] = mx;
    g0[(size_t)b * 2048 + 1024 + o] = sm * (1.f / Np);
}

__global__ __launch_bounds__(256) void k_fc(const float* __restrict__ In, int ldIn, int C,
                                            const float* __restrict__ Wm,
                                            const float* __restrict__ bias,
                                            const float* __restrict__ sc, const float* __restrict__ bnb,
                                            int leaky, float* __restrict__ Out, int ldOut, int O) {
    int wid = threadIdx.x >> 6, lane = threadIdx.x & 63;
    int o = blockIdx.x * 4 + wid;
    int b = blockIdx.y;
    if (o >= O) return;
    const float* in = In + (size_t)b * ldIn;
    const float* wr = Wm + (size_t)o * C;
    float acc = 0.f;
    for (int c = lane; c < C; c += 64) acc = fmaf(in[c], wr[c], acc);
    #pragma unroll
    for (int off = 32; off; off >>= 1) acc += __shfl_down(acc, off, 64);
    if (lane == 0) {
        float v = acc + (bias ? bias[o] : 0.f);
        if (sc) v = fmaf(v, sc[o], bnb[o]);
        if (leaky) v = lrelu(v);
        Out[(size_t)b * ldOut + o] = v;
    }
}

extern "C" void kernel_launch(void* const* d_in, const int* in_sizes, int n_in,
                              void* d_out, int out_size, void* d_ws, size_t ws_size,
                              hipStream_t stream) {
    const float* x   = (const float*)d_in[0];
    const float* W1  = (const float*)d_in[1];
    const float* s1  = (const float*)d_in[2];
    const float* b1  = (const float*)d_in[3];
    const float* W2  = (const float*)d_in[4];
    const float* s2  = (const float*)d_in[5];
    const float* b2  = (const float*)d_in[6];
    const float* W3  = (const float*)d_in[7];
    const float* s3  = (const float*)d_in[8];
    const float* b3  = (const float*)d_in[9];
    const float* W4  = (const float*)d_in[10];
    const float* s4  = (const float*)d_in[11];
    const float* b4  = (const float*)d_in[12];
    const float* W5  = (const float*)d_in[13];
    const float* s5  = (const float*)d_in[14];
    const float* b5  = (const float*)d_in[15];
    const float* L1w = (const float*)d_in[16];
    const float* s6  = (const float*)d_in[17];
    const float* b6  = (const float*)d_in[18];
    const float* L2w = (const float*)d_in[19];
    const float* L2b = (const float*)d_in[20];
    const float* s7  = (const float*)d_in[21];
    const float* b7  = (const float*)d_in[22];
    const float* L3w = (const float*)d_in[23];
    const float* L3b = (const float*)d_in[24];
    const float* F1w = (const float*)d_in[25];
    const float* s8  = (const float*)d_in[26];
    const float* b8  = (const float*)d_in[27];
    const float* F2w = (const float*)d_in[28];
    const float* F2b = (const float*)d_in[29];
    const float* s9  = (const float*)d_in[30];
    const float* b9  = (const float*)d_in[31];
    const float* F3w = (const float*)d_in[32];
    const float* F3b = (const float*)d_in[33];

    float* ws = (float*)d_ws;
    size_t off = 0;
    auto alloc = [&](size_t n) { float* p = ws + off; off += n; return p; };
    float* pts  = alloc((size_t)Bn * Np * 4);
    float* x1   = alloc((size_t)Bn * Np * 64);
    float* x2   = alloc((size_t)Bn * Np * 64);
    float* x3   = alloc((size_t)Bn * Np * 128);
    float* x4   = alloc((size_t)Bn * Np * 256);
    float* xcm  = alloc((size_t)Bn * Np * 128);   // aliased: pmax / psum
    float* xxb  = alloc((size_t)Bn * Np);
    int*   idxb = (int*)alloc((size_t)Bn * Np * Kn);
    float* g0   = alloc((size_t)Bn * 2048);
    float* g1   = alloc((size_t)Bn * 512);
    float* g2   = alloc((size_t)Bn * 256);
    float* y1   = alloc((size_t)Bn * 512);
    float* y2   = alloc((size_t)Bn * 256);
    float* WnsT2 = alloc(64 * 64);
    float* WdsT2 = alloc(64 * 64);
    float* WnsT3 = alloc(64 * 128);
    float* WdsT3 = alloc(64 * 128);
    float* WnsT4 = alloc(128 * 256);
    float* WdsT4 = alloc(128 * 256);
    ushortT* Bh2 = (ushortT*)alloc(64 * 64 / 2);
    ushortT* Bl2 = (ushortT*)alloc(64 * 64 / 2);
    ushortT* Bh3 = (ushortT*)alloc(64 * 128 / 2);
    ushortT* Bl3 = (ushortT*)alloc(64 * 128 / 2);
    ushortT* Bh4 = (ushortT*)alloc(128 * 256 / 2);
    ushortT* Bl4 = (ushortT*)alloc(128 * 256 / 2);
    ushortT* BhK = (ushortT*)alloc(1048576);   // knn B-frag hi (max C=128: 2M shorts)
    ushortT* BlK = (ushortT*)alloc(1048576);
    ushortT* Bh5 = (ushortT*)alloc(262144);    // W5 frag hi: 512K shorts
    ushortT* Bl5 = (ushortT*)alloc(262144);
    float* pmax = xcm;
    float* psum = xcm + 524288;
    float* cb2 = x2;
    float* cb3 = x3;
    float* cb4 = x4;

    // dynamic-LDS opt-ins (idempotent, safe pre-capture)
    auto shsz = [](int CP) { return 16 * CP * 2 * 2 + 64 + 16 * 2050 * 4; };
    int sh3 = shsz(40), sh64 = shsz(72), sh128 = shsz(136);
    int shw5 = 32 * 520 * 2 * 2;
    hipFuncSetAttribute((const void*)k_knn4<3, 32, 4>, hipFuncAttributeMaxDynamicSharedMemorySize, sh3);
    hipFuncSetAttribute((const void*)k_knn4<64, 64, 64>, hipFuncAttributeMaxDynamicSharedMemorySize, sh64);
    hipFuncSetAttribute((const void*)k_knn4<128, 128, 128>, hipFuncAttributeMaxDynamicSharedMemorySize, sh128);
    hipFuncSetAttribute((const void*)k_w5mfma, hipFuncAttributeMaxDynamicSharedMemorySize, shw5);

    k_transpose<<<Bn * Np / 256, 256, 0, stream>>>(x, pts);
    k_wsplit<<<16, 256, 0, stream>>>(W2, s2, 64, 64, WnsT2, WdsT2);
    k_wsplit<<<32, 256, 0, stream>>>(W3, s3, 64, 128, WnsT3, WdsT3);
    k_wsplit<<<128, 256, 0, stream>>>(W4, s4, 128, 256, WnsT4, WdsT4);
    k_wpack<<<16, 256, 0, stream>>>(W2, s2, 64, 64, Bh2, Bl2);
    k_wpack<<<32, 256, 0, stream>>>(W3, s3, 64, 128, Bh3, Bl3);
    k_wpack<<<128, 256, 0, stream>>>(W4, s4, 128, 256, Bh4, Bl4);
    k_w5pack<<<2048, 256, 0, stream>>>(W5, s5, Bh5, Bl5);

    // Layer 1: C=3
    k_xx<<<Bn * Np / 4, 256, 0, stream>>>(pts, xxb, 3, 4);
    k_bpack<3, 32, 4><<<2048, 256, 0, stream>>>(pts, BhK, BlK);
    k_knn4<3, 32, 4><<<Bn * Np / 16, 1024, sh3, stream>>>(pts, BhK, BlK, xxb, idxb);
    k_edgeconv<3, 4, 64, 1, 8, 4><<<Bn * Np / 4, 256, 0, stream>>>(pts, idxb, W1, s1, b1, x1);

    // Layer 2: C=64 -> O=64
    k_xx<<<Bn * Np / 4, 256, 0, stream>>>(x1, xxb, 64, 64);
    k_bpack<64, 64, 64><<<4096, 256, 0, stream>>>(x1, BhK, BlK);
    k_knn4<64, 64, 64><<<Bn * Np / 16, 1024, sh64, stream>>>(x1, BhK, BlK, xxb, idxb);
    k_ctr<64, 64, 4><<<Bn * Np / 32, 256, 0, stream>>>(x1, WdsT2, b2, cb2);
    k_ec3<64, 64, 2><<<Bn * Np / 2, 256, 0, stream>>>(x1, idxb, Bh2, Bl2, cb2, x2);

    // Layer 3: C=64 -> O=128
    k_xx<<<Bn * Np / 4, 256, 0, stream>>>(x2, xxb, 64, 64);
    k_bpack<64, 64, 64><<<4096, 256, 0, stream>>>(x2, BhK, BlK);
    k_knn4<64, 64, 64><<<Bn * Np / 16, 1024, sh64, stream>>>(x2, BhK, BlK, xxb, idxb);
    k_ctr<64, 128, 8><<<Bn * Np / 32, 256, 0, stream>>>(x2, WdsT3, b3, cb3);
    k_ec3<64, 128, 2><<<Bn * Np / 2, 256, 0, stream>>>(x2, idxb, Bh3, Bl3, cb3, x3);

    // Layer 4: C=128 -> O=256
    k_xx<<<Bn * Np / 4, 256, 0, stream>>>(x3, xxb, 128, 128);
    k_bpack<128, 128, 128><<<8192, 256, 0, stream>>>(x3, BhK, BlK);
    k_knn4<128, 128, 128><<<Bn * Np / 16, 1024, sh128, stream>>>(x3, BhK, BlK, xxb, idxb);
    k_ctr<128, 256, 8><<<Bn * Np / 32, 256, 0, stream>>>(x3, WdsT4, b4, cb4);
    k_ec3<128, 256, 2><<<Bn * Np / 2, 256, 0, stream>>>(x3, idxb, Bh4, Bl4, cb4, x4);

    // W5 + pooling (MFMA, 16-wave blocks)
    k_w5mfma<<<Bn * 64, 1024, shw5, stream>>>(x1, x2, x3, x4, Bh5, Bl5, b5, pmax, psum);
    k_poolred<<<Bn * 1024 / 256, 256, 0, stream>>>(pmax, psum, g0);

    float* out = (float*)d_out;
    k_fc<<<dim3(128, Bn), 256, 0, stream>>>(g0, 2048, 2048, L1w, nullptr, s6, b6, 1, g1, 512, 512);
    k_fc<<<dim3(64, Bn), 256, 0, stream>>>(g1, 512, 512, L2w, L2b, s7, b7, 1, g2, 256, 256);
    k_fc<<<dim3(2, Bn), 256, 0, stream>>>(g2, 256, 256, L3w, L3b, nullptr, nullptr, 0, out, 5, 5);
    k_fc<<<dim3(128, Bn), 256, 0, stream>>>(g0, 2048, 1024, F1w, nullptr, s8, b8, 1, y1, 512, 512);
    k_fc<<<dim3(64, Bn), 256, 0, stream>>>(y1, 512, 512, F2w, F2b, s9, b9, 1, y2, 256, 256);
    k_fc<<<dim3(2, Bn), 256, 0, stream>>>(y2, 256, 256, F3w, F3b, nullptr, nullptr, 0, out + 40, 5, 5);
}

// Round 12
// 938.759 us; speedup vs baseline: 4.5764x; 1.0380x over previous
//
#include <hip/hip_runtime.h>
#include <math.h>

constexpr int Bn = 8;
constexpr int Np = 2048;
constexpr int Kn = 32;
constexpr float NEGS = 0.2f;

typedef __attribute__((ext_vector_type(8))) short short8;
typedef __attribute__((ext_vector_type(4))) float f32x4;
typedef unsigned short ushortT;

__device__ __forceinline__ float lrelu(float v) { return v > 0.f ? v : NEGS * v; }

// split fp32 -> bf16 hi (truncate) + bf16 lo (residual, truncate); packed 2-at-a-time
__device__ __forceinline__ void cvt2u(float a, float b, unsigned& h, unsigned& l) {
    unsigned ua = __float_as_uint(a), ub = __float_as_uint(b);
    h = (ua >> 16) | (ub & 0xffff0000u);
    float ra = a - __uint_as_float(ua & 0xffff0000u);
    float rb = b - __uint_as_float(ub & 0xffff0000u);
    l = (__float_as_uint(ra) >> 16) | (__float_as_uint(rb) & 0xffff0000u);
}

// x [B,3,N] -> pts point-major [B*N, 4] (pad lane = 0)
__global__ __launch_bounds__(256) void k_transpose(const float* __restrict__ x, float* __restrict__ pts) {
    int i = blockIdx.x * 256 + threadIdx.x;
    int b = i / Np, n = i % Np;
    float p0 = x[((size_t)b * 3 + 0) * Np + n];
    float p1 = x[((size_t)b * 3 + 1) * Np + n];
    float p2 = x[((size_t)b * 3 + 2) * Np + n];
    float4 v = make_float4(p0, p1, p2, 0.f);
    *(float4*)&pts[(size_t)i * 4] = v;
}

// xx[i] = sum_c pm[i*ld+c]^2 ; one wave per point, 4 points per block
__global__ __launch_bounds__(256) void k_xx(const float* __restrict__ pm, float* __restrict__ xxg, int C, int ld) {
    int wid = threadIdx.x >> 6, lane = threadIdx.x & 63;
    int pt = blockIdx.x * 4 + wid;
    const float* row = pm + (size_t)pt * ld;
    float acc = 0.f;
    for (int c = lane; c < C; c += 64) { float v = row[c]; acc = fmaf(v, v, acc); }
    #pragma unroll
    for (int off = 32; off; off >>= 1) acc += __shfl_down(acc, off, 64);
    if (lane == 0) xxg[pt] = acc;
}

// Pack points into mfma_16x16x32 B-fragment order (bf16 hi/lo), per batch.
template<int C, int CK, int LD>
__global__ __launch_bounds__(256) void k_bpack(const float* __restrict__ Xpm,
                                               ushortT* __restrict__ Bh, ushortT* __restrict__ Bl) {
    constexpr int KS = CK / 32;
    int i = blockIdx.x * 256 + threadIdx.x;
    int j = i & 7;
    int lane = (i >> 3) & 63;
    int nt = (i >> 9) & 127;
    int rest = i >> 16;
    int ks = rest % KS;
    int b = rest / KS;
    int k = ks * 32 + (lane >> 4) * 8 + j;
    int n = nt * 16 + (lane & 15);
    float v = (k < C) ? Xpm[((size_t)b * Np + n) * LD + k] : 0.f;
    unsigned u = __float_as_uint(v);
    Bh[i] = (ushortT)(u >> 16);
    float r = v - __uint_as_float(u & 0xffff0000u);
    Bl[i] = (ushortT)(__float_as_uint(r) >> 16);
}

// MFMA kNN v6: column-chunked ping-pong dl (16 x 1026 fp32, ~66 KB) -> 2 blocks/CU
// (2x occupancy vs v5). Two chunks: MFMA cols [0,1024) -> sync -> load v[0..15] ->
// sync -> MFMA cols [1024,2048) -> sync -> load v[16..31]. Selection identical to v5
// (exact fp32 sequential argmax, value-only butterfly + ballot owner).
template<int C, int CK, int LD>
__global__ __launch_bounds__(1024) void k_knn5(const float* __restrict__ Xpm,
                                               const ushortT* __restrict__ Bh, const ushortT* __restrict__ Bl,
                                               const float* __restrict__ xxg, int* __restrict__ idxo) {
    constexpr int KS = CK / 32, CP = CK + 8, CK4 = CK / 4, C4src = LD / 4;
    constexpr int SD = 1026;
    extern __shared__ char smem[];
    ushortT* Ah = (ushortT*)smem;              // [16][CP]
    ushortT* Al = Ah + 16 * CP;                // [16][CP]
    float* xxm = (float*)(Al + 16 * CP);       // [16]
    float* dl = xxm + 16;                      // [16][SD] distances (one column-half)
    int b = blockIdx.x / (Np / 16);
    int n0 = (blockIdx.x % (Np / 16)) * 16;
    int t = threadIdx.x;
    const float4* Xp4 = (const float4*)Xpm;
    for (int e = t; e < 16 * CK4; e += 1024) {
        int r = e / CK4, c4 = e % CK4;
        float4 v = (c4 < C4src) ? Xp4[((size_t)b * Np + n0 + r) * C4src + c4] : make_float4(0.f, 0.f, 0.f, 0.f);
        unsigned h0, l0, h1, l1;
        cvt2u(v.x, v.y, h0, l0);
        cvt2u(v.z, v.w, h1, l1);
        *(uint2*)&Ah[r * CP + 4 * c4] = make_uint2(h0, h1);
        *(uint2*)&Al[r * CP + 4 * c4] = make_uint2(l0, l1);
    }
    if (t < 16) xxm[t] = xxg[b * Np + t + n0];
    __syncthreads();

    int w = t >> 6, lane = t & 63;
    int quad = lane >> 4, col = lane & 15;
    short8 ah[KS], al[KS];
    #pragma unroll
    for (int ks = 0; ks < KS; ++ks) {
        ah[ks] = *(const short8*)&Ah[col * CP + ks * 32 + quad * 8];
        al[ks] = *(const short8*)&Al[col * CP + ks * 32 + quad * 8];
    }
    float xmr[4];
    #pragma unroll
    for (int r = 0; r < 4; ++r) xmr[r] = xxm[quad * 4 + r];

    float v[32];
    #pragma unroll
    for (int cc = 0; cc < 2; ++cc) {
        // MFMA: 4 local n-tiles per wave (2 at a time), chunk covers 64 tiles = 1024 cols
        for (int i = 0; i < 2; ++i) {
            int ntl0 = w * 4 + 2 * i, ntl1 = ntl0 + 1;     // tile within chunk
            int ng0 = cc * 64 + ntl0, ng1 = cc * 64 + ntl1; // global tile
            f32x4 a0 = (f32x4){0.f, 0.f, 0.f, 0.f};
            f32x4 a1 = (f32x4){0.f, 0.f, 0.f, 0.f};
            #pragma unroll
            for (int ks = 0; ks < KS; ++ks) {
                int bi0 = (((b * KS + ks) * 128 + ng0) * 64 + lane) * 8;
                int bi1 = (((b * KS + ks) * 128 + ng1) * 64 + lane) * 8;
                short8 bh0 = *(const short8*)(Bh + bi0);
                short8 bl0 = *(const short8*)(Bl + bi0);
                short8 bh1 = *(const short8*)(Bh + bi1);
                short8 bl1 = *(const short8*)(Bl + bi1);
                a0 = __builtin_amdgcn_mfma_f32_16x16x32_bf16(ah[ks], bh0, a0, 0, 0, 0);
                a1 = __builtin_amdgcn_mfma_f32_16x16x32_bf16(ah[ks], bh1, a1, 0, 0, 0);
                a0 = __builtin_amdgcn_mfma_f32_16x16x32_bf16(ah[ks], bl0, a0, 0, 0, 0);
                a1 = __builtin_amdgcn_mfma_f32_16x16x32_bf16(ah[ks], bl1, a1, 0, 0, 0);
                a0 = __builtin_amdgcn_mfma_f32_16x16x32_bf16(al[ks], bh0, a0, 0, 0, 0);
                a1 = __builtin_amdgcn_mfma_f32_16x16x32_bf16(al[ks], bh1, a1, 0, 0, 0);
            }
            float xn0 = xxg[b * Np + ng0 * 16 + col];
            float xn1 = xxg[b * Np + ng1 * 16 + col];
            #pragma unroll
            for (int r = 0; r < 4; ++r) {
                int m = quad * 4 + r;
                dl[m * SD + ntl0 * 16 + col] = 2.f * a0[r] - xmr[r] - xn0;
                dl[m * SD + ntl1 * 16 + col] = 2.f * a1[r] - xmr[r] - xn1;
            }
        }
        __syncthreads();
        const float* drow = dl + w * SD;
        #pragma unroll
        for (int j = 0; j < 16; ++j) v[cc * 16 + j] = drow[lane + 64 * j];
        __syncthreads();   // chunk0: protect against chunk1 overwrite; chunk1: harmless
    }

    // ---- selection: wave w owns row w (identical to v5; exact fp32) ----
    float gv0, gv1, gv2, gv3;
    int gj0, gj1, gj2, gj3;
    gv0 = v[0]; gj0 = 0;
    #pragma unroll
    for (int e = 1; e < 8; ++e) if (v[e] > gv0) { gv0 = v[e]; gj0 = e; }
    gv1 = v[8]; gj1 = 8;
    #pragma unroll
    for (int e = 1; e < 8; ++e) if (v[8 + e] > gv1) { gv1 = v[8 + e]; gj1 = 8 + e; }
    gv2 = v[16]; gj2 = 16;
    #pragma unroll
    for (int e = 1; e < 8; ++e) if (v[16 + e] > gv2) { gv2 = v[16 + e]; gj2 = 16 + e; }
    gv3 = v[24]; gj3 = 24;
    #pragma unroll
    for (int e = 1; e < 8; ++e) if (v[24 + e] > gv3) { gv3 = v[24 + e]; gj3 = 24 + e; }

    size_t ob = ((size_t)b * Np + n0 + w) * Kn;
    for (int it = 0; it < Kn; ++it) {
        float lv = fmaxf(fmaxf(gv0, gv1), fmaxf(gv2, gv3));
        float Wv = lv;
        #pragma unroll
        for (int off = 1; off < 64; off <<= 1) Wv = fmaxf(Wv, __shfl_xor(Wv, off, 64));
        unsigned long long mk = __ballot(lv == Wv);
        int owner = __ffsll(mk) - 1;
        if (lane == owner) {
            int lj;
            if (gv0 == Wv) lj = gj0;
            else if (gv1 == Wv) lj = gj1;
            else if (gv2 == Wv) lj = gj2;
            else lj = gj3;
            idxo[ob + it] = lane + 64 * lj;
            int gg = lj >> 3;
            if (gg == 0) {
                #pragma unroll
                for (int e = 0; e < 8; ++e) if (e == lj) v[e] = -INFINITY;
                gv0 = v[0]; gj0 = 0;
                #pragma unroll
                for (int e = 1; e < 8; ++e) if (v[e] > gv0) { gv0 = v[e]; gj0 = e; }
            } else if (gg == 1) {
                #pragma unroll
                for (int e = 0; e < 8; ++e) if (8 + e == lj) v[8 + e] = -INFINITY;
                gv1 = v[8]; gj1 = 8;
                #pragma unroll
                for (int e = 1; e < 8; ++e) if (v[8 + e] > gv1) { gv1 = v[8 + e]; gj1 = 8 + e; }
            } else if (gg == 2) {
                #pragma unroll
                for (int e = 0; e < 8; ++e) if (16 + e == lj) v[16 + e] = -INFINITY;
                gv2 = v[16]; gj2 = 16;
                #pragma unroll
                for (int e = 1; e < 8; ++e) if (v[16 + e] > gv2) { gv2 = v[16 + e]; gj2 = 16 + e; }
            } else {
                #pragma unroll
                for (int e = 0; e < 8; ++e) if (24 + e == lj) v[24 + e] = -INFINITY;
                gv3 = v[24]; gj3 = 24;
                #pragma unroll
                for (int e = 1; e < 8; ++e) if (v[24 + e] > gv3) { gv3 = v[24 + e]; gj3 = 24 + e; }
            }
        }
    }
}

// W split+scale+transpose (fp32, for k_ctr): WdsT[c][o] = (W[o][C+c]-W[o][c])*s[o]
__global__ __launch_bounds__(256) void k_wsplit(const float* __restrict__ W, const float* __restrict__ s,
                                                int C, int O, float* __restrict__ WnsT, float* __restrict__ WdsT) {
    int i = blockIdx.x * 256 + threadIdx.x;
    if (i >= C * O) return;
    int c = i / O, o = i % O;
    float a = W[(size_t)o * 2 * C + c];
    float q = W[(size_t)o * 2 * C + C + c];
    float sv = s[o];
    WnsT[i] = a * sv;
    WdsT[i] = (q - a) * sv;
}

// Pack neighbor-half of W (scaled) into mfma_16x16x32 B-fragment order, split bf16 hi/lo.
__global__ __launch_bounds__(256) void k_wpack(const float* __restrict__ W, const float* __restrict__ s,
                                               int C, int O, ushortT* __restrict__ Bh, ushortT* __restrict__ Bl) {
    int i = blockIdx.x * 256 + threadIdx.x;
    if (i >= C * O) return;
    int k = i / O, o = i % O;
    float v = W[(size_t)o * 2 * C + k] * s[o];
    int ks = k >> 5, quad = (k >> 3) & 3, j = k & 7;
    int nt = o >> 4, lane = quad * 16 + (o & 15);
    int NT = O / 16;
    size_t idx = (((size_t)(ks * NT + nt)) * 64 + lane) * 8 + j;
    unsigned u = __float_as_uint(v);
    Bh[idx] = (ushortT)(u >> 16);
    float r = v - __uint_as_float(u & 0xffff0000u);
    Bl[idx] = (ushortT)(__float_as_uint(r) >> 16);
}

// Pack W5 (scaled by s5) [1024][512] into fragment order: KS=16, NT=64.
__global__ __launch_bounds__(256) void k_w5pack(const float* __restrict__ W5, const float* __restrict__ s5,
                                                ushortT* __restrict__ Bh, ushortT* __restrict__ Bl) {
    int i = blockIdx.x * 256 + threadIdx.x;   // 512*1024
    int k = i >> 10, o = i & 1023;
    float v = W5[(size_t)o * 512 + k] * s5[o];
    int ks = k >> 5, quad = (k >> 3) & 3, j = k & 7;
    int nt = o >> 4, lane = quad * 16 + (o & 15);
    size_t idx = (((size_t)(ks * 64 + nt)) * 64 + lane) * 8 + j;
    unsigned u = __float_as_uint(v);
    Bh[idx] = (ushortT)(u >> 16);
    float r = v - __uint_as_float(u & 0xffff0000u);
    Bl[idx] = (ushortT)(__float_as_uint(r) >> 16);
}

// cb[n][o] = sum_c ctr[n][c]*WdsT[c][o] + b[o].  32 points per block.
template<int C, int O, int OPT>
__global__ __launch_bounds__(256) void k_ctr(const float* __restrict__ Xpm, const float* __restrict__ WdsT,
                                             const float* __restrict__ bg, float* __restrict__ cb) {
    constexpr int OG = O / OPT, MG = 256 / OG, MPT = 32 / MG;
    constexpr int C4 = C / 4;
    __shared__ float xs[32][C];
    int b = blockIdx.x / (Np / 32);
    int n0 = (blockIdx.x % (Np / 32)) * 32;
    int t = threadIdx.x;
    const float4* Xp4 = (const float4*)Xpm;
    for (int e = t; e < 32 * C4; e += 256) {
        int pt = e / C4, c4 = e % C4;
        *(float4*)&xs[pt][4 * c4] = Xp4[((size_t)b * Np + n0 + pt) * C4 + c4];
    }
    __syncthreads();
    int og = t % OG, mg = t / OG;
    int o0 = og * OPT;
    float acc[MPT][OPT] = {};
    for (int c = 0; c < C; ++c) {
        float wv[OPT];
        #pragma unroll
        for (int p4 = 0; p4 < OPT / 4; ++p4)
            *(float4*)&wv[4 * p4] = *(const float4*)&WdsT[(size_t)c * O + o0 + 4 * p4];
        #pragma unroll
        for (int m = 0; m < MPT; ++m) {
            float xv = xs[mg * MPT + m][c];
            #pragma unroll
            for (int p = 0; p < OPT; ++p) acc[m][p] = fmaf(wv[p], xv, acc[m][p]);
        }
    }
    #pragma unroll
    for (int m = 0; m < MPT; ++m) {
        #pragma unroll
        for (int p = 0; p < OPT; ++p) {
            int o = o0 + p;
            cb[((size_t)b * Np + n0 + mg * MPT + m) * O + o] = acc[m][p] + bg[o];
        }
    }
}

// MFMA EdgeConv GEMM v2 (split-bf16): waves split the O dimension (B fragments read ONCE
// per block), each wave loops all 4 m-tiles from LDS. Per-point k-max is wave-local.
template<int C, int O, int PTS>
__global__ __launch_bounds__(256, 4) void k_ec3(const float* __restrict__ Xpm, const int* __restrict__ idxg,
                                                const ushortT* __restrict__ Bh, const ushortT* __restrict__ Bl,
                                                const float* __restrict__ cb,
                                                float* __restrict__ Ypm) {
    static_assert(PTS == 2, "M=64 mapping");
    constexpr int M = 64, NT = O / 16, NT4 = NT / 4, KS = C / 32, C4 = C / 4, CP = C + 8;
    static_assert(NT4 >= 1, "O>=64");
    __shared__ ushortT Ah[M][CP];
    __shared__ ushortT Al[M][CP];
    int b = blockIdx.x / (Np / PTS);
    int n0 = (blockIdx.x % (Np / PTS)) * PTS;
    int t = threadIdx.x;
    const int* ip = idxg + ((size_t)b * Np + n0) * Kn;
    const float4* Xp4 = (const float4*)Xpm;
    for (int e = t; e < M * C4; e += 256) {
        int row = e / C4, c4 = e % C4;
        float4 v = Xp4[((size_t)b * Np + ip[row]) * C4 + c4];
        unsigned h0, l0, h1, l1;
        cvt2u(v.x, v.y, h0, l0);
        cvt2u(v.z, v.w, h1, l1);
        *(uint2*)&Ah[row][4 * c4] = make_uint2(h0, h1);
        *(uint2*)&Al[row][4 * c4] = make_uint2(l0, l1);
    }
    __syncthreads();
    int w = t >> 6, lane = t & 63;
    int quad = lane >> 4, col = lane & 15;
    f32x4 acc[4][NT4];
    #pragma unroll
    for (int mt = 0; mt < 4; ++mt)
        #pragma unroll
        for (int i = 0; i < NT4; ++i) acc[mt][i] = (f32x4){0.f, 0.f, 0.f, 0.f};
    for (int ks = 0; ks < KS; ++ks) {
        int kb = ks * 32 + quad * 8;
        short8 ah[4], al[4];
        #pragma unroll
        for (int mt = 0; mt < 4; ++mt) {
            ah[mt] = *(const short8*)&Ah[mt * 16 + col][kb];
            al[mt] = *(const short8*)&Al[mt * 16 + col][kb];
        }
        #pragma unroll
        for (int i = 0; i < NT4; ++i) {
            int nt = w * NT4 + i;
            size_t bi = (((size_t)(ks * NT + nt)) * 64 + lane) * 8;
            short8 bh = *(const short8*)(Bh + bi);
            short8 bl = *(const short8*)(Bl + bi);
            #pragma unroll
            for (int mt = 0; mt < 4; ++mt) {
                acc[mt][i] = __builtin_amdgcn_mfma_f32_16x16x32_bf16(ah[mt], bh, acc[mt][i], 0, 0, 0);
                acc[mt][i] = __builtin_amdgcn_mfma_f32_16x16x32_bf16(ah[mt], bl, acc[mt][i], 0, 0, 0);
                acc[mt][i] = __builtin_amdgcn_mfma_f32_16x16x32_bf16(al[mt], bh, acc[mt][i], 0, 0, 0);
            }
        }
    }
    #pragma unroll
    for (int pt = 0; pt < PTS; ++pt) {
        size_t ni = (size_t)b * Np + n0 + pt;
        #pragma unroll
        for (int i = 0; i < NT4; ++i) {
            f32x4 a0 = acc[2 * pt][i], a1 = acc[2 * pt + 1][i];
            float m = fmaxf(fmaxf(fmaxf(a0[0], a0[1]), fmaxf(a0[2], a0[3])),
                            fmaxf(fmaxf(a1[0], a1[1]), fmaxf(a1[2], a1[3])));
            m = fmaxf(m, __shfl_xor(m, 16, 64));
            m = fmaxf(m, __shfl_xor(m, 32, 64));
            if (lane < 16) {
                int o = (w * NT4 + i) * 16 + col;
                Ypm[ni * O + o] = lrelu(m + cb[ni * O + o]);
            }
        }
    }
}

// Legacy fused EdgeConv for layer 1 (C=3)
template<int C, int CPAD, int O, int OPT, int KPT, int PTS>
__global__ __launch_bounds__(256) void k_edgeconv(
    const float* __restrict__ Xpm, const int* __restrict__ idxg,
    const float* __restrict__ W, const float* __restrict__ sg, const float* __restrict__ bg,
    float* __restrict__ Ypm)
{
    constexpr int OG = O / OPT;
    constexpr int NKG = 256 / OG;
    constexpr int CL = CPAD + 4;
    static_assert(NKG * KPT == Kn, "k mapping");
    __shared__ float nbr[PTS][Kn][CL];
    __shared__ float ctr[PTS][CPAD];
    __shared__ float red[PTS][OPT][4][OG];
    int blk = blockIdx.x;
    int b = blk / (Np / PTS);
    int n0 = (blk % (Np / PTS)) * PTS;
    int t = threadIdx.x;
    int lane = t & 63, wid = t >> 6;
    const int* ip = idxg + ((size_t)b * Np + n0) * Kn;
    const float4* Xp4 = (const float4*)Xpm;
    constexpr int C4 = CPAD / 4;
    for (int e = t; e < PTS * C4; e += 256) {
        int pt = e / C4, c4 = e % C4;
        *(float4*)&ctr[pt][4 * c4] = Xp4[((size_t)b * Np + n0 + pt) * C4 + c4];
    }
    for (int e = t; e < PTS * Kn * C4; e += 256) {
        int pt = e / (Kn * C4);
        int r = e % (Kn * C4);
        int k = r / C4, c4 = r % C4;
        int nb = ip[pt * Kn + k];
        *(float4*)&nbr[pt][k][4 * c4] = Xp4[((size_t)b * Np + nb) * C4 + c4];
    }
    __syncthreads();
    int og = t % OG, kg = t / OG;
    float acc[PTS][OPT][KPT] = {};
    float ctt[PTS][OPT] = {};
    for (int c0 = 0; c0 < CPAD; c0 += 4) {
        float wn[OPT][4], wd[OPT][4];
        #pragma unroll
        for (int p = 0; p < OPT; ++p) {
            #pragma unroll
            for (int cc = 0; cc < 4; ++cc) {
                int c = c0 + cc;
                float a = (c < C) ? W[(size_t)(og + p * OG) * (2 * C) + c] : 0.f;
                float q = (c < C) ? W[(size_t)(og + p * OG) * (2 * C) + C + c] : 0.f;
                wn[p][cc] = a; wd[p][cc] = q - a;
            }
        }
        #pragma unroll
        for (int pt = 0; pt < PTS; ++pt) {
            float4 cv = *(const float4*)&ctr[pt][c0];
            #pragma unroll
            for (int p = 0; p < OPT; ++p) {
                ctt[pt][p] = fmaf(wd[p][0], cv.x, ctt[pt][p]);
                ctt[pt][p] = fmaf(wd[p][1], cv.y, ctt[pt][p]);
                ctt[pt][p] = fmaf(wd[p][2], cv.z, ctt[pt][p]);
                ctt[pt][p] = fmaf(wd[p][3], cv.w, ctt[pt][p]);
            }
        }
        #pragma unroll
        for (int pt = 0; pt < PTS; ++pt) {
            #pragma unroll
            for (int k = 0; k < KPT; ++k) {
                float4 nv = *(const float4*)&nbr[pt][kg * KPT + k][c0];
                #pragma unroll
                for (int p = 0; p < OPT; ++p) {
                    acc[pt][p][k] = fmaf(wn[p][0], nv.x, acc[pt][p][k]);
                    acc[pt][p][k] = fmaf(wn[p][1], nv.y, acc[pt][p][k]);
                    acc[pt][p][k] = fmaf(wn[p][2], nv.z, acc[pt][p][k]);
                    acc[pt][p][k] = fmaf(wn[p][3], nv.w, acc[pt][p][k]);
                }
            }
        }
    }
    #pragma unroll
    for (int pt = 0; pt < PTS; ++pt) {
        #pragma unroll
        for (int p = 0; p < OPT; ++p) {
            int o = og + p * OG;
            float sv = sg[o], bv = bg[o];
            float m = -INFINITY;
            #pragma unroll
            for (int k = 0; k < KPT; ++k) {
                float hv = fmaf(acc[pt][p][k] + ctt[pt][p], sv, bv);
                m = fmaxf(m, lrelu(hv));
            }
            #pragma unroll
            for (int s = OG; s < 64; s <<= 1) m = fmaxf(m, __shfl_xor(m, s, 64));
            if (lane < OG) red[pt][p][wid][lane] = m;
        }
    }
    __syncthreads();
    if (t < OG) {
        #pragma unroll
        for (int pt = 0; pt < PTS; ++pt) {
            #pragma unroll
            for (int p = 0; p < OPT; ++p) {
                float m = fmaxf(fmaxf(red[pt][p][0][t], red[pt][p][1][t]),
                                fmaxf(red[pt][p][2][t], red[pt][p][3][t]));
                int o = t + p * OG;
                Ypm[((size_t)b * Np + n0 + pt) * O + o] = m;
            }
        }
    }
}

// MFMA W5 (K=512, O=1024) + bias + LeakyReLU + max/sum pool over 32 points -> partials.
__global__ __launch_bounds__(1024, 4) void k_w5mfma(
    const float* __restrict__ x1, const float* __restrict__ x2,
    const float* __restrict__ x3, const float* __restrict__ x4,
    const ushortT* __restrict__ Bh, const ushortT* __restrict__ Bl,
    const float* __restrict__ b5,
    float* __restrict__ pmax, float* __restrict__ psum)
{
    constexpr int CP = 520;                 // 512 + 8 pad
    extern __shared__ char smem[];
    ushortT* Ah = (ushortT*)smem;           // [32][CP]
    ushortT* Al = Ah + 32 * CP;             // [32][CP]
    int b = blockIdx.x >> 6;
    int chunk = blockIdx.x & 63;
    int n0 = chunk * 32;
    int t = threadIdx.x;
    for (int e = t; e < 32 * 128; e += 1024) {
        int pt = e >> 7, c4 = e & 127;
        size_t pi = (size_t)b * Np + n0 + pt;
        float4 v;
        if (c4 < 16)      v = ((const float4*)x1)[pi * 16 + c4];
        else if (c4 < 32) v = ((const float4*)x2)[pi * 16 + (c4 - 16)];
        else if (c4 < 64) v = ((const float4*)x3)[pi * 32 + (c4 - 32)];
        else              v = ((const float4*)x4)[pi * 64 + (c4 - 64)];
        unsigned h0, l0, h1, l1;
        cvt2u(v.x, v.y, h0, l0);
        cvt2u(v.z, v.w, h1, l1);
        *(uint2*)&Ah[pt * CP + 4 * c4] = make_uint2(h0, h1);
        *(uint2*)&Al[pt * CP + 4 * c4] = make_uint2(l0, l1);
    }
    __syncthreads();
    int w = t >> 6, lane = t & 63;
    int quad = lane >> 4, col = lane & 15;
    size_t pb = ((size_t)(b * 64 + chunk)) * 1024;
    for (int oi = 0; oi < 4; ++oi) {
        int nt = w * 4 + oi;
        f32x4 a0 = (f32x4){0.f, 0.f, 0.f, 0.f};
        f32x4 a1 = (f32x4){0.f, 0.f, 0.f, 0.f};
        #pragma unroll 2
        for (int ks = 0; ks < 16; ++ks) {
            size_t bi = (((size_t)(ks * 64 + nt)) * 64 + lane) * 8;
            short8 bh = *(const short8*)(Bh + bi);
            short8 bl = *(const short8*)(Bl + bi);
            int ao = ks * 32 + quad * 8;
            short8 ah0 = *(const short8*)&Ah[col * CP + ao];
            short8 al0 = *(const short8*)&Al[col * CP + ao];
            short8 ah1 = *(const short8*)&Ah[(16 + col) * CP + ao];
            short8 al1 = *(const short8*)&Al[(16 + col) * CP + ao];
            a0 = __builtin_amdgcn_mfma_f32_16x16x32_bf16(ah0, bh, a0, 0, 0, 0);
            a1 = __builtin_amdgcn_mfma_f32_16x16x32_bf16(ah1, bh, a1, 0, 0, 0);
            a0 = __builtin_amdgcn_mfma_f32_16x16x32_bf16(ah0, bl, a0, 0, 0, 0);
            a1 = __builtin_amdgcn_mfma_f32_16x16x32_bf16(ah1, bl, a1, 0, 0, 0);
            a0 = __builtin_amdgcn_mfma_f32_16x16x32_bf16(al0, bh, a0, 0, 0, 0);
            a1 = __builtin_amdgcn_mfma_f32_16x16x32_bf16(al1, bh, a1, 0, 0, 0);
        }
        float bb = b5[nt * 16 + col];
        float mx = -INFINITY, sm = 0.f;
        #pragma unroll
        for (int r = 0; r < 4; ++r) {
            float v0 = lrelu(a0[r] + bb);
            float v1 = lrelu(a1[r] + bb);
            mx = fmaxf(mx, fmaxf(v0, v1));
            sm += v0 + v1;
        }
        mx = fmaxf(mx, __shfl_xor(mx, 16, 64));
        mx = fmaxf(mx, __shfl_xor(mx, 32, 64));
        sm += __shfl_xor(sm, 16, 64);
        sm += __shfl_xor(sm, 32, 64);
        if (lane < 16) {
            pmax[pb + nt * 16 + col] = mx;
            psum[pb + nt * 16 + col] = sm;
        }
    }
}

__global__ __launch_bounds__(256) void k_poolred(const float* __restrict__ pmax, const float* __restrict__ psum,
                                                 float* __restrict__ g0) {
    int i = blockIdx.x * 256 + threadIdx.x;
    int b = i >> 10, o = i & 1023;
    float mx = -INFINITY, sm = 0.f;
    for (int ch = 0; ch < 64; ++ch) {
        size_t idx = ((size_t)(b * 64 + ch)) * 1024 + o;
        mx = fmaxf(mx, pmax[idx]);
        sm += psum[idx];
    }
    g0[(size_t)b * 2048 + o] = mx;
    g0[(size_t)b * 2048 + 1024 + o] = sm * (1.f / Np);
}

__global__ __launch_bounds__(256) void k_fc(const float* __restrict__ In, int ldIn, int C,
                                            const float* __restrict__ Wm,
                                            const float* __restrict__ bias,
                                            const float* __restrict__ sc, const float* __restrict__ bnb,
                                            int leaky, float* __restrict__ Out, int ldOut, int O) {
    int wid = threadIdx.x >> 6, lane = threadIdx.x & 63;
    int o = blockIdx.x * 4 + wid;
    int b = blockIdx.y;
    if (o >= O) return;
    const float* in = In + (size_t)b * ldIn;
    const float* wr = Wm + (size_t)o * C;
    float acc = 0.f;
    for (int c = lane; c < C; c += 64) acc = fmaf(in[c], wr[c], acc);
    #pragma unroll
    for (int off = 32; off; off >>= 1) acc += __shfl_down(acc, off, 64);
    if (lane == 0) {
        float v = acc + (bias ? bias[o] : 0.f);
        if (sc) v = fmaf(v, sc[o], bnb[o]);
        if (leaky) v = lrelu(v);
        Out[(size_t)b * ldOut + o] = v;
    }
}

extern "C" void kernel_launch(void* const* d_in, const int* in_sizes, int n_in,
                              void* d_out, int out_size, void* d_ws, size_t ws_size,
                              hipStream_t stream) {
    const float* x   = (const float*)d_in[0];
    const float* W1  = (const float*)d_in[1];
    const float* s1  = (const float*)d_in[2];
    const float* b1  = (const float*)d_in[3];
    const float* W2  = (const float*)d_in[4];
    const float* s2  = (const float*)d_in[5];
    const float* b2  = (const float*)d_in[6];
    const float* W3  = (const float*)d_in[7];
    const float* s3  = (const float*)d_in[8];
    const float* b3  = (const float*)d_in[9];
    const float* W4  = (const float*)d_in[10];
    const float* s4  = (const float*)d_in[11];
    const float* b4  = (const float*)d_in[12];
    const float* W5  = (const float*)d_in[13];
    const float* s5  = (const float*)d_in[14];
    const float* b5  = (const float*)d_in[15];
    const float* L1w = (const float*)d_in[16];
    const float* s6  = (const float*)d_in[17];
    const float* b6  = (const float*)d_in[18];
    const float* L2w = (const float*)d_in[19];
    const float* L2b = (const float*)d_in[20];
    const float* s7  = (const float*)d_in[21];
    const float* b7  = (const float*)d_in[22];
    const float* L3w = (const float*)d_in[23];
    const float* L3b = (const float*)d_in[24];
    const float* F1w = (const float*)d_in[25];
    const float* s8  = (const float*)d_in[26];
    const float* b8  = (const float*)d_in[27];
    const float* F2w = (const float*)d_in[28];
    const float* F2b = (const float*)d_in[29];
    const float* s9  = (const float*)d_in[30];
    const float* b9  = (const float*)d_in[31];
    const float* F3w = (const float*)d_in[32];
    const float* F3b = (const float*)d_in[33];

    float* ws = (float*)d_ws;
    size_t off = 0;
    auto alloc = [&](size_t n) { float* p = ws + off; off += n; return p; };
    float* pts  = alloc((size_t)Bn * Np * 4);
    float* x1   = alloc((size_t)Bn * Np * 64);
    float* x2   = alloc((size_t)Bn * Np * 64);
    float* x3   = alloc((size_t)Bn * Np * 128);
    float* x4   = alloc((size_t)Bn * Np * 256);
    float* xcm  = alloc((size_t)Bn * Np * 128);   // aliased: pmax / psum
    float* xxb  = alloc((size_t)Bn * Np);
    int*   idxb = (int*)alloc((size_t)Bn * Np * Kn);
    float* g0   = alloc((size_t)Bn * 2048);
    float* g1   = alloc((size_t)Bn * 512);
    float* g2   = alloc((size_t)Bn * 256);
    float* y1   = alloc((size_t)Bn * 512);
    float* y2   = alloc((size_t)Bn * 256);
    float* WnsT2 = alloc(64 * 64);
    float* WdsT2 = alloc(64 * 64);
    float* WnsT3 = alloc(64 * 128);
    float* WdsT3 = alloc(64 * 128);
    float* WnsT4 = alloc(128 * 256);
    float* WdsT4 = alloc(128 * 256);
    ushortT* Bh2 = (ushortT*)alloc(64 * 64 / 2);
    ushortT* Bl2 = (ushortT*)alloc(64 * 64 / 2);
    ushortT* Bh3 = (ushortT*)alloc(64 * 128 / 2);
    ushortT* Bl3 = (ushortT*)alloc(64 * 128 / 2);
    ushortT* Bh4 = (ushortT*)alloc(128 * 256 / 2);
    ushortT* Bl4 = (ushortT*)alloc(128 * 256 / 2);
    ushortT* BhK = (ushortT*)alloc(1048576);   // knn B-frag hi (max C=128: 2M shorts)
    ushortT* BlK = (ushortT*)alloc(1048576);
    ushortT* Bh5 = (ushortT*)alloc(262144);    // W5 frag hi: 512K shorts
    ushortT* Bl5 = (ushortT*)alloc(262144);
    float* pmax = xcm;
    float* psum = xcm + 524288;
    float* cb2 = x2;
    float* cb3 = x3;
    float* cb4 = x4;

    // dynamic-LDS opt-ins (idempotent, safe pre-capture)
    auto shsz = [](int CP) { return 16 * CP * 2 * 2 + 64 + 16 * 1026 * 4; };
    int sh3 = shsz(40), sh64 = shsz(72), sh128 = shsz(136);
    int shw5 = 32 * 520 * 2 * 2;
    hipFuncSetAttribute((const void*)k_knn5<3, 32, 4>, hipFuncAttributeMaxDynamicSharedMemorySize, sh3);
    hipFuncSetAttribute((const void*)k_knn5<64, 64, 64>, hipFuncAttributeMaxDynamicSharedMemorySize, sh64);
    hipFuncSetAttribute((const void*)k_knn5<128, 128, 128>, hipFuncAttributeMaxDynamicSharedMemorySize, sh128);
    hipFuncSetAttribute((const void*)k_w5mfma, hipFuncAttributeMaxDynamicSharedMemorySize, shw5);

    k_transpose<<<Bn * Np / 256, 256, 0, stream>>>(x, pts);
    k_wsplit<<<16, 256, 0, stream>>>(W2, s2, 64, 64, WnsT2, WdsT2);
    k_wsplit<<<32, 256, 0, stream>>>(W3, s3, 64, 128, WnsT3, WdsT3);
    k_wsplit<<<128, 256, 0, stream>>>(W4, s4, 128, 256, WnsT4, WdsT4);
    k_wpack<<<16, 256, 0, stream>>>(W2, s2, 64, 64, Bh2, Bl2);
    k_wpack<<<32, 256, 0, stream>>>(W3, s3, 64, 128, Bh3, Bl3);
    k_wpack<<<128, 256, 0, stream>>>(W4, s4, 128, 256, Bh4, Bl4);
    k_w5pack<<<2048, 256, 0, stream>>>(W5, s5, Bh5, Bl5);

    // Layer 1: C=3
    k_xx<<<Bn * Np / 4, 256, 0, stream>>>(pts, xxb, 3, 4);
    k_bpack<3, 32, 4><<<2048, 256, 0, stream>>>(pts, BhK, BlK);
    k_knn5<3, 32, 4><<<Bn * Np / 16, 1024, sh3, stream>>>(pts, BhK, BlK, xxb, idxb);
    k_edgeconv<3, 4, 64, 1, 8, 4><<<Bn * Np / 4, 256, 0, stream>>>(pts, idxb, W1, s1, b1, x1);

    // Layer 2: C=64 -> O=64
    k_xx<<<Bn * Np / 4, 256, 0, stream>>>(x1, xxb, 64, 64);
    k_bpack<64, 64, 64><<<4096, 256, 0, stream>>>(x1, BhK, BlK);
    k_knn5<64, 64, 64><<<Bn * Np / 16, 1024, sh64, stream>>>(x1, BhK, BlK, xxb, idxb);
    k_ctr<64, 64, 4><<<Bn * Np / 32, 256, 0, stream>>>(x1, WdsT2, b2, cb2);
    k_ec3<64, 64, 2><<<Bn * Np / 2, 256, 0, stream>>>(x1, idxb, Bh2, Bl2, cb2, x2);

    // Layer 3: C=64 -> O=128
    k_xx<<<Bn * Np / 4, 256, 0, stream>>>(x2, xxb, 64, 64);
    k_bpack<64, 64, 64><<<4096, 256, 0, stream>>>(x2, BhK, BlK);
    k_knn5<64, 64, 64><<<Bn * Np / 16, 1024, sh64, stream>>>(x2, BhK, BlK, xxb, idxb);
    k_ctr<64, 128, 8><<<Bn * Np / 32, 256, 0, stream>>>(x2, WdsT3, b3, cb3);
    k_ec3<64, 128, 2><<<Bn * Np / 2, 256, 0, stream>>>(x2, idxb, Bh3, Bl3, cb3, x3);

    // Layer 4: C=128 -> O=256
    k_xx<<<Bn * Np / 4, 256, 0, stream>>>(x3, xxb, 128, 128);
    k_bpack<128, 128, 128><<<8192, 256, 0, stream>>>(x3, BhK, BlK);
    k_knn5<128, 128, 128><<<Bn * Np / 16, 1024, sh128, stream>>>(x3, BhK, BlK, xxb, idxb);
    k_ctr<128, 256, 8><<<Bn * Np / 32, 256, 0, stream>>>(x3, WdsT4, b4, cb4);
    k_ec3<128, 256, 2><<<Bn * Np / 2, 256, 0, stream>>>(x3, idxb, Bh4, Bl4, cb4, x4);

    // W5 + pooling (MFMA, 16-wave blocks)
    k_w5mfma<<<Bn * 64, 1024, shw5, stream>>>(x1, x2, x3, x4, Bh5, Bl5, b5, pmax, psum);
    k_poolred<<<Bn * 1024 / 256, 256, 0, stream>>>(pmax, psum, g0);

    float* out = (float*)d_out;
    k_fc<<<dim3(128, Bn), 256, 0, stream>>>(g0, 2048, 2048, L1w, nullptr, s6, b6, 1, g1, 512, 512);
    k_fc<<<dim3(64, Bn), 256, 0, stream>>>(g1, 512, 512, L2w, L2b, s7, b7, 1, g2, 256, 256);
    k_fc<<<dim3(2, Bn), 256, 0, stream>>>(g2, 256, 256, L3w, L3b, nullptr, nullptr, 0, out, 5, 5);
    k_fc<<<dim3(128, Bn), 256, 0, stream>>>(g0, 2048, 1024, F1w, nullptr, s8, b8, 1, y1, 512, 512);
    k_fc<<<dim3(64, Bn), 256, 0, stream>>>(y1, 512, 512, F2w, F2b, s9, b9, 1, y2, 256, 256);
    k_fc<<<dim3(2, Bn), 256, 0, stream>>>(y2, 256, 256, F3w, F3b, nullptr, nullptr, 0, out + 40, 5, 5);
}

// Round 14
// 895.453 us; speedup vs baseline: 4.7977x; 1.0484x over previous
//
#include <hip/hip_runtime.h>
#include <math.h>

constexpr int Bn = 8;
constexpr int Np = 2048;
constexpr int Kn = 32;
constexpr float NEGS = 0.2f;

typedef __attribute__((ext_vector_type(8))) short short8;
typedef __attribute__((ext_vector_type(4))) float f32x4;
typedef unsigned short ushortT;

__device__ __forceinline__ float lrelu(float v) { return v > 0.f ? v : NEGS * v; }

// DPP-based max step; ctrl/rmask as template args (builtin requires ICE operands)
template<int CTRL, int RMASK>
__device__ __forceinline__ float dppmax(float v) {
    int o = __float_as_int(v);
    int s = __builtin_amdgcn_update_dpp(o, o, CTRL, RMASK, 0xf, false);
    return fmaxf(v, __int_as_float(s));
}
// full 64-lane max via DPP (valid in lane 63), then readlane-broadcast
__device__ __forceinline__ float wave_max_dpp(float v) {
    v = dppmax<0x111, 0xf>(v);   // row_shr:1
    v = dppmax<0x112, 0xf>(v);   // row_shr:2
    v = dppmax<0x114, 0xf>(v);   // row_shr:4
    v = dppmax<0x118, 0xf>(v);   // row_shr:8
    v = dppmax<0x142, 0xa>(v);   // row_bcast:15 -> rows 1,3
    v = dppmax<0x143, 0xc>(v);   // row_bcast:31 -> row 3 (and 2)
    return __int_as_float(__builtin_amdgcn_readlane(__float_as_int(v), 63));
}

// split fp32 -> bf16 hi (truncate) + bf16 lo (residual, truncate); packed 2-at-a-time
__device__ __forceinline__ void cvt2u(float a, float b, unsigned& h, unsigned& l) {
    unsigned ua = __float_as_uint(a), ub = __float_as_uint(b);
    h = (ua >> 16) | (ub & 0xffff0000u);
    float ra = a - __uint_as_float(ua & 0xffff0000u);
    float rb = b - __uint_as_float(ub & 0xffff0000u);
    l = (__float_as_uint(ra) >> 16) | (__float_as_uint(rb) & 0xffff0000u);
}

// x [B,3,N] -> pts point-major [B*N, 4] (pad lane = 0)
__global__ __launch_bounds__(256) void k_transpose(const float* __restrict__ x, float* __restrict__ pts) {
    int i = blockIdx.x * 256 + threadIdx.x;
    int b = i / Np, n = i % Np;
    float p0 = x[((size_t)b * 3 + 0) * Np + n];
    float p1 = x[((size_t)b * 3 + 1) * Np + n];
    float p2 = x[((size_t)b * 3 + 2) * Np + n];
    float4 v = make_float4(p0, p1, p2, 0.f);
    *(float4*)&pts[(size_t)i * 4] = v;
}

// xx[i] = sum_c pm[i*ld+c]^2 ; one wave per point, 4 points per block
__global__ __launch_bounds__(256) void k_xx(const float* __restrict__ pm, float* __restrict__ xxg, int C, int ld) {
    int wid = threadIdx.x >> 6, lane = threadIdx.x & 63;
    int pt = blockIdx.x * 4 + wid;
    const float* row = pm + (size_t)pt * ld;
    float acc = 0.f;
    for (int c = lane; c < C; c += 64) { float v = row[c]; acc = fmaf(v, v, acc); }
    #pragma unroll
    for (int off = 32; off; off >>= 1) acc += __shfl_down(acc, off, 64);
    if (lane == 0) xxg[pt] = acc;
}

// Pack points into mfma_16x16x32 B-fragment order (bf16 hi/lo), per batch.
template<int C, int CK, int LD>
__global__ __launch_bounds__(256) void k_bpack(const float* __restrict__ Xpm,
                                               ushortT* __restrict__ Bh, ushortT* __restrict__ Bl) {
    constexpr int KS = CK / 32;
    int i = blockIdx.x * 256 + threadIdx.x;
    int j = i & 7;
    int lane = (i >> 3) & 63;
    int nt = (i >> 9) & 127;
    int rest = i >> 16;
    int ks = rest % KS;
    int b = rest / KS;
    int k = ks * 32 + (lane >> 4) * 8 + j;
    int n = nt * 16 + (lane & 15);
    float v = (k < C) ? Xpm[((size_t)b * Np + n) * LD + k] : 0.f;
    unsigned u = __float_as_uint(v);
    Bh[i] = (ushortT)(u >> 16);
    float r = v - __uint_as_float(u & 0xffff0000u);
    Bl[i] = (ushortT)(__float_as_uint(r) >> 16);
}

// MFMA kNN v7: distance phase as v6 (chunked ping-pong dl); selection wave-max via DPP.
template<int C, int CK, int LD>
__global__ __launch_bounds__(1024) void k_knn5(const float* __restrict__ Xpm,
                                               const ushortT* __restrict__ Bh, const ushortT* __restrict__ Bl,
                                               const float* __restrict__ xxg, int* __restrict__ idxo) {
    constexpr int KS = CK / 32, CP = CK + 8, CK4 = CK / 4, C4src = LD / 4;
    constexpr int SD = 1026;
    extern __shared__ char smem[];
    ushortT* Ah = (ushortT*)smem;              // [16][CP]
    ushortT* Al = Ah + 16 * CP;                // [16][CP]
    float* xxm = (float*)(Al + 16 * CP);       // [16]
    float* dl = xxm + 16;                      // [16][SD] distances (one column-half)
    int b = blockIdx.x / (Np / 16);
    int n0 = (blockIdx.x % (Np / 16)) * 16;
    int t = threadIdx.x;
    const float4* Xp4 = (const float4*)Xpm;
    for (int e = t; e < 16 * CK4; e += 1024) {
        int r = e / CK4, c4 = e % CK4;
        float4 v = (c4 < C4src) ? Xp4[((size_t)b * Np + n0 + r) * C4src + c4] : make_float4(0.f, 0.f, 0.f, 0.f);
        unsigned h0, l0, h1, l1;
        cvt2u(v.x, v.y, h0, l0);
        cvt2u(v.z, v.w, h1, l1);
        *(uint2*)&Ah[r * CP + 4 * c4] = make_uint2(h0, h1);
        *(uint2*)&Al[r * CP + 4 * c4] = make_uint2(l0, l1);
    }
    if (t < 16) xxm[t] = xxg[b * Np + t + n0];
    __syncthreads();

    int w = t >> 6, lane = t & 63;
    int quad = lane >> 4, col = lane & 15;
    short8 ah[KS], al[KS];
    #pragma unroll
    for (int ks = 0; ks < KS; ++ks) {
        ah[ks] = *(const short8*)&Ah[col * CP + ks * 32 + quad * 8];
        al[ks] = *(const short8*)&Al[col * CP + ks * 32 + quad * 8];
    }
    float xmr[4];
    #pragma unroll
    for (int r = 0; r < 4; ++r) xmr[r] = xxm[quad * 4 + r];

    float v[32];
    #pragma unroll
    for (int cc = 0; cc < 2; ++cc) {
        for (int i = 0; i < 2; ++i) {
            int ntl0 = w * 4 + 2 * i, ntl1 = ntl0 + 1;
            int ng0 = cc * 64 + ntl0, ng1 = cc * 64 + ntl1;
            f32x4 a0 = (f32x4){0.f, 0.f, 0.f, 0.f};
            f32x4 a1 = (f32x4){0.f, 0.f, 0.f, 0.f};
            #pragma unroll
            for (int ks = 0; ks < KS; ++ks) {
                int bi0 = (((b * KS + ks) * 128 + ng0) * 64 + lane) * 8;
                int bi1 = (((b * KS + ks) * 128 + ng1) * 64 + lane) * 8;
                short8 bh0 = *(const short8*)(Bh + bi0);
                short8 bl0 = *(const short8*)(Bl + bi0);
                short8 bh1 = *(const short8*)(Bh + bi1);
                short8 bl1 = *(const short8*)(Bl + bi1);
                a0 = __builtin_amdgcn_mfma_f32_16x16x32_bf16(ah[ks], bh0, a0, 0, 0, 0);
                a1 = __builtin_amdgcn_mfma_f32_16x16x32_bf16(ah[ks], bh1, a1, 0, 0, 0);
                a0 = __builtin_amdgcn_mfma_f32_16x16x32_bf16(ah[ks], bl0, a0, 0, 0, 0);
                a1 = __builtin_amdgcn_mfma_f32_16x16x32_bf16(ah[ks], bl1, a1, 0, 0, 0);
                a0 = __builtin_amdgcn_mfma_f32_16x16x32_bf16(al[ks], bh0, a0, 0, 0, 0);
                a1 = __builtin_amdgcn_mfma_f32_16x16x32_bf16(al[ks], bh1, a1, 0, 0, 0);
            }
            float xn0 = xxg[b * Np + ng0 * 16 + col];
            float xn1 = xxg[b * Np + ng1 * 16 + col];
            #pragma unroll
            for (int r = 0; r < 4; ++r) {
                int m = quad * 4 + r;
                dl[m * SD + ntl0 * 16 + col] = 2.f * a0[r] - xmr[r] - xn0;
                dl[m * SD + ntl1 * 16 + col] = 2.f * a1[r] - xmr[r] - xn1;
            }
        }
        __syncthreads();
        const float* drow = dl + w * SD;
        #pragma unroll
        for (int j = 0; j < 16; ++j) v[cc * 16 + j] = drow[lane + 64 * j];
        __syncthreads();
    }

    // ---- selection: wave w owns row w (exact sequential argmax) ----
    float gv0, gv1, gv2, gv3;
    int gj0, gj1, gj2, gj3;
    gv0 = v[0]; gj0 = 0;
    #pragma unroll
    for (int e = 1; e < 8; ++e) if (v[e] > gv0) { gv0 = v[e]; gj0 = e; }
    gv1 = v[8]; gj1 = 8;
    #pragma unroll
    for (int e = 1; e < 8; ++e) if (v[8 + e] > gv1) { gv1 = v[8 + e]; gj1 = 8 + e; }
    gv2 = v[16]; gj2 = 16;
    #pragma unroll
    for (int e = 1; e < 8; ++e) if (v[16 + e] > gv2) { gv2 = v[16 + e]; gj2 = 16 + e; }
    gv3 = v[24]; gj3 = 24;
    #pragma unroll
    for (int e = 1; e < 8; ++e) if (v[24 + e] > gv3) { gv3 = v[24 + e]; gj3 = 24 + e; }

    size_t ob = ((size_t)b * Np + n0 + w) * Kn;
    for (int it = 0; it < Kn; ++it) {
        float lv = fmaxf(fmaxf(gv0, gv1), fmaxf(gv2, gv3));
        float Wv = wave_max_dpp(lv);
        unsigned long long mk = __ballot(lv == Wv);
        int owner = __ffsll(mk) - 1;
        if (lane == owner) {
            int lj;
            if (gv0 == Wv) lj = gj0;
            else if (gv1 == Wv) lj = gj1;
            else if (gv2 == Wv) lj = gj2;
            else lj = gj3;
            idxo[ob + it] = lane + 64 * lj;
            int gg = lj >> 3;
            if (gg == 0) {
                #pragma unroll
                for (int e = 0; e < 8; ++e) if (e == lj) v[e] = -INFINITY;
                gv0 = v[0]; gj0 = 0;
                #pragma unroll
                for (int e = 1; e < 8; ++e) if (v[e] > gv0) { gv0 = v[e]; gj0 = e; }
            } else if (gg == 1) {
                #pragma unroll
                for (int e = 0; e < 8; ++e) if (8 + e == lj) v[8 + e] = -INFINITY;
                gv1 = v[8]; gj1 = 8;
                #pragma unroll
                for (int e = 1; e < 8; ++e) if (v[8 + e] > gv1) { gv1 = v[8 + e]; gj1 = 8 + e; }
            } else if (gg == 2) {
                #pragma unroll
                for (int e = 0; e < 8; ++e) if (16 + e == lj) v[16 + e] = -INFINITY;
                gv2 = v[16]; gj2 = 16;
                #pragma unroll
                for (int e = 1; e < 8; ++e) if (v[16 + e] > gv2) { gv2 = v[16 + e]; gj2 = 16 + e; }
            } else {
                #pragma unroll
                for (int e = 0; e < 8; ++e) if (24 + e == lj) v[24 + e] = -INFINITY;
                gv3 = v[24]; gj3 = 24;
                #pragma unroll
                for (int e = 1; e < 8; ++e) if (v[24 + e] > gv3) { gv3 = v[24 + e]; gj3 = 24 + e; }
            }
        }
    }
}

// W split+scale+transpose (fp32, for k_ctr): WdsT[c][o] = (W[o][C+c]-W[o][c])*s[o]
__global__ __launch_bounds__(256) void k_wsplit(const float* __restrict__ W, const float* __restrict__ s,
                                                int C, int O, float* __restrict__ WnsT, float* __restrict__ WdsT) {
    int i = blockIdx.x * 256 + threadIdx.x;
    if (i >= C * O) return;
    int c = i / O, o = i % O;
    float a = W[(size_t)o * 2 * C + c];
    float q = W[(size_t)o * 2 * C + C + c];
    float sv = s[o];
    WnsT[i] = a * sv;
    WdsT[i] = (q - a) * sv;
}

// Pack neighbor-half of W (scaled) into mfma_16x16x32 B-fragment order, split bf16 hi/lo.
__global__ __launch_bounds__(256) void k_wpack(const float* __restrict__ W, const float* __restrict__ s,
                                               int C, int O, ushortT* __restrict__ Bh, ushortT* __restrict__ Bl) {
    int i = blockIdx.x * 256 + threadIdx.x;
    if (i >= C * O) return;
    int k = i / O, o = i % O;
    float v = W[(size_t)o * 2 * C + k] * s[o];
    int ks = k >> 5, quad = (k >> 3) & 3, j = k & 7;
    int nt = o >> 4, lane = quad * 16 + (o & 15);
    int NT = O / 16;
    size_t idx = (((size_t)(ks * NT + nt)) * 64 + lane) * 8 + j;
    unsigned u = __float_as_uint(v);
    Bh[idx] = (ushortT)(u >> 16);
    float r = v - __uint_as_float(u & 0xffff0000u);
    Bl[idx] = (ushortT)(__float_as_uint(r) >> 16);
}

// Pack W5 (scaled by s5) [1024][512] into fragment order: KS=16, NT=64.
__global__ __launch_bounds__(256) void k_w5pack(const float* __restrict__ W5, const float* __restrict__ s5,
                                                ushortT* __restrict__ Bh, ushortT* __restrict__ Bl) {
    int i = blockIdx.x * 256 + threadIdx.x;   // 512*1024
    int k = i >> 10, o = i & 1023;
    float v = W5[(size_t)o * 512 + k] * s5[o];
    int ks = k >> 5, quad = (k >> 3) & 3, j = k & 7;
    int nt = o >> 4, lane = quad * 16 + (o & 15);
    size_t idx = (((size_t)(ks * 64 + nt)) * 64 + lane) * 8 + j;
    unsigned u = __float_as_uint(v);
    Bh[idx] = (ushortT)(u >> 16);
    float r = v - __uint_as_float(u & 0xffff0000u);
    Bl[idx] = (ushortT)(__float_as_uint(r) >> 16);
}

// cb[n][o] = sum_c ctr[n][c]*WdsT[c][o] + b[o].  32 points per block.
template<int C, int O, int OPT>
__global__ __launch_bounds__(256) void k_ctr(const float* __restrict__ Xpm, const float* __restrict__ WdsT,
                                             const float* __restrict__ bg, float* __restrict__ cb) {
    constexpr int OG = O / OPT, MG = 256 / OG, MPT = 32 / MG;
    constexpr int C4 = C / 4;
    __shared__ float xs[32][C];
    int b = blockIdx.x / (Np / 32);
    int n0 = (blockIdx.x % (Np / 32)) * 32;
    int t = threadIdx.x;
    const float4* Xp4 = (const float4*)Xpm;
    for (int e = t; e < 32 * C4; e += 256) {
        int pt = e / C4, c4 = e % C4;
        *(float4*)&xs[pt][4 * c4] = Xp4[((size_t)b * Np + n0 + pt) * C4 + c4];
    }
    __syncthreads();
    int og = t % OG, mg = t / OG;
    int o0 = og * OPT;
    float acc[MPT][OPT] = {};
    for (int c = 0; c < C; ++c) {
        float wv[OPT];
        #pragma unroll
        for (int p4 = 0; p4 < OPT / 4; ++p4)
            *(float4*)&wv[4 * p4] = *(const float4*)&WdsT[(size_t)c * O + o0 + 4 * p4];
        #pragma unroll
        for (int m = 0; m < MPT; ++m) {
            float xv = xs[mg * MPT + m][c];
            #pragma unroll
            for (int p = 0; p < OPT; ++p) acc[m][p] = fmaf(wv[p], xv, acc[m][p]);
        }
    }
    #pragma unroll
    for (int m = 0; m < MPT; ++m) {
        #pragma unroll
        for (int p = 0; p < OPT; ++p) {
            int o = o0 + p;
            cb[((size_t)b * Np + n0 + mg * MPT + m) * O + o] = acc[m][p] + bg[o];
        }
    }
}

// MFMA EdgeConv GEMM v2 (split-bf16): waves split the O dimension.
template<int C, int O, int PTS>
__global__ __launch_bounds__(256, 4) void k_ec3(const float* __restrict__ Xpm, const int* __restrict__ idxg,
                                                const ushortT* __restrict__ Bh, const ushortT* __restrict__ Bl,
                                                const float* __restrict__ cb,
                                                float* __restrict__ Ypm) {
    static_assert(PTS == 2, "M=64 mapping");
    constexpr int M = 64, NT = O / 16, NT4 = NT / 4, KS = C / 32, C4 = C / 4, CP = C + 8;
    static_assert(NT4 >= 1, "O>=64");
    __shared__ ushortT Ah[M][CP];
    __shared__ ushortT Al[M][CP];
    int b = blockIdx.x / (Np / PTS);
    int n0 = (blockIdx.x % (Np / PTS)) * PTS;
    int t = threadIdx.x;
    const int* ip = idxg + ((size_t)b * Np + n0) * Kn;
    const float4* Xp4 = (const float4*)Xpm;
    for (int e = t; e < M * C4; e += 256) {
        int row = e / C4, c4 = e % C4;
        float4 v = Xp4[((size_t)b * Np + ip[row]) * C4 + c4];
        unsigned h0, l0, h1, l1;
        cvt2u(v.x, v.y, h0, l0);
        cvt2u(v.z, v.w, h1, l1);
        *(uint2*)&Ah[row][4 * c4] = make_uint2(h0, h1);
        *(uint2*)&Al[row][4 * c4] = make_uint2(l0, l1);
    }
    __syncthreads();
    int w = t >> 6, lane = t & 63;
    int quad = lane >> 4, col = lane & 15;
    f32x4 acc[4][NT4];
    #pragma unroll
    for (int mt = 0; mt < 4; ++mt)
        #pragma unroll
        for (int i = 0; i < NT4; ++i) acc[mt][i] = (f32x4){0.f, 0.f, 0.f, 0.f};
    for (int ks = 0; ks < KS; ++ks) {
        int kb = ks * 32 + quad * 8;
        short8 ah[4], al[4];
        #pragma unroll
        for (int mt = 0; mt < 4; ++mt) {
            ah[mt] = *(const short8*)&Ah[mt * 16 + col][kb];
            al[mt] = *(const short8*)&Al[mt * 16 + col][kb];
        }
        #pragma unroll
        for (int i = 0; i < NT4; ++i) {
            int nt = w * NT4 + i;
            size_t bi = (((size_t)(ks * NT + nt)) * 64 + lane) * 8;
            short8 bh = *(const short8*)(Bh + bi);
            short8 bl = *(const short8*)(Bl + bi);
            #pragma unroll
            for (int mt = 0; mt < 4; ++mt) {
                acc[mt][i] = __builtin_amdgcn_mfma_f32_16x16x32_bf16(ah[mt], bh, acc[mt][i], 0, 0, 0);
                acc[mt][i] = __builtin_amdgcn_mfma_f32_16x16x32_bf16(ah[mt], bl, acc[mt][i], 0, 0, 0);
                acc[mt][i] = __builtin_amdgcn_mfma_f32_16x16x32_bf16(al[mt], bh, acc[mt][i], 0, 0, 0);
            }
        }
    }
    #pragma unroll
    for (int pt = 0; pt < PTS; ++pt) {
        size_t ni = (size_t)b * Np + n0 + pt;
        #pragma unroll
        for (int i = 0; i < NT4; ++i) {
            f32x4 a0 = acc[2 * pt][i], a1 = acc[2 * pt + 1][i];
            float m = fmaxf(fmaxf(fmaxf(a0[0], a0[1]), fmaxf(a0[2], a0[3])),
                            fmaxf(fmaxf(a1[0], a1[1]), fmaxf(a1[2], a1[3])));
            m = fmaxf(m, __shfl_xor(m, 16, 64));
            m = fmaxf(m, __shfl_xor(m, 32, 64));
            if (lane < 16) {
                int o = (w * NT4 + i) * 16 + col;
                Ypm[ni * O + o] = lrelu(m + cb[ni * O + o]);
            }
        }
    }
}

// Legacy fused EdgeConv for layer 1 (C=3)
template<int C, int CPAD, int O, int OPT, int KPT, int PTS>
__global__ __launch_bounds__(256) void k_edgeconv(
    const float* __restrict__ Xpm, const int* __restrict__ idxg,
    const float* __restrict__ W, const float* __restrict__ sg, const float* __restrict__ bg,
    float* __restrict__ Ypm)
{
    constexpr int OG = O / OPT;
    constexpr int NKG = 256 / OG;
    constexpr int CL = CPAD + 4;
    static_assert(NKG * KPT == Kn, "k mapping");
    __shared__ float nbr[PTS][Kn][CL];
    __shared__ float ctr[PTS][CPAD];
    __shared__ float red[PTS][OPT][4][OG];
    int blk = blockIdx.x;
    int b = blk / (Np / PTS);
    int n0 = (blk % (Np / PTS)) * PTS;
    int t = threadIdx.x;
    int lane = t & 63, wid = t >> 6;
    const int* ip = idxg + ((size_t)b * Np + n0) * Kn;
    const float4* Xp4 = (const float4*)Xpm;
    constexpr int C4 = CPAD / 4;
    for (int e = t; e < PTS * C4; e += 256) {
        int pt = e / C4, c4 = e % C4;
        *(float4*)&ctr[pt][4 * c4] = Xp4[((size_t)b * Np + n0 + pt) * C4 + c4];
    }
    for (int e = t; e < PTS * Kn * C4; e += 256) {
        int pt = e / (Kn * C4);
        int r = e % (Kn * C4);
        int k = r / C4, c4 = r % C4;
        int nb = ip[pt * Kn + k];
        *(float4*)&nbr[pt][k][4 * c4] = Xp4[((size_t)b * Np + nb) * C4 + c4];
    }
    __syncthreads();
    int og = t % OG, kg = t / OG;
    float acc[PTS][OPT][KPT] = {};
    float ctt[PTS][OPT] = {};
    for (int c0 = 0; c0 < CPAD; c0 += 4) {
        float wn[OPT][4], wd[OPT][4];
        #pragma unroll
        for (int p = 0; p < OPT; ++p) {
            #pragma unroll
            for (int cc = 0; cc < 4; ++cc) {
                int c = c0 + cc;
                float a = (c < C) ? W[(size_t)(og + p * OG) * (2 * C) + c] : 0.f;
                float q = (c < C) ? W[(size_t)(og + p * OG) * (2 * C) + C + c] : 0.f;
                wn[p][cc] = a; wd[p][cc] = q - a;
            }
        }
        #pragma unroll
        for (int pt = 0; pt < PTS; ++pt) {
            float4 cv = *(const float4*)&ctr[pt][c0];
            #pragma unroll
            for (int p = 0; p < OPT; ++p) {
                ctt[pt][p] = fmaf(wd[p][0], cv.x, ctt[pt][p]);
                ctt[pt][p] = fmaf(wd[p][1], cv.y, ctt[pt][p]);
                ctt[pt][p] = fmaf(wd[p][2], cv.z, ctt[pt][p]);
                ctt[pt][p] = fmaf(wd[p][3], cv.w, ctt[pt][p]);
            }
        }
        #pragma unroll
        for (int pt = 0; pt < PTS; ++pt) {
            #pragma unroll
            for (int k = 0; k < KPT; ++k) {
                float4 nv = *(const float4*)&nbr[pt][kg * KPT + k][c0];
                #pragma unroll
                for (int p = 0; p < OPT; ++p) {
                    acc[pt][p][k] = fmaf(wn[p][0], nv.x, acc[pt][p][k]);
                    acc[pt][p][k] = fmaf(wn[p][1], nv.y, acc[pt][p][k]);
                    acc[pt][p][k] = fmaf(wn[p][2], nv.z, acc[pt][p][k]);
                    acc[pt][p][k] = fmaf(wn[p][3], nv.w, acc[pt][p][k]);
                }
            }
        }
    }
    #pragma unroll
    for (int pt = 0; pt < PTS; ++pt) {
        #pragma unroll
        for (int p = 0; p < OPT; ++p) {
            int o = og + p * OG;
            float sv = sg[o], bv = bg[o];
            float m = -INFINITY;
            #pragma unroll
            for (int k = 0; k < KPT; ++k) {
                float hv = fmaf(acc[pt][p][k] + ctt[pt][p], sv, bv);
                m = fmaxf(m, lrelu(hv));
            }
            #pragma unroll
            for (int s = OG; s < 64; s <<= 1) m = fmaxf(m, __shfl_xor(m, s, 64));
            if (lane < OG) red[pt][p][wid][lane] = m;
        }
    }
    __syncthreads();
    if (t < OG) {
        #pragma unroll
        for (int pt = 0; pt < PTS; ++pt) {
            #pragma unroll
            for (int p = 0; p < OPT; ++p) {
                float m = fmaxf(fmaxf(red[pt][p][0][t], red[pt][p][1][t]),
                                fmaxf(red[pt][p][2][t], red[pt][p][3][t]));
                int o = t + p * OG;
                Ypm[((size_t)b * Np + n0 + pt) * O + o] = m;
            }
        }
    }
}

// MFMA W5 (K=512, O=1024) + bias + LeakyReLU + max/sum pool over 32 points -> partials.
__global__ __launch_bounds__(1024, 4) void k_w5mfma(
    const float* __restrict__ x1, const float* __restrict__ x2,
    const float* __restrict__ x3, const float* __restrict__ x4,
    const ushortT* __restrict__ Bh, const ushortT* __restrict__ Bl,
    const float* __restrict__ b5,
    float* __restrict__ pmax, float* __restrict__ psum)
{
    constexpr int CP = 520;                 // 512 + 8 pad
    extern __shared__ char smem[];
    ushortT* Ah = (ushortT*)smem;           // [32][CP]
    ushortT* Al = Ah + 32 * CP;             // [32][CP]
    int b = blockIdx.x >> 6;
    int chunk = blockIdx.x & 63;
    int n0 = chunk * 32;
    int t = threadIdx.x;
    for (int e = t; e < 32 * 128; e += 1024) {
        int pt = e >> 7, c4 = e & 127;
        size_t pi = (size_t)b * Np + n0 + pt;
        float4 v;
        if (c4 < 16)      v = ((const float4*)x1)[pi * 16 + c4];
        else if (c4 < 32) v = ((const float4*)x2)[pi * 16 + (c4 - 16)];
        else if (c4 < 64) v = ((const float4*)x3)[pi * 32 + (c4 - 32)];
        else              v = ((const float4*)x4)[pi * 64 + (c4 - 64)];
        unsigned h0, l0, h1, l1;
        cvt2u(v.x, v.y, h0, l0);
        cvt2u(v.z, v.w, h1, l1);
        *(uint2*)&Ah[pt * CP + 4 * c4] = make_uint2(h0, h1);
        *(uint2*)&Al[pt * CP + 4 * c4] = make_uint2(l0, l1);
    }
    __syncthreads();
    int w = t >> 6, lane = t & 63;
    int quad = lane >> 4, col = lane & 15;
    size_t pb = ((size_t)(b * 64 + chunk)) * 1024;
    for (int oi = 0; oi < 4; ++oi) {
        int nt = w * 4 + oi;
        f32x4 a0 = (f32x4){0.f, 0.f, 0.f, 0.f};
        f32x4 a1 = (f32x4){0.f, 0.f, 0.f, 0.f};
        #pragma unroll 2
        for (int ks = 0; ks < 16; ++ks) {
            size_t bi = (((size_t)(ks * 64 + nt)) * 64 + lane) * 8;
            short8 bh = *(const short8*)(Bh + bi);
            short8 bl = *(const short8*)(Bl + bi);
            int ao = ks * 32 + quad * 8;
            short8 ah0 = *(const short8*)&Ah[col * CP + ao];
            short8 al0 = *(const short8*)&Al[col * CP + ao];
            short8 ah1 = *(const short8*)&Ah[(16 + col) * CP + ao];
            short8 al1 = *(const short8*)&Al[(16 + col) * CP + ao];
            a0 = __builtin_amdgcn_mfma_f32_16x16x32_bf16(ah0, bh, a0, 0, 0, 0);
            a1 = __builtin_amdgcn_mfma_f32_16x16x32_bf16(ah1, bh, a1, 0, 0, 0);
            a0 = __builtin_amdgcn_mfma_f32_16x16x32_bf16(ah0, bl, a0, 0, 0, 0);
            a1 = __builtin_amdgcn_mfma_f32_16x16x32_bf16(ah1, bl, a1, 0, 0, 0);
            a0 = __builtin_amdgcn_mfma_f32_16x16x32_bf16(al0, bh, a0, 0, 0, 0);
            a1 = __builtin_amdgcn_mfma_f32_16x16x32_bf16(al1, bh, a1, 0, 0, 0);
        }
        float bb = b5[nt * 16 + col];
        float mx = -INFINITY, sm = 0.f;
        #pragma unroll
        for (int r = 0; r < 4; ++r) {
            float v0 = lrelu(a0[r] + bb);
            float v1 = lrelu(a1[r] + bb);
            mx = fmaxf(mx, fmaxf(v0, v1));
            sm += v0 + v1;
        }
        mx = fmaxf(mx, __shfl_xor(mx, 16, 64));
        mx = fmaxf(mx, __shfl_xor(mx, 32, 64));
        sm += __shfl_xor(sm, 16, 64);
        sm += __shfl_xor(sm, 32, 64);
        if (lane < 16) {
            pmax[pb + nt * 16 + col] = mx;
            psum[pb + nt * 16 + col] = sm;
        }
    }
}

__global__ __launch_bounds__(256) void k_poolred(const float* __restrict__ pmax, const float* __restrict__ psum,
                                                 float* __restrict__ g0) {
    int i = blockIdx.x * 256 + threadIdx.x;
    int b = i >> 10, o = i & 1023;
    float mx = -INFINITY, sm = 0.f;
    for (int ch = 0; ch < 64; ++ch) {
        size_t idx = ((size_t)(b * 64 + ch)) * 1024 + o;
        mx = fmaxf(mx, pmax[idx]);
        sm += psum[idx];
    }
    g0[(size_t)b * 2048 + o] = mx;
    g0[(size_t)b * 2048 + 1024 + o] = sm * (1.f / Np);
}

__global__ __launch_bounds__(256) void k_fc(const float* __restrict__ In, int ldIn, int C,
                                            const float* __restrict__ Wm,
                                            const float* __restrict__ bias,
                                            const float* __restrict__ sc, const float* __restrict__ bnb,
                                            int leaky, float* __restrict__ Out, int ldOut, int O) {
    int wid = threadIdx.x >> 6, lane = threadIdx.x & 63;
    int o = blockIdx.x * 4 + wid;
    int b = blockIdx.y;
    if (o >= O) return;
    const float* in = In + (size_t)b * ldIn;
    const float* wr = Wm + (size_t)o * C;
    float acc = 0.f;
    for (int c = lane; c < C; c += 64) acc = fmaf(in[c], wr[c], acc);
    #pragma unroll
    for (int off = 32; off; off >>= 1) acc += __shfl_down(acc, off, 64);
    if (lane == 0) {
        float v = acc + (bias ? bias[o] : 0.f);
        if (sc) v = fmaf(v, sc[o], bnb[o]);
        if (leaky) v = lrelu(v);
        Out[(size_t)b * ldOut + o] = v;
    }
}

extern "C" void kernel_launch(void* const* d_in, const int* in_sizes, int n_in,
                              void* d_out, int out_size, void* d_ws, size_t ws_size,
                              hipStream_t stream) {
    const float* x   = (const float*)d_in[0];
    const float* W1  = (const float*)d_in[1];
    const float* s1  = (const float*)d_in[2];
    const float* b1  = (const float*)d_in[3];
    const float* W2  = (const float*)d_in[4];
    const float* s2  = (const float*)d_in[5];
    const float* b2  = (const float*)d_in[6];
    const float* W3  = (const float*)d_in[7];
    const float* s3  = (const float*)d_in[8];
    const float* b3  = (const float*)d_in[9];
    const float* W4  = (const float*)d_in[10];
    const float* s4  = (const float*)d_in[11];
    const float* b4  = (const float*)d_in[12];
    const float* W5  = (const float*)d_in[13];
    const float* s5  = (const float*)d_in[14];
    const float* b5  = (const float*)d_in[15];
    const float* L1w = (const float*)d_in[16];
    const float* s6  = (const float*)d_in[17];
    const float* b6  = (const float*)d_in[18];
    const float* L2w = (const float*)d_in[19];
    const float* L2b = (const float*)d_in[20];
    const float* s7  = (const float*)d_in[21];
    const float* b7  = (const float*)d_in[22];
    const float* L3w = (const float*)d_in[23];
    const float* L3b = (const float*)d_in[24];
    const float* F1w = (const float*)d_in[25];
    const float* s8  = (const float*)d_in[26];
    const float* b8  = (const float*)d_in[27];
    const float* F2w = (const float*)d_in[28];
    const float* F2b = (const float*)d_in[29];
    const float* s9  = (const float*)d_in[30];
    const float* b9  = (const float*)d_in[31];
    const float* F3w = (const float*)d_in[32];
    const float* F3b = (const float*)d_in[33];

    float* ws = (float*)d_ws;
    size_t off = 0;
    auto alloc = [&](size_t n) { float* p = ws + off; off += n; return p; };
    float* pts  = alloc((size_t)Bn * Np * 4);
    float* x1   = alloc((size_t)Bn * Np * 64);
    float* x2   = alloc((size_t)Bn * Np * 64);
    float* x3   = alloc((size_t)Bn * Np * 128);
    float* x4   = alloc((size_t)Bn * Np * 256);
    float* xcm  = alloc((size_t)Bn * Np * 128);   // aliased: pmax / psum
    float* xxb  = alloc((size_t)Bn * Np);
    int*   idxb = (int*)alloc((size_t)Bn * Np * Kn);
    float* g0   = alloc((size_t)Bn * 2048);
    float* g1   = alloc((size_t)Bn * 512);
    float* g2   = alloc((size_t)Bn * 256);
    float* y1   = alloc((size_t)Bn * 512);
    float* y2   = alloc((size_t)Bn * 256);
    float* WnsT2 = alloc(64 * 64);
    float* WdsT2 = alloc(64 * 64);
    float* WnsT3 = alloc(64 * 128);
    float* WdsT3 = alloc(64 * 128);
    float* WnsT4 = alloc(128 * 256);
    float* WdsT4 = alloc(128 * 256);
    ushortT* Bh2 = (ushortT*)alloc(64 * 64 / 2);
    ushortT* Bl2 = (ushortT*)alloc(64 * 64 / 2);
    ushortT* Bh3 = (ushortT*)alloc(64 * 128 / 2);
    ushortT* Bl3 = (ushortT*)alloc(64 * 128 / 2);
    ushortT* Bh4 = (ushortT*)alloc(128 * 256 / 2);
    ushortT* Bl4 = (ushortT*)alloc(128 * 256 / 2);
    ushortT* BhK = (ushortT*)alloc(1048576);   // knn B-frag hi (max C=128: 2M shorts)
    ushortT* BlK = (ushortT*)alloc(1048576);
    ushortT* Bh5 = (ushortT*)alloc(262144);    // W5 frag hi: 512K shorts
    ushortT* Bl5 = (ushortT*)alloc(262144);
    float* pmax = xcm;
    float* psum = xcm + 524288;
    float* cb2 = x2;
    float* cb3 = x3;
    float* cb4 = x4;

    // dynamic-LDS opt-ins (idempotent, safe pre-capture)
    auto shsz = [](int CP) { return 16 * CP * 2 * 2 + 64 + 16 * 1026 * 4; };
    int sh3 = shsz(40), sh64 = shsz(72), sh128 = shsz(136);
    int shw5 = 32 * 520 * 2 * 2;
    (void)hipFuncSetAttribute((const void*)k_knn5<3, 32, 4>, hipFuncAttributeMaxDynamicSharedMemorySize, sh3);
    (void)hipFuncSetAttribute((const void*)k_knn5<64, 64, 64>, hipFuncAttributeMaxDynamicSharedMemorySize, sh64);
    (void)hipFuncSetAttribute((const void*)k_knn5<128, 128, 128>, hipFuncAttributeMaxDynamicSharedMemorySize, sh128);
    (void)hipFuncSetAttribute((const void*)k_w5mfma, hipFuncAttributeMaxDynamicSharedMemorySize, shw5);

    k_transpose<<<Bn * Np / 256, 256, 0, stream>>>(x, pts);
    k_wsplit<<<16, 256, 0, stream>>>(W2, s2, 64, 64, WnsT2, WdsT2);
    k_wsplit<<<32, 256, 0, stream>>>(W3, s3, 64, 128, WnsT3, WdsT3);
    k_wsplit<<<128, 256, 0, stream>>>(W4, s4, 128, 256, WnsT4, WdsT4);
    k_wpack<<<16, 256, 0, stream>>>(W2, s2, 64, 64, Bh2, Bl2);
    k_wpack<<<32, 256, 0, stream>>>(W3, s3, 64, 128, Bh3, Bl3);
    k_wpack<<<128, 256, 0, stream>>>(W4, s4, 128, 256, Bh4, Bl4);
    k_w5pack<<<2048, 256, 0, stream>>>(W5, s5, Bh5, Bl5);

    // Layer 1: C=3
    k_xx<<<Bn * Np / 4, 256, 0, stream>>>(pts, xxb, 3, 4);
    k_bpack<3, 32, 4><<<2048, 256, 0, stream>>>(pts, BhK, BlK);
    k_knn5<3, 32, 4><<<Bn * Np / 16, 1024, sh3, stream>>>(pts, BhK, BlK, xxb, idxb);
    k_edgeconv<3, 4, 64, 1, 8, 4><<<Bn * Np / 4, 256, 0, stream>>>(pts, idxb, W1, s1, b1, x1);

    // Layer 2: C=64 -> O=64
    k_xx<<<Bn * Np / 4, 256, 0, stream>>>(x1, xxb, 64, 64);
    k_bpack<64, 64, 64><<<4096, 256, 0, stream>>>(x1, BhK, BlK);
    k_knn5<64, 64, 64><<<Bn * Np / 16, 1024, sh64, stream>>>(x1, BhK, BlK, xxb, idxb);
    k_ctr<64, 64, 4><<<Bn * Np / 32, 256, 0, stream>>>(x1, WdsT2, b2, cb2);
    k_ec3<64, 64, 2><<<Bn * Np / 2, 256, 0, stream>>>(x1, idxb, Bh2, Bl2, cb2, x2);

    // Layer 3: C=64 -> O=128
    k_xx<<<Bn * Np / 4, 256, 0, stream>>>(x2, xxb, 64, 64);
    k_bpack<64, 64, 64><<<4096, 256, 0, stream>>>(x2, BhK, BlK);
    k_knn5<64, 64, 64><<<Bn * Np / 16, 1024, sh64, stream>>>(x2, BhK, BlK, xxb, idxb);
    k_ctr<64, 128, 8><<<Bn * Np / 32, 256, 0, stream>>>(x2, WdsT3, b3, cb3);
    k_ec3<64, 128, 2><<<Bn * Np / 2, 256, 0, stream>>>(x2, idxb, Bh3, Bl3, cb3, x3);

    // Layer 4: C=128 -> O=256
    k_xx<<<Bn * Np / 4, 256, 0, stream>>>(x3, xxb, 128, 128);
    k_bpack<128, 128, 128><<<8192, 256, 0, stream>>>(x3, BhK, BlK);
    k_knn5<128, 128, 128><<<Bn * Np / 16, 1024, sh128, stream>>>(x3, BhK, BlK, xxb, idxb);
    k_ctr<128, 256, 8><<<Bn * Np / 32, 256, 0, stream>>>(x3, WdsT4, b4, cb4);
    k_ec3<128, 256, 2><<<Bn * Np / 2, 256, 0, stream>>>(x3, idxb, Bh4, Bl4, cb4, x4);

    // W5 + pooling (MFMA, 16-wave blocks)
    k_w5mfma<<<Bn * 64, 1024, shw5, stream>>>(x1, x2, x3, x4, Bh5, Bl5, b5, pmax, psum);
    k_poolred<<<Bn * 1024 / 256, 256, 0, stream>>>(pmax, psum, g0);

    float* out = (float*)d_out;
    k_fc<<<dim3(128, Bn), 256, 0, stream>>>(g0, 2048, 2048, L1w, nullptr, s6, b6, 1, g1, 512, 512);
    k_fc<<<dim3(64, Bn), 256, 0, stream>>>(g1, 512, 512, L2w, L2b, s7, b7, 1, g2, 256, 256);
    k_fc<<<dim3(2, Bn), 256, 0, stream>>>(g2, 256, 256, L3w, L3b, nullptr, nullptr, 0, out, 5, 5);
    k_fc<<<dim3(128, Bn), 256, 0, stream>>>(g0, 2048, 1024, F1w, nullptr, s8, b8, 1, y1, 512, 512);
    k_fc<<<dim3(64, Bn), 256, 0, stream>>>(y1, 512, 512, F2w, F2b, s9, b9, 1, y2, 256, 256);
    k_fc<<<dim3(2, Bn), 256, 0, stream>>>(y2, 256, 256, F3w, F3b, nullptr, nullptr, 0, out + 40, 5, 5);
}